// Round 6
// baseline (226.057 us; speedup 1.0000x reference)
//
#include <hip/hip_runtime.h>
#include <hip/hip_bf16.h>

// MultiHeadAttention: B=4 S=2048 D=1024 H=16 DK=DV=64 scale=8
// R6: proj rebuilt as m97-structure bf16 GEMM with 16B global_load_lds staging.
// conv_kernel pre-converts X (fp32->bf16, A-frag column-perm applied) and W
// (fp32->bf16, B-tile-contiguous order) so GEMM staging is linear DMA with
// zero VALU. Evidence: R2/R4/R5 showed conversion style irrelevant (~150us
// regardless); proj is latency-structure-bound (MfmaUtil 14, VALUBusy 43,
// nothing saturated). m151: gload_lds 874TF vs reg-staged 646TF at 128^2.
// Fallback to R5 proj if ws_size < 107MB. Attn unchanged (~66us).

typedef unsigned short u16;
typedef unsigned int   u32;
typedef short bf16x8 __attribute__((ext_vector_type(8)));
typedef short bf16x4 __attribute__((ext_vector_type(4)));
typedef float f32x4  __attribute__((ext_vector_type(4)));
typedef u32   u32x4  __attribute__((ext_vector_type(4)));

#define S_TOT 2048
#define HD    1024
#define QK_SCALE 0.18033688f   // log2(e)/8

#if __has_builtin(__builtin_amdgcn_exp2f)
#define EXP2(x) __builtin_amdgcn_exp2f(x)
#else
#define EXP2(x) exp2f(x)
#endif

// branchless RNE f32->bf16
__device__ __forceinline__ u16 f2bf(float f) {
  union { float f; unsigned u; } v; v.f = f;
  unsigned r = v.u + 0x7FFFu + ((v.u >> 16) & 1u);
  return (u16)(r >> 16);
}

__device__ __forceinline__ u32 cvt_pk_bf16(float lo, float hi) {
  u32 r;
  asm("v_cvt_pk_bf16_f32 %0, %1, %2" : "=v"(r) : "v"(lo), "v"(hi));
  return r;
}

__device__ __forceinline__ bf16x4 ds_tr16(unsigned a) {
  bf16x4 d;
  asm volatile("ds_read_b64_tr_b16 %0, %1" : "=v"(d) : "v"(a) : "memory");
  return d;
}

// direct global->LDS DMA, 16B per lane; LDS dst = wave-uniform base + lane*16
__device__ __forceinline__ void gld16(const u16* g, u16* l) {
  __builtin_amdgcn_global_load_lds(
      (const __attribute__((address_space(1))) u32*)g,
      (__attribute__((address_space(3))) u32*)l, 16, 0, 0);
}

// rule #18: inline-asm lgkmcnt needs sched_barrier(0) right after
#define LGKM_FENCE() do { asm volatile("s_waitcnt lgkmcnt(0)" ::: "memory"); \
                          __builtin_amdgcn_sched_barrier(0); } while (0)

// ---------------------------------------------------------------------------
// conv_kernel: fp32 -> bf16 re-layout pass.
//  X: [8192][1024] per z -> Xb (row-major, intra-32 column perm so a b128 LDS
//     read yields the split-K A-fragment directly).
//  W: [1024][1024] per z -> Wt in B-tile order: [(nb*32+kb)][nsub8][ksub2][16k][16n]
//     so each GEMM B-tile is one contiguous 8KB chunk.
// ---------------------------------------------------------------------------
__global__ __launch_bounds__(256)
void conv_kernel(const float* __restrict__ x0, const float* __restrict__ x1, const float* __restrict__ x2,
                 const float* __restrict__ w0, const float* __restrict__ w1, const float* __restrict__ w2,
                 u16* __restrict__ Xb, u16* __restrict__ Wt)
{
  const int z = blockIdx.y;
  const int t = threadIdx.x;
  if (blockIdx.x < 1024) {
    const float* X = z == 0 ? x0 : (z == 1 ? x1 : x2);
    u16* Xz = Xb + (size_t)z * 8388608;
    int tid = blockIdx.x * 256 + t;          // 0..262143
#pragma unroll
    for (int i = 0; i < 8; ++i) {
      int c = tid + i * 262144;              // chunk id, 2097152 total
      int row = c >> 8, k4 = (c & 255) * 4;
      const float4 xv = *(const float4*)&X[(size_t)row * 1024 + k4];
      int p = (k4 & ~31) + 8 * ((k4 & 15) >> 2) + 4 * ((k4 >> 4) & 1);
      bf16x4 sv = { (short)f2bf(xv.x), (short)f2bf(xv.y), (short)f2bf(xv.z), (short)f2bf(xv.w) };
      *(bf16x4*)&Xz[(size_t)row * 1024 + p] = sv;
    }
  } else {
    const float* W = z == 0 ? w0 : (z == 1 ? w1 : w2);
    u16* Wz = Wt + (size_t)z * 1048576;
    int tid = (blockIdx.x - 1024) * 256 + t; // 0..32767
#pragma unroll
    for (int i = 0; i < 8; ++i) {
      int c = tid + i * 32768;               // 262144 total
      int k = c >> 8, n4 = (c & 255) * 4;
      const float4 wv = *(const float4*)&W[(size_t)k * 1024 + n4];
      int off = ((n4 >> 7) * 32 + (k >> 5)) * 4096 + ((n4 >> 4) & 7) * 512
              + ((k >> 4) & 1) * 256 + (k & 15) * 16 + (n4 & 15);
      bf16x4 sv = { (short)f2bf(wv.x), (short)f2bf(wv.y), (short)f2bf(wv.z), (short)f2bf(wv.w) };
      *(bf16x4*)&Wz[off] = sv;
    }
  }
}

// ---------------------------------------------------------------------------
// gemm_kernel (m97 structure): out = bf16( osc * (Xb.W + bias) )
// 128x128xBK32 tiles, 4 waves, wave tile 64x64, single-buffer LDS (16KB),
// staging = 4x global_load_lds(16B) per thread per k-step, 2 barriers/step.
// ---------------------------------------------------------------------------
__global__ __launch_bounds__(256)
void gemm_kernel(const u16* __restrict__ Xb, const u16* __restrict__ Wt,
                 const float* __restrict__ b0, const float* __restrict__ b1, const float* __restrict__ b2,
                 u16* __restrict__ o0, u16* __restrict__ o1, u16* __restrict__ o2)
{
  // bijective XCD swizzle: nwg=1536 (%8==0)
  int p  = blockIdx.x + 8 * blockIdx.y + 512 * blockIdx.z;
  int wk = (p & 7) * 192 + (p >> 3);
  int nb = wk & 7, mb = (wk >> 3) & 63, z = wk >> 9;

  const u16* Xz = Xb + (size_t)z * 8388608;
  const u16* Wz = Wt + (size_t)z * 1048576;
  const float* BS = z == 0 ? b0 : (z == 1 ? b1 : b2);
  u16*         O  = z == 0 ? o0 : (z == 1 ? o1 : o2);
  const float  osc = (z == 0) ? QK_SCALE : 1.0f;

  const int t = threadIdx.x;
  const int lane = t & 63, wid = t >> 6;
  const int g = lane >> 4, ln = lane & 15;
  const int wm = wid >> 1, wn = wid & 1;
  const int mbase = mb * 128, nbase = nb * 128;

  __shared__ __align__(16) u16 Al[128 * 32];     // 8KB, row-major (cols pre-permuted in Xb)
  __shared__ __align__(16) u16 Bl[16 * 256];     // 8KB, [nsub8][ksub2][16k][16n] tiles

  f32x4 acc[4][4];
#pragma unroll
  for (int i = 0; i < 4; ++i)
#pragma unroll
    for (int j = 0; j < 4; ++j) { acc[i][j][0]=0.f; acc[i][j][1]=0.f; acc[i][j][2]=0.f; acc[i][j][3]=0.f; }

  // staging sources (per lane); LDS dst = wave base + lane*16 (implicit)
  const u16* sa = Xz + (size_t)(mbase + (t >> 2)) * 1024 + (t & 3) * 8;
  const u16* sb = Wz + (size_t)(nb * 32) * 4096 + t * 8;
  u16* al_w = &Al[wid * 512];                    // wave-uniform LDS bases
  u16* bl_w = &Bl[wid * 512];

  const unsigned bs_base = (unsigned)(size_t)&Bl[0] + (unsigned)((wn * 4) * 1024) + lane * 8;

  for (int kb = 0; kb < 32; ++kb) {
    // stage tile kb: A rows (64 per round), B contiguous 4KB rounds
    gld16(sa + kb * 32,                 al_w);
    gld16(sa + kb * 32 + 64 * 1024,     al_w + 2048);
    gld16(sb + kb * 4096,               bl_w);
    gld16(sb + kb * 4096 + 2048,        bl_w + 2048);
    __syncthreads();                    // drains vmcnt -> tile visible

    bf16x8 af[4];
#pragma unroll
    for (int mf = 0; mf < 4; ++mf)
      af[mf] = *(const bf16x8*)&Al[(wm * 64 + mf * 16 + ln) * 32 + g * 8];

    bf16x8 bfv[4];
#pragma unroll
    for (int nf = 0; nf < 4; ++nf) {
      bf16x4 lo = ds_tr16(bs_base + (unsigned)(nf * 1024));        // ksub0: k 0..15
      bf16x4 hi = ds_tr16(bs_base + (unsigned)(nf * 1024 + 512));  // ksub1: k 16..31
      bf16x8 bb;
      bb[0]=lo[0]; bb[1]=lo[1]; bb[2]=lo[2]; bb[3]=lo[3];
      bb[4]=hi[0]; bb[5]=hi[1]; bb[6]=hi[2]; bb[7]=hi[3];
      bfv[nf] = bb;
    }
    LGKM_FENCE();
#pragma unroll
    for (int mf = 0; mf < 4; ++mf)
#pragma unroll
      for (int nf = 0; nf < 4; ++nf)
        acc[mf][nf] = __builtin_amdgcn_mfma_f32_16x16x32_bf16(af[mf], bfv[nf], acc[mf][nf], 0, 0, 0);
    __syncthreads();                    // all reads done before next stage
  }

  // epilogue: bias + scale + bf16 store
#pragma unroll
  for (int nf = 0; nf < 4; ++nf) {
    int n = nbase + wn * 64 + nf * 16 + ln;
    float bv = BS[n];
#pragma unroll
    for (int mf = 0; mf < 4; ++mf)
#pragma unroll
      for (int r = 0; r < 4; ++r) {
        int m = mbase + wm * 64 + mf * 16 + 4 * g + r;
        O[(size_t)m * 1024 + n] = f2bf((acc[mf][nf][r] + bv) * osc);
      }
  }
}

// ---------------------------------------------------------------------------
// Fallback proj (R5 body): used only if ws_size can't hold Xb+Wt.
// ---------------------------------------------------------------------------
__global__ __launch_bounds__(256)
void proj_kernel(const float* __restrict__ x0, const float* __restrict__ x1, const float* __restrict__ x2,
                 const float* __restrict__ w0, const float* __restrict__ w1, const float* __restrict__ w2,
                 const float* __restrict__ b0, const float* __restrict__ b1, const float* __restrict__ b2,
                 u16* __restrict__ o0, u16* __restrict__ o1, u16* __restrict__ o2)
{
  int p  = blockIdx.x + 8 * blockIdx.y + 512 * blockIdx.z;
  int wk = (p & 7) * 192 + (p >> 3);
  int nb = wk & 7, mb = (wk >> 3) & 63, z = wk >> 9;

  const float* X  = z == 0 ? x0 : (z == 1 ? x1 : x2);
  const float* W  = z == 0 ? w0 : (z == 1 ? w1 : w2);
  const float* BS = z == 0 ? b0 : (z == 1 ? b1 : b2);
  u16*         O  = z == 0 ? o0 : (z == 1 ? o1 : o2);
  const float  osc = (z == 0) ? QK_SCALE : 1.0f;

  const int t = threadIdx.x;
  const int lane = t & 63, wid = t >> 6;
  const int g = lane >> 4, ln = lane & 15;
  const int wm = wid >> 1, wn = wid & 1;
  const int mbase = mb * 128, nbase = nb * 128;

  __shared__ __align__(16) u16 As[128 * 40];
  __shared__ __align__(16) u16 Bs[16 * 272];

  f32x4 acc[4][4];
#pragma unroll
  for (int i = 0; i < 4; ++i)
#pragma unroll
    for (int j = 0; j < 4; ++j) { acc[i][j][0]=0.f; acc[i][j][1]=0.f; acc[i][j][2]=0.f; acc[i][j][3]=0.f; }

  const int arow = t >> 3;
  const int ak0  = (t & 7) * 4;
  const int ap   = 8 * ((ak0 & 15) >> 2) + 4 * (ak0 >> 4);
  const int bkr  = t >> 5;
  const int bnc  = (t & 31) * 4;
  const int bnblk = bnc >> 4, bncl = bnc & 15;

  const unsigned bs_base = (unsigned)(size_t)&Bs[0];

  for (int kb = 0; kb < 32; ++kb) {
    const int kbase = kb * 32;
#pragma unroll
    for (int ps = 0; ps < 4; ++ps) {
      int row = arow + 32 * ps;
      const float4 xv = *(const float4*)&X[(size_t)(mbase + row) * 1024 + kbase + ak0];
      bf16x4 sv = { (short)f2bf(xv.x), (short)f2bf(xv.y), (short)f2bf(xv.z), (short)f2bf(xv.w) };
      *(bf16x4*)&As[row * 40 + ap] = sv;
    }
#pragma unroll
    for (int ps = 0; ps < 4; ++ps) {
      int kr = bkr + 8 * ps;
      const float4 wv = *(const float4*)&W[(size_t)(kbase + kr) * 1024 + nbase + bnc];
      bf16x4 sv = { (short)f2bf(wv.x), (short)f2bf(wv.y), (short)f2bf(wv.z), (short)f2bf(wv.w) };
      *(bf16x4*)&Bs[(bnblk * 2 + (kr >> 4)) * 272 + (kr & 15) * 16 + bncl] = sv;
    }
    __syncthreads();

    bf16x8 af[4];
#pragma unroll
    for (int mf = 0; mf < 4; ++mf)
      af[mf] = *(const bf16x8*)&As[(wm * 64 + mf * 16 + ln) * 40 + g * 8];

    bf16x8 bfv[4];
#pragma unroll
    for (int nf = 0; nf < 4; ++nf) {
      unsigned base = bs_base + (unsigned)(((wn * 4 + nf) * 2) * 544) + lane * 8;
      bf16x4 lo = ds_tr16(base);
      bf16x4 hi = ds_tr16(base + 544);
      bf16x8 bb;
      bb[0]=lo[0]; bb[1]=lo[1]; bb[2]=lo[2]; bb[3]=lo[3];
      bb[4]=hi[0]; bb[5]=hi[1]; bb[6]=hi[2]; bb[7]=hi[3];
      bfv[nf] = bb;
    }
    LGKM_FENCE();
#pragma unroll
    for (int mf = 0; mf < 4; ++mf)
#pragma unroll
      for (int nf = 0; nf < 4; ++nf)
        acc[mf][nf] = __builtin_amdgcn_mfma_f32_16x16x32_bf16(af[mf], bfv[nf], acc[mf][nf], 0, 0, 0);
    __syncthreads();
  }

#pragma unroll
  for (int nf = 0; nf < 4; ++nf) {
    int n = nbase + wn * 64 + nf * 16 + ln;
    float bv = BS[n];
#pragma unroll
    for (int mf = 0; mf < 4; ++mf)
#pragma unroll
      for (int r = 0; r < 4; ++r) {
        int m = mbase + wm * 64 + mf * 16 + 4 * g + r;
        O[(size_t)m * 1024 + n] = f2bf((acc[mf][nf][r] + bv) * osc);
      }
  }
}

// ---------------------------------------------------------------------------
// Attention (unchanged): swapped QK^T, max-free softmax, tr-read V.
// ---------------------------------------------------------------------------
__global__ __launch_bounds__(256)
void attn_kernel(const u16* __restrict__ qh, const u16* __restrict__ kh, const u16* __restrict__ vh,
                 float* __restrict__ out)
{
  int p  = blockIdx.x + 16 * blockIdx.y + 256 * blockIdx.z;
  int wk = (p & 7) * 128 + (p >> 3);
  int qt = wk & 15, h = (wk >> 4) & 15, b = wk >> 8;

  const int t = threadIdx.x;
  const int lane = t & 63, wid = t >> 6;
  const int g = lane >> 4, ln = lane & 15;
  const size_t bS = (size_t)b * S_TOT;
  const int qwin = qt * 128 + wid * 32;

  __shared__ __align__(16) u16 Ks[32 * 72];
  __shared__ __align__(16) u16 Vs[8 * 272];

  bf16x8 qf[2][2];
#pragma unroll
  for (int nf = 0; nf < 2; ++nf) {
    const u16* qrow = &qh[(bS + qwin + nf * 16 + ln) * HD + h * 64];
#pragma unroll
    for (int kk = 0; kk < 2; ++kk) {
      bf16x4 lo = *(const bf16x4*)&qrow[kk * 32 + 4 * g];
      bf16x4 hi = *(const bf16x4*)&qrow[kk * 32 + 4 * g + 16];
      bf16x8 qq;
      qq[0]=lo[0]; qq[1]=lo[1]; qq[2]=lo[2]; qq[3]=lo[3];
      qq[4]=hi[0]; qq[5]=hi[1]; qq[6]=hi[2]; qq[7]=hi[3];
      qf[nf][kk] = qq;
    }
  }

  f32x4 o[2][4];
#pragma unroll
  for (int i = 0; i < 2; ++i)
#pragma unroll
    for (int j = 0; j < 4; ++j) { o[i][j][0]=0.f; o[i][j][1]=0.f; o[i][j][2]=0.f; o[i][j][3]=0.f; }
  float lsum[2] = {0.f, 0.f};

  const unsigned vs_base = (unsigned)(size_t)&Vs[0] + lane * 8;
  const int skv = t >> 4;
  const int sd0 = (t & 15) * 4;
  const int kpos = 32 * (sd0 >> 5) + 8 * ((sd0 & 15) >> 2) + 4 * ((sd0 >> 4) & 1);

  u16* ksw0 = &Ks[skv * 72 + kpos];
  u16* ksw1 = &Ks[(skv + 16) * 72 + kpos];
  u16* vsw0 = &Vs[(2 * (sd0 >> 4) + 0) * 272 + skv * 16 + (sd0 & 15)];
  u16* vsw1 = &Vs[(2 * (sd0 >> 4) + 1) * 272 + skv * 16 + (sd0 & 15)];
  const u16* kp = &kh[(bS + skv) * HD + h * 64 + sd0];
  const u16* vp = &vh[(bS + skv) * HD + h * 64 + sd0];

  for (int kvstep = 0; kvstep < 64; ++kvstep) {
    *(bf16x4*)ksw0 = *(const bf16x4*)kp;
    *(bf16x4*)ksw1 = *(const bf16x4*)(kp + (size_t)16 * HD);
    *(bf16x4*)vsw0 = *(const bf16x4*)vp;
    *(bf16x4*)vsw1 = *(const bf16x4*)(vp + (size_t)16 * HD);
    kp += (size_t)32 * HD; vp += (size_t)32 * HD;
    __syncthreads();

    bf16x8 kf[2][2];
#pragma unroll
    for (int mf = 0; mf < 2; ++mf)
#pragma unroll
      for (int kk = 0; kk < 2; ++kk)
        kf[mf][kk] = *(const bf16x8*)&Ks[(mf * 16 + ln) * 72 + kk * 32 + 8 * g];

    f32x4 sc[2][2];
#pragma unroll
    for (int mf = 0; mf < 2; ++mf)
#pragma unroll
      for (int nf = 0; nf < 2; ++nf) {
        f32x4 a; a[0]=0.f; a[1]=0.f; a[2]=0.f; a[3]=0.f;
#pragma unroll
        for (int kk = 0; kk < 2; ++kk)
          a = __builtin_amdgcn_mfma_f32_16x16x32_bf16(kf[mf][kk], qf[nf][kk], a, 0, 0, 0);
        sc[mf][nf] = a;
      }

    bf16x8 vf[4];
#pragma unroll
    for (int nf = 0; nf < 4; ++nf) {
      bf16x4 lo = ds_tr16(vs_base + (unsigned)((nf * 2) * 544));
      bf16x4 hi = ds_tr16(vs_base + (unsigned)((nf * 2 + 1) * 544));
      bf16x8 bb;
      bb[0]=lo[0]; bb[1]=lo[1]; bb[2]=lo[2]; bb[3]=lo[3];
      bb[4]=hi[0]; bb[5]=hi[1]; bb[6]=hi[2]; bb[7]=hi[3];
      vf[nf] = bb;
    }

    bf16x8 pa[2];
#pragma unroll
    for (int nf = 0; nf < 2; ++nf) {
      float pv[2][4];
#pragma unroll
      for (int mf = 0; mf < 2; ++mf)
#pragma unroll
        for (int r = 0; r < 4; ++r)
          pv[mf][r] = EXP2(sc[mf][nf][r]);
      float s0 = pv[0][0] + pv[0][1], s1 = pv[0][2] + pv[0][3];
      float s2 = pv[1][0] + pv[1][1], s3 = pv[1][2] + pv[1][3];
      lsum[nf] += (s0 + s1) + (s2 + s3);
      union { u32x4 u; bf16x8 b; } pk;
      pk.u[0] = cvt_pk_bf16(pv[0][0], pv[0][1]);
      pk.u[1] = cvt_pk_bf16(pv[0][2], pv[0][3]);
      pk.u[2] = cvt_pk_bf16(pv[1][0], pv[1][1]);
      pk.u[3] = cvt_pk_bf16(pv[1][2], pv[1][3]);
      pa[nf] = pk.b;
    }

    LGKM_FENCE();
#pragma unroll
    for (int mq = 0; mq < 2; ++mq)
#pragma unroll
      for (int nf = 0; nf < 4; ++nf)
        o[mq][nf] = __builtin_amdgcn_mfma_f32_16x16x32_bf16(pa[mq], vf[nf], o[mq][nf], 0, 0, 0);
    __syncthreads();
  }

#pragma unroll
  for (int nf = 0; nf < 2; ++nf) {
    lsum[nf] += __shfl_xor(lsum[nf], 16, 64);
    lsum[nf] += __shfl_xor(lsum[nf], 32, 64);
  }

#pragma unroll
  for (int mq = 0; mq < 2; ++mq)
#pragma unroll
    for (int r = 0; r < 4; ++r) {
      int src = (lane & 48) | (4 * g + r);
      float inv = 1.0f / __shfl(lsum[mq], src, 64);
      int qrow = qwin + mq * 16 + 4 * g + r;
#pragma unroll
      for (int nf = 0; nf < 4; ++nf)
        out[(bS + qrow) * HD + h * 64 + nf * 16 + ln] = o[mq][nf][r] * inv;
    }
}

extern "C" void kernel_launch(void* const* d_in, const int* in_sizes, int n_in,
                              void* d_out, int out_size, void* d_ws, size_t ws_size,
                              hipStream_t stream) {
  const float* q  = (const float*)d_in[0];
  const float* k  = (const float*)d_in[1];
  const float* v  = (const float*)d_in[2];
  const float* Wq = (const float*)d_in[3];
  const float* bq = (const float*)d_in[4];
  const float* Wk = (const float*)d_in[5];
  const float* bk = (const float*)d_in[6];
  const float* Wv = (const float*)d_in[7];
  const float* bv = (const float*)d_in[8];
  float* out = (float*)d_out;

  u16* qh = (u16*)d_ws;                                   // 3 x 16.78MB outputs
  u16* kh = qh + (size_t)8192 * 1024;
  u16* vh = kh + (size_t)8192 * 1024;

  const size_t XB_OFF = (size_t)3 * 8192 * 1024;          // elems
  const size_t WT_OFF = XB_OFF + (size_t)3 * 8192 * 1024;
  const size_t NEED   = (WT_OFF + (size_t)3 * 1024 * 1024) * 2;  // bytes = 107MB

  if (ws_size >= NEED) {
    u16* Xb = (u16*)d_ws + XB_OFF;
    u16* Wt = (u16*)d_ws + WT_OFF;
    conv_kernel<<<dim3(1152, 3), 256, 0, stream>>>(q, k, v, Wq, Wk, Wv, Xb, Wt);
    gemm_kernel<<<dim3(8, 64, 3), 256, 0, stream>>>(Xb, Wt, bq, bk, bv, qh, kh, vh);
  } else {
    proj_kernel<<<dim3(8, 64, 3), 256, 0, stream>>>(q, k, v, Wq, Wk, Wv, bq, bk, bv, qh, kh, vh);
  }
  attn_kernel<<<dim3(16, 16, 4), 256, 0, stream>>>(qh, kh, vh, out);
}

// Round 8
// 211.720 us; speedup vs baseline: 1.0677x; 1.0677x over previous
//
#include <hip/hip_runtime.h>
#include <hip/hip_bf16.h>

// MultiHeadAttention: B=4 S=2048 D=1024 H=16 DK=DV=64 scale=8
// R8: attn = R6's exact 2-barrier single-buffer protocol; ONLY change is the
// global K/V loads for step t+1 are issued right after barrier #1 of step t
// (latency hides under compute; consumed by next step's ds_writes). R7's
// 1-barrier dbuf raced (absmax 3.6e-3) -> abandoned per m152. setprio(1)
// around MFMA clusters (T5, correctness-neutral). conv/gemm/proj frozen.

typedef unsigned short u16;
typedef unsigned int   u32;
typedef short bf16x8 __attribute__((ext_vector_type(8)));
typedef short bf16x4 __attribute__((ext_vector_type(4)));
typedef float f32x4  __attribute__((ext_vector_type(4)));
typedef u32   u32x4  __attribute__((ext_vector_type(4)));

#define S_TOT 2048
#define HD    1024
#define QK_SCALE 0.18033688f   // log2(e)/8

#if __has_builtin(__builtin_amdgcn_exp2f)
#define EXP2(x) __builtin_amdgcn_exp2f(x)
#else
#define EXP2(x) exp2f(x)
#endif

// branchless RNE f32->bf16
__device__ __forceinline__ u16 f2bf(float f) {
  union { float f; unsigned u; } v; v.f = f;
  unsigned r = v.u + 0x7FFFu + ((v.u >> 16) & 1u);
  return (u16)(r >> 16);
}

__device__ __forceinline__ u32 cvt_pk_bf16(float lo, float hi) {
  u32 r;
  asm("v_cvt_pk_bf16_f32 %0, %1, %2" : "=v"(r) : "v"(lo), "v"(hi));
  return r;
}

__device__ __forceinline__ bf16x4 ds_tr16(unsigned a) {
  bf16x4 d;
  asm volatile("ds_read_b64_tr_b16 %0, %1" : "=v"(d) : "v"(a) : "memory");
  return d;
}

// direct global->LDS DMA, 16B per lane
__device__ __forceinline__ void gld16(const u16* g, u16* l) {
  __builtin_amdgcn_global_load_lds(
      (const __attribute__((address_space(1))) u32*)g,
      (__attribute__((address_space(3))) u32*)l, 16, 0, 0);
}

// rule #18: inline-asm lgkmcnt needs sched_barrier(0) right after
#define LGKM_FENCE() do { asm volatile("s_waitcnt lgkmcnt(0)" ::: "memory"); \
                          __builtin_amdgcn_sched_barrier(0); } while (0)

// ---------------------------------------------------------------------------
// conv_kernel (R6, frozen): fp32 -> bf16 re-layout pass.
// ---------------------------------------------------------------------------
__global__ __launch_bounds__(256)
void conv_kernel(const float* __restrict__ x0, const float* __restrict__ x1, const float* __restrict__ x2,
                 const float* __restrict__ w0, const float* __restrict__ w1, const float* __restrict__ w2,
                 u16* __restrict__ Xb, u16* __restrict__ Wt)
{
  const int z = blockIdx.y;
  const int t = threadIdx.x;
  if (blockIdx.x < 1024) {
    const float* X = z == 0 ? x0 : (z == 1 ? x1 : x2);
    u16* Xz = Xb + (size_t)z * 8388608;
    int tid = blockIdx.x * 256 + t;
#pragma unroll
    for (int i = 0; i < 8; ++i) {
      int c = tid + i * 262144;
      int row = c >> 8, k4 = (c & 255) * 4;
      const float4 xv = *(const float4*)&X[(size_t)row * 1024 + k4];
      int p = (k4 & ~31) + 8 * ((k4 & 15) >> 2) + 4 * ((k4 >> 4) & 1);
      bf16x4 sv = { (short)f2bf(xv.x), (short)f2bf(xv.y), (short)f2bf(xv.z), (short)f2bf(xv.w) };
      *(bf16x4*)&Xz[(size_t)row * 1024 + p] = sv;
    }
  } else {
    const float* W = z == 0 ? w0 : (z == 1 ? w1 : w2);
    u16* Wz = Wt + (size_t)z * 1048576;
    int tid = (blockIdx.x - 1024) * 256 + t;
#pragma unroll
    for (int i = 0; i < 8; ++i) {
      int c = tid + i * 32768;
      int k = c >> 8, n4 = (c & 255) * 4;
      const float4 wv = *(const float4*)&W[(size_t)k * 1024 + n4];
      int off = ((n4 >> 7) * 32 + (k >> 5)) * 4096 + ((n4 >> 4) & 7) * 512
              + ((k >> 4) & 1) * 256 + (k & 15) * 16 + (n4 & 15);
      bf16x4 sv = { (short)f2bf(wv.x), (short)f2bf(wv.y), (short)f2bf(wv.z), (short)f2bf(wv.w) };
      *(bf16x4*)&Wz[off] = sv;
    }
  }
}

// ---------------------------------------------------------------------------
// gemm_kernel (R6, frozen): m97-structure bf16 GEMM, gload_lds staging.
// ---------------------------------------------------------------------------
__global__ __launch_bounds__(256)
void gemm_kernel(const u16* __restrict__ Xb, const u16* __restrict__ Wt,
                 const float* __restrict__ b0, const float* __restrict__ b1, const float* __restrict__ b2,
                 u16* __restrict__ o0, u16* __restrict__ o1, u16* __restrict__ o2)
{
  int p  = blockIdx.x + 8 * blockIdx.y + 512 * blockIdx.z;
  int wk = (p & 7) * 192 + (p >> 3);
  int nb = wk & 7, mb = (wk >> 3) & 63, z = wk >> 9;

  const u16* Xz = Xb + (size_t)z * 8388608;
  const u16* Wz = Wt + (size_t)z * 1048576;
  const float* BS = z == 0 ? b0 : (z == 1 ? b1 : b2);
  u16*         O  = z == 0 ? o0 : (z == 1 ? o1 : o2);
  const float  osc = (z == 0) ? QK_SCALE : 1.0f;

  const int t = threadIdx.x;
  const int lane = t & 63, wid = t >> 6;
  const int g = lane >> 4, ln = lane & 15;
  const int wm = wid >> 1, wn = wid & 1;
  const int mbase = mb * 128, nbase = nb * 128;

  __shared__ __align__(16) u16 Al[128 * 32];
  __shared__ __align__(16) u16 Bl[16 * 256];

  f32x4 acc[4][4];
#pragma unroll
  for (int i = 0; i < 4; ++i)
#pragma unroll
    for (int j = 0; j < 4; ++j) { acc[i][j][0]=0.f; acc[i][j][1]=0.f; acc[i][j][2]=0.f; acc[i][j][3]=0.f; }

  const u16* sa = Xz + (size_t)(mbase + (t >> 2)) * 1024 + (t & 3) * 8;
  const u16* sb = Wz + (size_t)(nb * 32) * 4096 + t * 8;
  u16* al_w = &Al[wid * 512];
  u16* bl_w = &Bl[wid * 512];

  const unsigned bs_base = (unsigned)(size_t)&Bl[0] + (unsigned)((wn * 4) * 1024) + lane * 8;

  for (int kb = 0; kb < 32; ++kb) {
    gld16(sa + kb * 32,                 al_w);
    gld16(sa + kb * 32 + 64 * 1024,     al_w + 2048);
    gld16(sb + kb * 4096,               bl_w);
    gld16(sb + kb * 4096 + 2048,        bl_w + 2048);
    __syncthreads();

    bf16x8 af[4];
#pragma unroll
    for (int mf = 0; mf < 4; ++mf)
      af[mf] = *(const bf16x8*)&Al[(wm * 64 + mf * 16 + ln) * 32 + g * 8];

    bf16x8 bfv[4];
#pragma unroll
    for (int nf = 0; nf < 4; ++nf) {
      bf16x4 lo = ds_tr16(bs_base + (unsigned)(nf * 1024));
      bf16x4 hi = ds_tr16(bs_base + (unsigned)(nf * 1024 + 512));
      bf16x8 bb;
      bb[0]=lo[0]; bb[1]=lo[1]; bb[2]=lo[2]; bb[3]=lo[3];
      bb[4]=hi[0]; bb[5]=hi[1]; bb[6]=hi[2]; bb[7]=hi[3];
      bfv[nf] = bb;
    }
    LGKM_FENCE();
#pragma unroll
    for (int mf = 0; mf < 4; ++mf)
#pragma unroll
      for (int nf = 0; nf < 4; ++nf)
        acc[mf][nf] = __builtin_amdgcn_mfma_f32_16x16x32_bf16(af[mf], bfv[nf], acc[mf][nf], 0, 0, 0);
    __syncthreads();
  }

#pragma unroll
  for (int nf = 0; nf < 4; ++nf) {
    int n = nbase + wn * 64 + nf * 16 + ln;
    float bv = BS[n];
#pragma unroll
    for (int mf = 0; mf < 4; ++mf)
#pragma unroll
      for (int r = 0; r < 4; ++r) {
        int m = mbase + wm * 64 + mf * 16 + 4 * g + r;
        O[(size_t)m * 1024 + n] = f2bf((acc[mf][nf][r] + bv) * osc);
      }
  }
}

// ---------------------------------------------------------------------------
// Fallback proj (R5 body, frozen).
// ---------------------------------------------------------------------------
__global__ __launch_bounds__(256)
void proj_kernel(const float* __restrict__ x0, const float* __restrict__ x1, const float* __restrict__ x2,
                 const float* __restrict__ w0, const float* __restrict__ w1, const float* __restrict__ w2,
                 const float* __restrict__ b0, const float* __restrict__ b1, const float* __restrict__ b2,
                 u16* __restrict__ o0, u16* __restrict__ o1, u16* __restrict__ o2)
{
  int p  = blockIdx.x + 8 * blockIdx.y + 512 * blockIdx.z;
  int wk = (p & 7) * 192 + (p >> 3);
  int nb = wk & 7, mb = (wk >> 3) & 63, z = wk >> 9;

  const float* X  = z == 0 ? x0 : (z == 1 ? x1 : x2);
  const float* W  = z == 0 ? w0 : (z == 1 ? w1 : w2);
  const float* BS = z == 0 ? b0 : (z == 1 ? b1 : b2);
  u16*         O  = z == 0 ? o0 : (z == 1 ? o1 : o2);
  const float  osc = (z == 0) ? QK_SCALE : 1.0f;

  const int t = threadIdx.x;
  const int lane = t & 63, wid = t >> 6;
  const int g = lane >> 4, ln = lane & 15;
  const int wm = wid >> 1, wn = wid & 1;
  const int mbase = mb * 128, nbase = nb * 128;

  __shared__ __align__(16) u16 As[128 * 40];
  __shared__ __align__(16) u16 Bs[16 * 272];

  f32x4 acc[4][4];
#pragma unroll
  for (int i = 0; i < 4; ++i)
#pragma unroll
    for (int j = 0; j < 4; ++j) { acc[i][j][0]=0.f; acc[i][j][1]=0.f; acc[i][j][2]=0.f; acc[i][j][3]=0.f; }

  const int arow = t >> 3;
  const int ak0  = (t & 7) * 4;
  const int ap   = 8 * ((ak0 & 15) >> 2) + 4 * (ak0 >> 4);
  const int bkr  = t >> 5;
  const int bnc  = (t & 31) * 4;
  const int bnblk = bnc >> 4, bncl = bnc & 15;

  const unsigned bs_base = (unsigned)(size_t)&Bs[0];

  for (int kb = 0; kb < 32; ++kb) {
    const int kbase = kb * 32;
#pragma unroll
    for (int ps = 0; ps < 4; ++ps) {
      int row = arow + 32 * ps;
      const float4 xv = *(const float4*)&X[(size_t)(mbase + row) * 1024 + kbase + ak0];
      bf16x4 sv = { (short)f2bf(xv.x), (short)f2bf(xv.y), (short)f2bf(xv.z), (short)f2bf(xv.w) };
      *(bf16x4*)&As[row * 40 + ap] = sv;
    }
#pragma unroll
    for (int ps = 0; ps < 4; ++ps) {
      int kr = bkr + 8 * ps;
      const float4 wv = *(const float4*)&W[(size_t)(kbase + kr) * 1024 + nbase + bnc];
      bf16x4 sv = { (short)f2bf(wv.x), (short)f2bf(wv.y), (short)f2bf(wv.z), (short)f2bf(wv.w) };
      *(bf16x4*)&Bs[(bnblk * 2 + (kr >> 4)) * 272 + (kr & 15) * 16 + bncl] = sv;
    }
    __syncthreads();

    bf16x8 af[4];
#pragma unroll
    for (int mf = 0; mf < 4; ++mf)
      af[mf] = *(const bf16x8*)&As[(wm * 64 + mf * 16 + ln) * 40 + g * 8];

    bf16x8 bfv[4];
#pragma unroll
    for (int nf = 0; nf < 4; ++nf) {
      unsigned base = bs_base + (unsigned)(((wn * 4 + nf) * 2) * 544) + lane * 8;
      bf16x4 lo = ds_tr16(base);
      bf16x4 hi = ds_tr16(base + 544);
      bf16x8 bb;
      bb[0]=lo[0]; bb[1]=lo[1]; bb[2]=lo[2]; bb[3]=lo[3];
      bb[4]=hi[0]; bb[5]=hi[1]; bb[6]=hi[2]; bb[7]=hi[3];
      bfv[nf] = bb;
    }
    LGKM_FENCE();
#pragma unroll
    for (int mf = 0; mf < 4; ++mf)
#pragma unroll
      for (int nf = 0; nf < 4; ++nf)
        acc[mf][nf] = __builtin_amdgcn_mfma_f32_16x16x32_bf16(af[mf], bfv[nf], acc[mf][nf], 0, 0, 0);
    __syncthreads();
  }

#pragma unroll
  for (int nf = 0; nf < 4; ++nf) {
    int n = nbase + wn * 64 + nf * 16 + ln;
    float bv = BS[n];
#pragma unroll
    for (int mf = 0; mf < 4; ++mf)
#pragma unroll
      for (int r = 0; r < 4; ++r) {
        int m = mbase + wm * 64 + mf * 16 + 4 * g + r;
        O[(size_t)m * 1024 + n] = f2bf((acc[mf][nf][r] + bv) * osc);
      }
  }
}

// ---------------------------------------------------------------------------
// Attention R8: R6 protocol (single K/V buffer, 2 __syncthreads per step);
// global loads for step t+1 issued right after barrier #1 of step t.
// ---------------------------------------------------------------------------
__global__ __launch_bounds__(256)
void attn_kernel(const u16* __restrict__ qh, const u16* __restrict__ kh, const u16* __restrict__ vh,
                 float* __restrict__ out)
{
  int p  = blockIdx.x + 16 * blockIdx.y + 256 * blockIdx.z;
  int wk = (p & 7) * 128 + (p >> 3);
  int qt = wk & 15, h = (wk >> 4) & 15, b = wk >> 8;

  const int t = threadIdx.x;
  const int lane = t & 63, wid = t >> 6;
  const int g = lane >> 4, ln = lane & 15;
  const size_t bS = (size_t)b * S_TOT;
  const int qwin = qt * 128 + wid * 32;

  __shared__ __align__(16) u16 Ks[32 * 72];
  __shared__ __align__(16) u16 Vs[8 * 272];

  // Q fragments (qh pre-scaled by log2e/8)
  bf16x8 qf[2][2];
#pragma unroll
  for (int nf = 0; nf < 2; ++nf) {
    const u16* qrow = &qh[(bS + qwin + nf * 16 + ln) * HD + h * 64];
#pragma unroll
    for (int kk = 0; kk < 2; ++kk) {
      bf16x4 lo = *(const bf16x4*)&qrow[kk * 32 + 4 * g];
      bf16x4 hi = *(const bf16x4*)&qrow[kk * 32 + 4 * g + 16];
      bf16x8 qq;
      qq[0]=lo[0]; qq[1]=lo[1]; qq[2]=lo[2]; qq[3]=lo[3];
      qq[4]=hi[0]; qq[5]=hi[1]; qq[6]=hi[2]; qq[7]=hi[3];
      qf[nf][kk] = qq;
    }
  }

  f32x4 o[2][4];
#pragma unroll
  for (int i = 0; i < 2; ++i)
#pragma unroll
    for (int j = 0; j < 4; ++j) { o[i][j][0]=0.f; o[i][j][1]=0.f; o[i][j][2]=0.f; o[i][j][3]=0.f; }
  float lsum[2] = {0.f, 0.f};

  const unsigned vs_base = (unsigned)(size_t)&Vs[0] + lane * 8;
  const int skv = t >> 4;
  const int sd0 = (t & 15) * 4;
  const int kpos = 32 * (sd0 >> 5) + 8 * ((sd0 & 15) >> 2) + 4 * ((sd0 >> 4) & 1);

  u16* ksw0 = &Ks[skv * 72 + kpos];
  u16* ksw1 = &Ks[(skv + 16) * 72 + kpos];
  u16* vsw0 = &Vs[(2 * (sd0 >> 4) + 0) * 272 + skv * 16 + (sd0 & 15)];
  u16* vsw1 = &Vs[(2 * (sd0 >> 4) + 1) * 272 + skv * 16 + (sd0 & 15)];
  const u16* kp = &kh[(bS + skv) * HD + h * 64 + sd0];
  const u16* vp = &vh[(bS + skv) * HD + h * 64 + sd0];
  const size_t STEP = (size_t)32 * HD, HALF = (size_t)16 * HD;

  // prologue: load step-0 data into regs
  bf16x4 kr0 = *(const bf16x4*)kp, kr1 = *(const bf16x4*)(kp + HALF);
  bf16x4 vr0 = *(const bf16x4*)vp, vr1 = *(const bf16x4*)(vp + HALF);
  kp += STEP; vp += STEP;

  for (int kvstep = 0; kvstep < 64; ++kvstep) {
    // stage step t's data (already in regs)
    *(bf16x4*)ksw0 = kr0;
    *(bf16x4*)ksw1 = kr1;
    *(bf16x4*)vsw0 = vr0;
    *(bf16x4*)vsw1 = vr1;
    __syncthreads();                                   // barrier #1

    // issue loads for step t+1 — latency hides under this step's compute
    if (kvstep < 63) {
      kr0 = *(const bf16x4*)kp; kr1 = *(const bf16x4*)(kp + HALF);
      vr0 = *(const bf16x4*)vp; vr1 = *(const bf16x4*)(vp + HALF);
      kp += STEP; vp += STEP;
    }

    // K fragments (A operand)
    bf16x8 kf[2][2];
#pragma unroll
    for (int mf = 0; mf < 2; ++mf)
#pragma unroll
      for (int kk = 0; kk < 2; ++kk)
        kf[mf][kk] = *(const bf16x8*)&Ks[(mf * 16 + ln) * 72 + kk * 32 + 8 * g];

    // S^T = K.Q^T
    f32x4 sc[2][2];
    __builtin_amdgcn_s_setprio(1);
#pragma unroll
    for (int mf = 0; mf < 2; ++mf)
#pragma unroll
      for (int nf = 0; nf < 2; ++nf) {
        f32x4 a; a[0]=0.f; a[1]=0.f; a[2]=0.f; a[3]=0.f;
#pragma unroll
        for (int kk = 0; kk < 2; ++kk)
          a = __builtin_amdgcn_mfma_f32_16x16x32_bf16(kf[mf][kk], qf[nf][kk], a, 0, 0, 0);
        sc[mf][nf] = a;
      }
    __builtin_amdgcn_s_setprio(0);

    // V fragments via tr-reads
    bf16x8 vf[4];
#pragma unroll
    for (int nf = 0; nf < 4; ++nf) {
      bf16x4 lo = ds_tr16(vs_base + (unsigned)((nf * 2) * 544));
      bf16x4 hi = ds_tr16(vs_base + (unsigned)((nf * 2 + 1) * 544));
      bf16x8 bb;
      bb[0]=lo[0]; bb[1]=lo[1]; bb[2]=lo[2]; bb[3]=lo[3];
      bb[4]=hi[0]; bb[5]=hi[1]; bb[6]=hi[2]; bb[7]=hi[3];
      vf[nf] = bb;
    }

    // P = exp2(sc), pack into PV A-frags
    bf16x8 pa[2];
#pragma unroll
    for (int nf = 0; nf < 2; ++nf) {
      float pv[2][4];
#pragma unroll
      for (int mf = 0; mf < 2; ++mf)
#pragma unroll
        for (int r = 0; r < 4; ++r)
          pv[mf][r] = EXP2(sc[mf][nf][r]);
      float s0 = pv[0][0] + pv[0][1], s1 = pv[0][2] + pv[0][3];
      float s2 = pv[1][0] + pv[1][1], s3 = pv[1][2] + pv[1][3];
      lsum[nf] += (s0 + s1) + (s2 + s3);
      union { u32x4 u; bf16x8 b; } pk;
      pk.u[0] = cvt_pk_bf16(pv[0][0], pv[0][1]);
      pk.u[1] = cvt_pk_bf16(pv[0][2], pv[0][3]);
      pk.u[2] = cvt_pk_bf16(pv[1][0], pv[1][1]);
      pk.u[3] = cvt_pk_bf16(pv[1][2], pv[1][3]);
      pa[nf] = pk.b;
    }

    LGKM_FENCE();
    __builtin_amdgcn_s_setprio(1);
#pragma unroll
    for (int mq = 0; mq < 2; ++mq)
#pragma unroll
      for (int nf = 0; nf < 4; ++nf)
        o[mq][nf] = __builtin_amdgcn_mfma_f32_16x16x32_bf16(pa[mq], vf[nf], o[mq][nf], 0, 0, 0);
    __builtin_amdgcn_s_setprio(0);
    __syncthreads();                                   // barrier #2
  }

  // reduce lsum across lane-groups
#pragma unroll
  for (int nf = 0; nf < 2; ++nf) {
    lsum[nf] += __shfl_xor(lsum[nf], 16, 64);
    lsum[nf] += __shfl_xor(lsum[nf], 32, 64);
  }

  // normalize + store
#pragma unroll
  for (int mq = 0; mq < 2; ++mq)
#pragma unroll
    for (int r = 0; r < 4; ++r) {
      int src = (lane & 48) | (4 * g + r);
      float inv = 1.0f / __shfl(lsum[mq], src, 64);
      int qrow = qwin + mq * 16 + 4 * g + r;
#pragma unroll
      for (int nf = 0; nf < 4; ++nf)
        out[(bS + qrow) * HD + h * 64 + nf * 16 + ln] = o[mq][nf][r] * inv;
    }
}

extern "C" void kernel_launch(void* const* d_in, const int* in_sizes, int n_in,
                              void* d_out, int out_size, void* d_ws, size_t ws_size,
                              hipStream_t stream) {
  const float* q  = (const float*)d_in[0];
  const float* k  = (const float*)d_in[1];
  const float* v  = (const float*)d_in[2];
  const float* Wq = (const float*)d_in[3];
  const float* bq = (const float*)d_in[4];
  const float* Wk = (const float*)d_in[5];
  const float* bk = (const float*)d_in[6];
  const float* Wv = (const float*)d_in[7];
  const float* bv = (const float*)d_in[8];
  float* out = (float*)d_out;

  u16* qh = (u16*)d_ws;
  u16* kh = qh + (size_t)8192 * 1024;
  u16* vh = kh + (size_t)8192 * 1024;

  const size_t XB_OFF = (size_t)3 * 8192 * 1024;
  const size_t WT_OFF = XB_OFF + (size_t)3 * 8192 * 1024;
  const size_t NEED   = (WT_OFF + (size_t)3 * 1024 * 1024) * 2;

  if (ws_size >= NEED) {
    u16* Xb = (u16*)d_ws + XB_OFF;
    u16* Wt = (u16*)d_ws + WT_OFF;
    conv_kernel<<<dim3(1152, 3), 256, 0, stream>>>(q, k, v, Wq, Wk, Wv, Xb, Wt);
    gemm_kernel<<<dim3(8, 64, 3), 256, 0, stream>>>(Xb, Wt, bq, bk, bv, qh, kh, vh);
  } else {
    proj_kernel<<<dim3(8, 64, 3), 256, 0, stream>>>(q, k, v, Wq, Wk, Wv, bq, bk, bv, qh, kh, vh);
  }
  attn_kernel<<<dim3(16, 16, 4), 256, 0, stream>>>(qh, kh, vh, out);
}

// Round 9
// 210.092 us; speedup vs baseline: 1.0760x; 1.0078x over previous
//
#include <hip/hip_runtime.h>
#include <hip/hip_bf16.h>

// MultiHeadAttention: B=4 S=2048 D=1024 H=16 DK=DV=64 scale=8
// R9: attn — (1) KVBLK=64: two compute sub-steps per barrier interval (barrier
// count halved, cross-substep ILP), same proven 2-barrier protocol per interval;
// (2) row-sum via ones-MFMA: o1[mq]=mfma(pa,ones) replaces lsum VALU adds and
// the entire epilogue shuffle reduce (rowsum is lane-local in o1[mq][r]).
// Load-early prefetch + setprio kept from R8. conv/gemm/proj frozen.

typedef unsigned short u16;
typedef unsigned int   u32;
typedef short bf16x8 __attribute__((ext_vector_type(8)));
typedef short bf16x4 __attribute__((ext_vector_type(4)));
typedef float f32x4  __attribute__((ext_vector_type(4)));
typedef u32   u32x4  __attribute__((ext_vector_type(4)));

#define S_TOT 2048
#define HD    1024
#define QK_SCALE 0.18033688f   // log2(e)/8

#if __has_builtin(__builtin_amdgcn_exp2f)
#define EXP2(x) __builtin_amdgcn_exp2f(x)
#else
#define EXP2(x) exp2f(x)
#endif

// branchless RNE f32->bf16
__device__ __forceinline__ u16 f2bf(float f) {
  union { float f; unsigned u; } v; v.f = f;
  unsigned r = v.u + 0x7FFFu + ((v.u >> 16) & 1u);
  return (u16)(r >> 16);
}

__device__ __forceinline__ u32 cvt_pk_bf16(float lo, float hi) {
  u32 r;
  asm("v_cvt_pk_bf16_f32 %0, %1, %2" : "=v"(r) : "v"(lo), "v"(hi));
  return r;
}

__device__ __forceinline__ bf16x4 ds_tr16(unsigned a) {
  bf16x4 d;
  asm volatile("ds_read_b64_tr_b16 %0, %1" : "=v"(d) : "v"(a) : "memory");
  return d;
}

// direct global->LDS DMA, 16B per lane
__device__ __forceinline__ void gld16(const u16* g, u16* l) {
  __builtin_amdgcn_global_load_lds(
      (const __attribute__((address_space(1))) u32*)g,
      (__attribute__((address_space(3))) u32*)l, 16, 0, 0);
}

// rule #18: inline-asm lgkmcnt needs sched_barrier(0) right after
#define LGKM_FENCE() do { asm volatile("s_waitcnt lgkmcnt(0)" ::: "memory"); \
                          __builtin_amdgcn_sched_barrier(0); } while (0)

// ---------------------------------------------------------------------------
// conv_kernel (R6, frozen): fp32 -> bf16 re-layout pass.
// ---------------------------------------------------------------------------
__global__ __launch_bounds__(256)
void conv_kernel(const float* __restrict__ x0, const float* __restrict__ x1, const float* __restrict__ x2,
                 const float* __restrict__ w0, const float* __restrict__ w1, const float* __restrict__ w2,
                 u16* __restrict__ Xb, u16* __restrict__ Wt)
{
  const int z = blockIdx.y;
  const int t = threadIdx.x;
  if (blockIdx.x < 1024) {
    const float* X = z == 0 ? x0 : (z == 1 ? x1 : x2);
    u16* Xz = Xb + (size_t)z * 8388608;
    int tid = blockIdx.x * 256 + t;
#pragma unroll
    for (int i = 0; i < 8; ++i) {
      int c = tid + i * 262144;
      int row = c >> 8, k4 = (c & 255) * 4;
      const float4 xv = *(const float4*)&X[(size_t)row * 1024 + k4];
      int p = (k4 & ~31) + 8 * ((k4 & 15) >> 2) + 4 * ((k4 >> 4) & 1);
      bf16x4 sv = { (short)f2bf(xv.x), (short)f2bf(xv.y), (short)f2bf(xv.z), (short)f2bf(xv.w) };
      *(bf16x4*)&Xz[(size_t)row * 1024 + p] = sv;
    }
  } else {
    const float* W = z == 0 ? w0 : (z == 1 ? w1 : w2);
    u16* Wz = Wt + (size_t)z * 1048576;
    int tid = (blockIdx.x - 1024) * 256 + t;
#pragma unroll
    for (int i = 0; i < 8; ++i) {
      int c = tid + i * 32768;
      int k = c >> 8, n4 = (c & 255) * 4;
      const float4 wv = *(const float4*)&W[(size_t)k * 1024 + n4];
      int off = ((n4 >> 7) * 32 + (k >> 5)) * 4096 + ((n4 >> 4) & 7) * 512
              + ((k >> 4) & 1) * 256 + (k & 15) * 16 + (n4 & 15);
      bf16x4 sv = { (short)f2bf(wv.x), (short)f2bf(wv.y), (short)f2bf(wv.z), (short)f2bf(wv.w) };
      *(bf16x4*)&Wz[off] = sv;
    }
  }
}

// ---------------------------------------------------------------------------
// gemm_kernel (R6, frozen): m97-structure bf16 GEMM, gload_lds staging.
// ---------------------------------------------------------------------------
__global__ __launch_bounds__(256)
void gemm_kernel(const u16* __restrict__ Xb, const u16* __restrict__ Wt,
                 const float* __restrict__ b0, const float* __restrict__ b1, const float* __restrict__ b2,
                 u16* __restrict__ o0, u16* __restrict__ o1, u16* __restrict__ o2)
{
  int p  = blockIdx.x + 8 * blockIdx.y + 512 * blockIdx.z;
  int wk = (p & 7) * 192 + (p >> 3);
  int nb = wk & 7, mb = (wk >> 3) & 63, z = wk >> 9;

  const u16* Xz = Xb + (size_t)z * 8388608;
  const u16* Wz = Wt + (size_t)z * 1048576;
  const float* BS = z == 0 ? b0 : (z == 1 ? b1 : b2);
  u16*         O  = z == 0 ? o0 : (z == 1 ? o1 : o2);
  const float  osc = (z == 0) ? QK_SCALE : 1.0f;

  const int t = threadIdx.x;
  const int lane = t & 63, wid = t >> 6;
  const int g = lane >> 4, ln = lane & 15;
  const int wm = wid >> 1, wn = wid & 1;
  const int mbase = mb * 128, nbase = nb * 128;

  __shared__ __align__(16) u16 Al[128 * 32];
  __shared__ __align__(16) u16 Bl[16 * 256];

  f32x4 acc[4][4];
#pragma unroll
  for (int i = 0; i < 4; ++i)
#pragma unroll
    for (int j = 0; j < 4; ++j) { acc[i][j][0]=0.f; acc[i][j][1]=0.f; acc[i][j][2]=0.f; acc[i][j][3]=0.f; }

  const u16* sa = Xz + (size_t)(mbase + (t >> 2)) * 1024 + (t & 3) * 8;
  const u16* sb = Wz + (size_t)(nb * 32) * 4096 + t * 8;
  u16* al_w = &Al[wid * 512];
  u16* bl_w = &Bl[wid * 512];

  const unsigned bs_base = (unsigned)(size_t)&Bl[0] + (unsigned)((wn * 4) * 1024) + lane * 8;

  for (int kb = 0; kb < 32; ++kb) {
    gld16(sa + kb * 32,                 al_w);
    gld16(sa + kb * 32 + 64 * 1024,     al_w + 2048);
    gld16(sb + kb * 4096,               bl_w);
    gld16(sb + kb * 4096 + 2048,        bl_w + 2048);
    __syncthreads();

    bf16x8 af[4];
#pragma unroll
    for (int mf = 0; mf < 4; ++mf)
      af[mf] = *(const bf16x8*)&Al[(wm * 64 + mf * 16 + ln) * 32 + g * 8];

    bf16x8 bfv[4];
#pragma unroll
    for (int nf = 0; nf < 4; ++nf) {
      bf16x4 lo = ds_tr16(bs_base + (unsigned)(nf * 1024));
      bf16x4 hi = ds_tr16(bs_base + (unsigned)(nf * 1024 + 512));
      bf16x8 bb;
      bb[0]=lo[0]; bb[1]=lo[1]; bb[2]=lo[2]; bb[3]=lo[3];
      bb[4]=hi[0]; bb[5]=hi[1]; bb[6]=hi[2]; bb[7]=hi[3];
      bfv[nf] = bb;
    }
    LGKM_FENCE();
#pragma unroll
    for (int mf = 0; mf < 4; ++mf)
#pragma unroll
      for (int nf = 0; nf < 4; ++nf)
        acc[mf][nf] = __builtin_amdgcn_mfma_f32_16x16x32_bf16(af[mf], bfv[nf], acc[mf][nf], 0, 0, 0);
    __syncthreads();
  }

#pragma unroll
  for (int nf = 0; nf < 4; ++nf) {
    int n = nbase + wn * 64 + nf * 16 + ln;
    float bv = BS[n];
#pragma unroll
    for (int mf = 0; mf < 4; ++mf)
#pragma unroll
      for (int r = 0; r < 4; ++r) {
        int m = mbase + wm * 64 + mf * 16 + 4 * g + r;
        O[(size_t)m * 1024 + n] = f2bf((acc[mf][nf][r] + bv) * osc);
      }
  }
}

// ---------------------------------------------------------------------------
// Fallback proj (R5 body, frozen).
// ---------------------------------------------------------------------------
__global__ __launch_bounds__(256)
void proj_kernel(const float* __restrict__ x0, const float* __restrict__ x1, const float* __restrict__ x2,
                 const float* __restrict__ w0, const float* __restrict__ w1, const float* __restrict__ w2,
                 const float* __restrict__ b0, const float* __restrict__ b1, const float* __restrict__ b2,
                 u16* __restrict__ o0, u16* __restrict__ o1, u16* __restrict__ o2)
{
  int p  = blockIdx.x + 8 * blockIdx.y + 512 * blockIdx.z;
  int wk = (p & 7) * 192 + (p >> 3);
  int nb = wk & 7, mb = (wk >> 3) & 63, z = wk >> 9;

  const float* X  = z == 0 ? x0 : (z == 1 ? x1 : x2);
  const float* W  = z == 0 ? w0 : (z == 1 ? w1 : w2);
  const float* BS = z == 0 ? b0 : (z == 1 ? b1 : b2);
  u16*         O  = z == 0 ? o0 : (z == 1 ? o1 : o2);
  const float  osc = (z == 0) ? QK_SCALE : 1.0f;

  const int t = threadIdx.x;
  const int lane = t & 63, wid = t >> 6;
  const int g = lane >> 4, ln = lane & 15;
  const int wm = wid >> 1, wn = wid & 1;
  const int mbase = mb * 128, nbase = nb * 128;

  __shared__ __align__(16) u16 As[128 * 40];
  __shared__ __align__(16) u16 Bs[16 * 272];

  f32x4 acc[4][4];
#pragma unroll
  for (int i = 0; i < 4; ++i)
#pragma unroll
    for (int j = 0; j < 4; ++j) { acc[i][j][0]=0.f; acc[i][j][1]=0.f; acc[i][j][2]=0.f; acc[i][j][3]=0.f; }

  const int arow = t >> 3;
  const int ak0  = (t & 7) * 4;
  const int ap   = 8 * ((ak0 & 15) >> 2) + 4 * (ak0 >> 4);
  const int bkr  = t >> 5;
  const int bnc  = (t & 31) * 4;
  const int bnblk = bnc >> 4, bncl = bnc & 15;

  const unsigned bs_base = (unsigned)(size_t)&Bs[0];

  for (int kb = 0; kb < 32; ++kb) {
    const int kbase = kb * 32;
#pragma unroll
    for (int ps = 0; ps < 4; ++ps) {
      int row = arow + 32 * ps;
      const float4 xv = *(const float4*)&X[(size_t)(mbase + row) * 1024 + kbase + ak0];
      bf16x4 sv = { (short)f2bf(xv.x), (short)f2bf(xv.y), (short)f2bf(xv.z), (short)f2bf(xv.w) };
      *(bf16x4*)&As[row * 40 + ap] = sv;
    }
#pragma unroll
    for (int ps = 0; ps < 4; ++ps) {
      int kr = bkr + 8 * ps;
      const float4 wv = *(const float4*)&W[(size_t)(kbase + kr) * 1024 + nbase + bnc];
      bf16x4 sv = { (short)f2bf(wv.x), (short)f2bf(wv.y), (short)f2bf(wv.z), (short)f2bf(wv.w) };
      *(bf16x4*)&Bs[(bnblk * 2 + (kr >> 4)) * 272 + (kr & 15) * 16 + bncl] = sv;
    }
    __syncthreads();

    bf16x8 af[4];
#pragma unroll
    for (int mf = 0; mf < 4; ++mf)
      af[mf] = *(const bf16x8*)&As[(wm * 64 + mf * 16 + ln) * 40 + g * 8];

    bf16x8 bfv[4];
#pragma unroll
    for (int nf = 0; nf < 4; ++nf) {
      unsigned base = bs_base + (unsigned)(((wn * 4 + nf) * 2) * 544) + lane * 8;
      bf16x4 lo = ds_tr16(base);
      bf16x4 hi = ds_tr16(base + 544);
      bf16x8 bb;
      bb[0]=lo[0]; bb[1]=lo[1]; bb[2]=lo[2]; bb[3]=lo[3];
      bb[4]=hi[0]; bb[5]=hi[1]; bb[6]=hi[2]; bb[7]=hi[3];
      bfv[nf] = bb;
    }
    LGKM_FENCE();
#pragma unroll
    for (int mf = 0; mf < 4; ++mf)
#pragma unroll
      for (int nf = 0; nf < 4; ++nf)
        acc[mf][nf] = __builtin_amdgcn_mfma_f32_16x16x32_bf16(af[mf], bfv[nf], acc[mf][nf], 0, 0, 0);
    __syncthreads();
  }

#pragma unroll
  for (int nf = 0; nf < 4; ++nf) {
    int n = nbase + wn * 64 + nf * 16 + ln;
    float bv = BS[n];
#pragma unroll
    for (int mf = 0; mf < 4; ++mf)
#pragma unroll
      for (int r = 0; r < 4; ++r) {
        int m = mbase + wm * 64 + mf * 16 + 4 * g + r;
        O[(size_t)m * 1024 + n] = f2bf((acc[mf][nf][r] + bv) * osc);
      }
  }
}

// ---------------------------------------------------------------------------
// Attention R9: KVBLK=64 (2 sub-steps per barrier interval, 2-barrier protocol
// per interval as R6/R8); rowsum via ones-MFMA; load-early prefetch; setprio.
// ---------------------------------------------------------------------------
__global__ __launch_bounds__(256)
void attn_kernel(const u16* __restrict__ qh, const u16* __restrict__ kh, const u16* __restrict__ vh,
                 float* __restrict__ out)
{
  int p  = blockIdx.x + 16 * blockIdx.y + 256 * blockIdx.z;
  int wk = (p & 7) * 128 + (p >> 3);
  int qt = wk & 15, h = (wk >> 4) & 15, b = wk >> 8;

  const int t = threadIdx.x;
  const int lane = t & 63, wid = t >> 6;
  const int g = lane >> 4, ln = lane & 15;
  const size_t bS = (size_t)b * S_TOT;
  const int qwin = qt * 128 + wid * 32;

  __shared__ __align__(16) u16 Ks[64 * 72];    // 64 kv rows, perm row-major
  __shared__ __align__(16) u16 Vs[16 * 272];   // [dvblk4][kvblk4] tiles [16kv][16dv]

  // Q fragments (qh pre-scaled by log2e/8)
  bf16x8 qf[2][2];
#pragma unroll
  for (int nf = 0; nf < 2; ++nf) {
    const u16* qrow = &qh[(bS + qwin + nf * 16 + ln) * HD + h * 64];
#pragma unroll
    for (int kk = 0; kk < 2; ++kk) {
      bf16x4 lo = *(const bf16x4*)&qrow[kk * 32 + 4 * g];
      bf16x4 hi = *(const bf16x4*)&qrow[kk * 32 + 4 * g + 16];
      bf16x8 qq;
      qq[0]=lo[0]; qq[1]=lo[1]; qq[2]=lo[2]; qq[3]=lo[3];
      qq[4]=hi[0]; qq[5]=hi[1]; qq[6]=hi[2]; qq[7]=hi[3];
      qf[nf][kk] = qq;
    }
  }

  // ones B-fragment (bf16 1.0 in every slot) for rowsum MFMA
  bf16x8 ones;
#pragma unroll
  for (int j = 0; j < 8; ++j) ones[j] = (short)0x3F80;

  f32x4 o[2][4];
#pragma unroll
  for (int i = 0; i < 2; ++i)
#pragma unroll
    for (int j = 0; j < 4; ++j) { o[i][j][0]=0.f; o[i][j][1]=0.f; o[i][j][2]=0.f; o[i][j][3]=0.f; }
  f32x4 o1[2];
  o1[0][0]=0.f; o1[0][1]=0.f; o1[0][2]=0.f; o1[0][3]=0.f;
  o1[1][0]=0.f; o1[1][1]=0.f; o1[1][2]=0.f; o1[1][3]=0.f;

  const unsigned vs_base = (unsigned)(size_t)&Vs[0] + lane * 8;
  const int skv = t >> 4;          // 0..15; chunks at +16c
  const int sd0 = (t & 15) * 4;
  const int kpos = 32 * (sd0 >> 5) + 8 * ((sd0 & 15) >> 2) + 4 * ((sd0 >> 4) & 1);

  u16* ksw[4]; u16* vsw[4];
#pragma unroll
  for (int c = 0; c < 4; ++c) {
    ksw[c] = &Ks[(skv + 16 * c) * 72 + kpos];
    vsw[c] = &Vs[((sd0 >> 4) * 4 + c) * 272 + skv * 16 + (sd0 & 15)];
  }
  const u16* kp = &kh[(bS + skv) * HD + h * 64 + sd0];
  const u16* vp = &vh[(bS + skv) * HD + h * 64 + sd0];
  const size_t STEP64 = (size_t)64 * HD, C16 = (size_t)16 * HD;

  // prologue: interval 0 into regs
  bf16x4 kr[4], vr[4];
#pragma unroll
  for (int c = 0; c < 4; ++c) {
    kr[c] = *(const bf16x4*)(kp + c * C16);
    vr[c] = *(const bf16x4*)(vp + c * C16);
  }
  kp += STEP64; vp += STEP64;

  for (int it = 0; it < 32; ++it) {
    // stage interval it (regs -> LDS)
#pragma unroll
    for (int c = 0; c < 4; ++c) { *(bf16x4*)ksw[c] = kr[c]; *(bf16x4*)vsw[c] = vr[c]; }
    __syncthreads();                                   // barrier #1

    // issue next interval's loads — latency hides under this interval's compute
    if (it < 31) {
#pragma unroll
      for (int c = 0; c < 4; ++c) {
        kr[c] = *(const bf16x4*)(kp + c * C16);
        vr[c] = *(const bf16x4*)(vp + c * C16);
      }
      kp += STEP64; vp += STEP64;
    }

#pragma unroll
    for (int s = 0; s < 2; ++s) {
      // K fragments for kv rows [32s, 32s+32)
      bf16x8 kf[2][2];
#pragma unroll
      for (int mf = 0; mf < 2; ++mf)
#pragma unroll
        for (int kk = 0; kk < 2; ++kk)
          kf[mf][kk] = *(const bf16x8*)&Ks[(s * 32 + mf * 16 + ln) * 72 + kk * 32 + 8 * g];

      // S^T = K.Q^T
      f32x4 sc[2][2];
      __builtin_amdgcn_s_setprio(1);
#pragma unroll
      for (int mf = 0; mf < 2; ++mf)
#pragma unroll
        for (int nf = 0; nf < 2; ++nf) {
          f32x4 a; a[0]=0.f; a[1]=0.f; a[2]=0.f; a[3]=0.f;
#pragma unroll
          for (int kk = 0; kk < 2; ++kk)
            a = __builtin_amdgcn_mfma_f32_16x16x32_bf16(kf[mf][kk], qf[nf][kk], a, 0, 0, 0);
          sc[mf][nf] = a;
        }
      __builtin_amdgcn_s_setprio(0);

      // V fragments (kvblk {2s, 2s+1}) via tr-reads
      bf16x8 vf[4];
#pragma unroll
      for (int nf = 0; nf < 4; ++nf) {
        bf16x4 lo = ds_tr16(vs_base + (unsigned)((nf * 4 + 2 * s) * 544));
        bf16x4 hi = ds_tr16(vs_base + (unsigned)((nf * 4 + 2 * s + 1) * 544));
        bf16x8 bb;
        bb[0]=lo[0]; bb[1]=lo[1]; bb[2]=lo[2]; bb[3]=lo[3];
        bb[4]=hi[0]; bb[5]=hi[1]; bb[6]=hi[2]; bb[7]=hi[3];
        vf[nf] = bb;
      }

      // P = exp2(sc), pack into PV A-frags
      bf16x8 pa[2];
#pragma unroll
      for (int nf = 0; nf < 2; ++nf) {
        float pv[2][4];
#pragma unroll
        for (int mf = 0; mf < 2; ++mf)
#pragma unroll
          for (int r = 0; r < 4; ++r)
            pv[mf][r] = EXP2(sc[mf][nf][r]);
        union { u32x4 u; bf16x8 b; } pk;
        pk.u[0] = cvt_pk_bf16(pv[0][0], pv[0][1]);
        pk.u[1] = cvt_pk_bf16(pv[0][2], pv[0][3]);
        pk.u[2] = cvt_pk_bf16(pv[1][0], pv[1][1]);
        pk.u[3] = cvt_pk_bf16(pv[1][2], pv[1][3]);
        pa[nf] = pk.b;
      }

      LGKM_FENCE();
      __builtin_amdgcn_s_setprio(1);
#pragma unroll
      for (int mq = 0; mq < 2; ++mq) {
#pragma unroll
        for (int nf = 0; nf < 4; ++nf)
          o[mq][nf] = __builtin_amdgcn_mfma_f32_16x16x32_bf16(pa[mq], vf[nf], o[mq][nf], 0, 0, 0);
        o1[mq] = __builtin_amdgcn_mfma_f32_16x16x32_bf16(pa[mq], ones, o1[mq], 0, 0, 0);
      }
      __builtin_amdgcn_s_setprio(0);
    }
    __syncthreads();                                   // barrier #2
  }

  // normalize + store: rowsum for q-row (4g+r) is lane-local in o1[mq][r]
#pragma unroll
  for (int mq = 0; mq < 2; ++mq)
#pragma unroll
    for (int r = 0; r < 4; ++r) {
      float inv = 1.0f / o1[mq][r];
      int qrow = qwin + mq * 16 + 4 * g + r;
#pragma unroll
      for (int nf = 0; nf < 4; ++nf)
        out[(bS + qrow) * HD + h * 64 + nf * 16 + ln] = o[mq][nf][r] * inv;
    }
}

extern "C" void kernel_launch(void* const* d_in, const int* in_sizes, int n_in,
                              void* d_out, int out_size, void* d_ws, size_t ws_size,
                              hipStream_t stream) {
  const float* q  = (const float*)d_in[0];
  const float* k  = (const float*)d_in[1];
  const float* v  = (const float*)d_in[2];
  const float* Wq = (const float*)d_in[3];
  const float* bq = (const float*)d_in[4];
  const float* Wk = (const float*)d_in[5];
  const float* bk = (const float*)d_in[6];
  const float* Wv = (const float*)d_in[7];
  const float* bv = (const float*)d_in[8];
  float* out = (float*)d_out;

  u16* qh = (u16*)d_ws;
  u16* kh = qh + (size_t)8192 * 1024;
  u16* vh = kh + (size_t)8192 * 1024;

  const size_t XB_OFF = (size_t)3 * 8192 * 1024;
  const size_t WT_OFF = XB_OFF + (size_t)3 * 8192 * 1024;
  const size_t NEED   = (WT_OFF + (size_t)3 * 1024 * 1024) * 2;

  if (ws_size >= NEED) {
    u16* Xb = (u16*)d_ws + XB_OFF;
    u16* Wt = (u16*)d_ws + WT_OFF;
    conv_kernel<<<dim3(1152, 3), 256, 0, stream>>>(q, k, v, Wq, Wk, Wv, Xb, Wt);
    gemm_kernel<<<dim3(8, 64, 3), 256, 0, stream>>>(Xb, Wt, bq, bk, bv, qh, kh, vh);
  } else {
    proj_kernel<<<dim3(8, 64, 3), 256, 0, stream>>>(q, k, v, Wq, Wk, Wv, bq, bk, bv, qh, kh, vh);
  }
  attn_kernel<<<dim3(16, 16, 4), 256, 0, stream>>>(qh, kh, vh, out);
}

// Round 10
// 186.814 us; speedup vs baseline: 1.2101x; 1.1246x over previous
//
#include <hip/hip_runtime.h>
#include <hip/hip_bf16.h>

// MultiHeadAttention: B=4 S=2048 D=1024 H=16 DK=DV=64 scale=8
// R10: attn — 8-wave blocks (QBLK=256, grid 512, 2 blocks/CU): staged K/V tile
// serves 2x q-rows (per-thread staging + K/V HBM traffic halve), barrier events
// halve, two independent blocks per CU fill barrier/dep-chain stalls. Per-wave
// code and the proven 2-barrier protocol are UNCHANGED from R9 (KVBLK=64,
// rowsum ones-MFMA, load-early prefetch, setprio). conv/gemm/proj frozen.
// Evidence: R9 VALU drop (57->47) with flat time + occupancy 19.8% -> latency/
// sync-bound, not VALU-bound.

typedef unsigned short u16;
typedef unsigned int   u32;
typedef short bf16x8 __attribute__((ext_vector_type(8)));
typedef short bf16x4 __attribute__((ext_vector_type(4)));
typedef float f32x4  __attribute__((ext_vector_type(4)));
typedef u32   u32x4  __attribute__((ext_vector_type(4)));

#define S_TOT 2048
#define HD    1024
#define QK_SCALE 0.18033688f   // log2(e)/8

#if __has_builtin(__builtin_amdgcn_exp2f)
#define EXP2(x) __builtin_amdgcn_exp2f(x)
#else
#define EXP2(x) exp2f(x)
#endif

// branchless RNE f32->bf16
__device__ __forceinline__ u16 f2bf(float f) {
  union { float f; unsigned u; } v; v.f = f;
  unsigned r = v.u + 0x7FFFu + ((v.u >> 16) & 1u);
  return (u16)(r >> 16);
}

__device__ __forceinline__ u32 cvt_pk_bf16(float lo, float hi) {
  u32 r;
  asm("v_cvt_pk_bf16_f32 %0, %1, %2" : "=v"(r) : "v"(lo), "v"(hi));
  return r;
}

__device__ __forceinline__ bf16x4 ds_tr16(unsigned a) {
  bf16x4 d;
  asm volatile("ds_read_b64_tr_b16 %0, %1" : "=v"(d) : "v"(a) : "memory");
  return d;
}

// direct global->LDS DMA, 16B per lane
__device__ __forceinline__ void gld16(const u16* g, u16* l) {
  __builtin_amdgcn_global_load_lds(
      (const __attribute__((address_space(1))) u32*)g,
      (__attribute__((address_space(3))) u32*)l, 16, 0, 0);
}

// rule #18: inline-asm lgkmcnt needs sched_barrier(0) right after
#define LGKM_FENCE() do { asm volatile("s_waitcnt lgkmcnt(0)" ::: "memory"); \
                          __builtin_amdgcn_sched_barrier(0); } while (0)

// ---------------------------------------------------------------------------
// conv_kernel (R6, frozen): fp32 -> bf16 re-layout pass.
// ---------------------------------------------------------------------------
__global__ __launch_bounds__(256)
void conv_kernel(const float* __restrict__ x0, const float* __restrict__ x1, const float* __restrict__ x2,
                 const float* __restrict__ w0, const float* __restrict__ w1, const float* __restrict__ w2,
                 u16* __restrict__ Xb, u16* __restrict__ Wt)
{
  const int z = blockIdx.y;
  const int t = threadIdx.x;
  if (blockIdx.x < 1024) {
    const float* X = z == 0 ? x0 : (z == 1 ? x1 : x2);
    u16* Xz = Xb + (size_t)z * 8388608;
    int tid = blockIdx.x * 256 + t;
#pragma unroll
    for (int i = 0; i < 8; ++i) {
      int c = tid + i * 262144;
      int row = c >> 8, k4 = (c & 255) * 4;
      const float4 xv = *(const float4*)&X[(size_t)row * 1024 + k4];
      int p = (k4 & ~31) + 8 * ((k4 & 15) >> 2) + 4 * ((k4 >> 4) & 1);
      bf16x4 sv = { (short)f2bf(xv.x), (short)f2bf(xv.y), (short)f2bf(xv.z), (short)f2bf(xv.w) };
      *(bf16x4*)&Xz[(size_t)row * 1024 + p] = sv;
    }
  } else {
    const float* W = z == 0 ? w0 : (z == 1 ? w1 : w2);
    u16* Wz = Wt + (size_t)z * 1048576;
    int tid = (blockIdx.x - 1024) * 256 + t;
#pragma unroll
    for (int i = 0; i < 8; ++i) {
      int c = tid + i * 32768;
      int k = c >> 8, n4 = (c & 255) * 4;
      const float4 wv = *(const float4*)&W[(size_t)k * 1024 + n4];
      int off = ((n4 >> 7) * 32 + (k >> 5)) * 4096 + ((n4 >> 4) & 7) * 512
              + ((k >> 4) & 1) * 256 + (k & 15) * 16 + (n4 & 15);
      bf16x4 sv = { (short)f2bf(wv.x), (short)f2bf(wv.y), (short)f2bf(wv.z), (short)f2bf(wv.w) };
      *(bf16x4*)&Wz[off] = sv;
    }
  }
}

// ---------------------------------------------------------------------------
// gemm_kernel (R6, frozen): m97-structure bf16 GEMM, gload_lds staging.
// ---------------------------------------------------------------------------
__global__ __launch_bounds__(256)
void gemm_kernel(const u16* __restrict__ Xb, const u16* __restrict__ Wt,
                 const float* __restrict__ b0, const float* __restrict__ b1, const float* __restrict__ b2,
                 u16* __restrict__ o0, u16* __restrict__ o1, u16* __restrict__ o2)
{
  int p  = blockIdx.x + 8 * blockIdx.y + 512 * blockIdx.z;
  int wk = (p & 7) * 192 + (p >> 3);
  int nb = wk & 7, mb = (wk >> 3) & 63, z = wk >> 9;

  const u16* Xz = Xb + (size_t)z * 8388608;
  const u16* Wz = Wt + (size_t)z * 1048576;
  const float* BS = z == 0 ? b0 : (z == 1 ? b1 : b2);
  u16*         O  = z == 0 ? o0 : (z == 1 ? o1 : o2);
  const float  osc = (z == 0) ? QK_SCALE : 1.0f;

  const int t = threadIdx.x;
  const int lane = t & 63, wid = t >> 6;
  const int g = lane >> 4, ln = lane & 15;
  const int wm = wid >> 1, wn = wid & 1;
  const int mbase = mb * 128, nbase = nb * 128;

  __shared__ __align__(16) u16 Al[128 * 32];
  __shared__ __align__(16) u16 Bl[16 * 256];

  f32x4 acc[4][4];
#pragma unroll
  for (int i = 0; i < 4; ++i)
#pragma unroll
    for (int j = 0; j < 4; ++j) { acc[i][j][0]=0.f; acc[i][j][1]=0.f; acc[i][j][2]=0.f; acc[i][j][3]=0.f; }

  const u16* sa = Xz + (size_t)(mbase + (t >> 2)) * 1024 + (t & 3) * 8;
  const u16* sb = Wz + (size_t)(nb * 32) * 4096 + t * 8;
  u16* al_w = &Al[wid * 512];
  u16* bl_w = &Bl[wid * 512];

  const unsigned bs_base = (unsigned)(size_t)&Bl[0] + (unsigned)((wn * 4) * 1024) + lane * 8;

  for (int kb = 0; kb < 32; ++kb) {
    gld16(sa + kb * 32,                 al_w);
    gld16(sa + kb * 32 + 64 * 1024,     al_w + 2048);
    gld16(sb + kb * 4096,               bl_w);
    gld16(sb + kb * 4096 + 2048,        bl_w + 2048);
    __syncthreads();

    bf16x8 af[4];
#pragma unroll
    for (int mf = 0; mf < 4; ++mf)
      af[mf] = *(const bf16x8*)&Al[(wm * 64 + mf * 16 + ln) * 32 + g * 8];

    bf16x8 bfv[4];
#pragma unroll
    for (int nf = 0; nf < 4; ++nf) {
      bf16x4 lo = ds_tr16(bs_base + (unsigned)(nf * 1024));
      bf16x4 hi = ds_tr16(bs_base + (unsigned)(nf * 1024 + 512));
      bf16x8 bb;
      bb[0]=lo[0]; bb[1]=lo[1]; bb[2]=lo[2]; bb[3]=lo[3];
      bb[4]=hi[0]; bb[5]=hi[1]; bb[6]=hi[2]; bb[7]=hi[3];
      bfv[nf] = bb;
    }
    LGKM_FENCE();
#pragma unroll
    for (int mf = 0; mf < 4; ++mf)
#pragma unroll
      for (int nf = 0; nf < 4; ++nf)
        acc[mf][nf] = __builtin_amdgcn_mfma_f32_16x16x32_bf16(af[mf], bfv[nf], acc[mf][nf], 0, 0, 0);
    __syncthreads();
  }

#pragma unroll
  for (int nf = 0; nf < 4; ++nf) {
    int n = nbase + wn * 64 + nf * 16 + ln;
    float bv = BS[n];
#pragma unroll
    for (int mf = 0; mf < 4; ++mf)
#pragma unroll
      for (int r = 0; r < 4; ++r) {
        int m = mbase + wm * 64 + mf * 16 + 4 * g + r;
        O[(size_t)m * 1024 + n] = f2bf((acc[mf][nf][r] + bv) * osc);
      }
  }
}

// ---------------------------------------------------------------------------
// Fallback proj (R5 body, frozen).
// ---------------------------------------------------------------------------
__global__ __launch_bounds__(256)
void proj_kernel(const float* __restrict__ x0, const float* __restrict__ x1, const float* __restrict__ x2,
                 const float* __restrict__ w0, const float* __restrict__ w1, const float* __restrict__ w2,
                 const float* __restrict__ b0, const float* __restrict__ b1, const float* __restrict__ b2,
                 u16* __restrict__ o0, u16* __restrict__ o1, u16* __restrict__ o2)
{
  int p  = blockIdx.x + 8 * blockIdx.y + 512 * blockIdx.z;
  int wk = (p & 7) * 192 + (p >> 3);
  int nb = wk & 7, mb = (wk >> 3) & 63, z = wk >> 9;

  const float* X  = z == 0 ? x0 : (z == 1 ? x1 : x2);
  const float* W  = z == 0 ? w0 : (z == 1 ? w1 : w2);
  const float* BS = z == 0 ? b0 : (z == 1 ? b1 : b2);
  u16*         O  = z == 0 ? o0 : (z == 1 ? o1 : o2);
  const float  osc = (z == 0) ? QK_SCALE : 1.0f;

  const int t = threadIdx.x;
  const int lane = t & 63, wid = t >> 6;
  const int g = lane >> 4, ln = lane & 15;
  const int wm = wid >> 1, wn = wid & 1;
  const int mbase = mb * 128, nbase = nb * 128;

  __shared__ __align__(16) u16 As[128 * 40];
  __shared__ __align__(16) u16 Bs[16 * 272];

  f32x4 acc[4][4];
#pragma unroll
  for (int i = 0; i < 4; ++i)
#pragma unroll
    for (int j = 0; j < 4; ++j) { acc[i][j][0]=0.f; acc[i][j][1]=0.f; acc[i][j][2]=0.f; acc[i][j][3]=0.f; }

  const int arow = t >> 3;
  const int ak0  = (t & 7) * 4;
  const int ap   = 8 * ((ak0 & 15) >> 2) + 4 * (ak0 >> 4);
  const int bkr  = t >> 5;
  const int bnc  = (t & 31) * 4;
  const int bnblk = bnc >> 4, bncl = bnc & 15;

  const unsigned bs_base = (unsigned)(size_t)&Bs[0];

  for (int kb = 0; kb < 32; ++kb) {
    const int kbase = kb * 32;
#pragma unroll
    for (int ps = 0; ps < 4; ++ps) {
      int row = arow + 32 * ps;
      const float4 xv = *(const float4*)&X[(size_t)(mbase + row) * 1024 + kbase + ak0];
      bf16x4 sv = { (short)f2bf(xv.x), (short)f2bf(xv.y), (short)f2bf(xv.z), (short)f2bf(xv.w) };
      *(bf16x4*)&As[row * 40 + ap] = sv;
    }
#pragma unroll
    for (int ps = 0; ps < 4; ++ps) {
      int kr = bkr + 8 * ps;
      const float4 wv = *(const float4*)&W[(size_t)(kbase + kr) * 1024 + nbase + bnc];
      bf16x4 sv = { (short)f2bf(wv.x), (short)f2bf(wv.y), (short)f2bf(wv.z), (short)f2bf(wv.w) };
      *(bf16x4*)&Bs[(bnblk * 2 + (kr >> 4)) * 272 + (kr & 15) * 16 + bncl] = sv;
    }
    __syncthreads();

    bf16x8 af[4];
#pragma unroll
    for (int mf = 0; mf < 4; ++mf)
      af[mf] = *(const bf16x8*)&As[(wm * 64 + mf * 16 + ln) * 40 + g * 8];

    bf16x8 bfv[4];
#pragma unroll
    for (int nf = 0; nf < 4; ++nf) {
      unsigned base = bs_base + (unsigned)(((wn * 4 + nf) * 2) * 544) + lane * 8;
      bf16x4 lo = ds_tr16(base);
      bf16x4 hi = ds_tr16(base + 544);
      bf16x8 bb;
      bb[0]=lo[0]; bb[1]=lo[1]; bb[2]=lo[2]; bb[3]=lo[3];
      bb[4]=hi[0]; bb[5]=hi[1]; bb[6]=hi[2]; bb[7]=hi[3];
      bfv[nf] = bb;
    }
    LGKM_FENCE();
#pragma unroll
    for (int mf = 0; mf < 4; ++mf)
#pragma unroll
      for (int nf = 0; nf < 4; ++nf)
        acc[mf][nf] = __builtin_amdgcn_mfma_f32_16x16x32_bf16(af[mf], bfv[nf], acc[mf][nf], 0, 0, 0);
    __syncthreads();
  }

#pragma unroll
  for (int nf = 0; nf < 4; ++nf) {
    int n = nbase + wn * 64 + nf * 16 + ln;
    float bv = BS[n];
#pragma unroll
    for (int mf = 0; mf < 4; ++mf)
#pragma unroll
      for (int r = 0; r < 4; ++r) {
        int m = mbase + wm * 64 + mf * 16 + 4 * g + r;
        O[(size_t)m * 1024 + n] = f2bf((acc[mf][nf][r] + bv) * osc);
      }
  }
}

// ---------------------------------------------------------------------------
// Attention R10: 8 waves x 32 q-rows (QBLK=256), KVBLK=64 (2 sub-steps per
// barrier interval, 2-barrier protocol), rowsum ones-MFMA, load-early, setprio.
// ---------------------------------------------------------------------------
__global__ __launch_bounds__(512)
void attn_kernel(const u16* __restrict__ qh, const u16* __restrict__ kh, const u16* __restrict__ vh,
                 float* __restrict__ out)
{
  // bijective XCD swizzle (nwg=512): 64 contiguous work ids per XCD
  int p  = blockIdx.x + 8 * blockIdx.y + 128 * blockIdx.z;
  int wk = (p & 7) * 64 + (p >> 3);
  int qt = wk & 7, h = (wk >> 3) & 15, b = wk >> 7;

  const int t = threadIdx.x;
  const int lane = t & 63, wid = t >> 6;
  const int g = lane >> 4, ln = lane & 15;
  const size_t bS = (size_t)b * S_TOT;
  const int qwin = qt * 256 + wid * 32;

  __shared__ __align__(16) u16 Ks[64 * 72];    // 64 kv rows, perm row-major
  __shared__ __align__(16) u16 Vs[16 * 272];   // [dvblk4][kvblk4] tiles [16kv][16dv]

  // Q fragments (qh pre-scaled by log2e/8)
  bf16x8 qf[2][2];
#pragma unroll
  for (int nf = 0; nf < 2; ++nf) {
    const u16* qrow = &qh[(bS + qwin + nf * 16 + ln) * HD + h * 64];
#pragma unroll
    for (int kk = 0; kk < 2; ++kk) {
      bf16x4 lo = *(const bf16x4*)&qrow[kk * 32 + 4 * g];
      bf16x4 hi = *(const bf16x4*)&qrow[kk * 32 + 4 * g + 16];
      bf16x8 qq;
      qq[0]=lo[0]; qq[1]=lo[1]; qq[2]=lo[2]; qq[3]=lo[3];
      qq[4]=hi[0]; qq[5]=hi[1]; qq[6]=hi[2]; qq[7]=hi[3];
      qf[nf][kk] = qq;
    }
  }

  // ones B-fragment for rowsum MFMA
  bf16x8 ones;
#pragma unroll
  for (int j = 0; j < 8; ++j) ones[j] = (short)0x3F80;

  f32x4 o[2][4];
#pragma unroll
  for (int i = 0; i < 2; ++i)
#pragma unroll
    for (int j = 0; j < 4; ++j) { o[i][j][0]=0.f; o[i][j][1]=0.f; o[i][j][2]=0.f; o[i][j][3]=0.f; }
  f32x4 o1[2];
  o1[0][0]=0.f; o1[0][1]=0.f; o1[0][2]=0.f; o1[0][3]=0.f;
  o1[1][0]=0.f; o1[1][1]=0.f; o1[1][2]=0.f; o1[1][3]=0.f;

  const unsigned vs_base = (unsigned)(size_t)&Vs[0] + lane * 8;
  // staging: 512 threads cover 64 kv rows x 64 d; each thread 2 K + 2 V b64
  const int skv = t >> 4;          // 0..31; second chunk at +32
  const int sd0 = (t & 15) * 4;
  const int kpos = 32 * (sd0 >> 5) + 8 * ((sd0 & 15) >> 2) + 4 * ((sd0 >> 4) & 1);

  u16* ksw[2]; u16* vsw[2];
#pragma unroll
  for (int c = 0; c < 2; ++c) {
    ksw[c] = &Ks[(skv + 32 * c) * 72 + kpos];
    vsw[c] = &Vs[((sd0 >> 4) * 4 + (skv >> 4) + 2 * c) * 272 + (skv & 15) * 16 + (sd0 & 15)];
  }
  const u16* kp = &kh[(bS + skv) * HD + h * 64 + sd0];
  const u16* vp = &vh[(bS + skv) * HD + h * 64 + sd0];
  const size_t STEP64 = (size_t)64 * HD, C32 = (size_t)32 * HD;

  // prologue: interval 0 into regs
  bf16x4 kr[2], vr[2];
#pragma unroll
  for (int c = 0; c < 2; ++c) {
    kr[c] = *(const bf16x4*)(kp + c * C32);
    vr[c] = *(const bf16x4*)(vp + c * C32);
  }
  kp += STEP64; vp += STEP64;

  for (int it = 0; it < 32; ++it) {
    // stage interval it (regs -> LDS)
#pragma unroll
    for (int c = 0; c < 2; ++c) { *(bf16x4*)ksw[c] = kr[c]; *(bf16x4*)vsw[c] = vr[c]; }
    __syncthreads();                                   // barrier #1

    // issue next interval's loads — latency hides under this interval's compute
    if (it < 31) {
#pragma unroll
      for (int c = 0; c < 2; ++c) {
        kr[c] = *(const bf16x4*)(kp + c * C32);
        vr[c] = *(const bf16x4*)(vp + c * C32);
      }
      kp += STEP64; vp += STEP64;
    }

#pragma unroll
    for (int s = 0; s < 2; ++s) {
      // K fragments for kv rows [32s, 32s+32)
      bf16x8 kf[2][2];
#pragma unroll
      for (int mf = 0; mf < 2; ++mf)
#pragma unroll
        for (int kk = 0; kk < 2; ++kk)
          kf[mf][kk] = *(const bf16x8*)&Ks[(s * 32 + mf * 16 + ln) * 72 + kk * 32 + 8 * g];

      // S^T = K.Q^T
      f32x4 sc[2][2];
      __builtin_amdgcn_s_setprio(1);
#pragma unroll
      for (int mf = 0; mf < 2; ++mf)
#pragma unroll
        for (int nf = 0; nf < 2; ++nf) {
          f32x4 a; a[0]=0.f; a[1]=0.f; a[2]=0.f; a[3]=0.f;
#pragma unroll
          for (int kk = 0; kk < 2; ++kk)
            a = __builtin_amdgcn_mfma_f32_16x16x32_bf16(kf[mf][kk], qf[nf][kk], a, 0, 0, 0);
          sc[mf][nf] = a;
        }
      __builtin_amdgcn_s_setprio(0);

      // V fragments (kvblk {2s, 2s+1}) via tr-reads
      bf16x8 vf[4];
#pragma unroll
      for (int nf = 0; nf < 4; ++nf) {
        bf16x4 lo = ds_tr16(vs_base + (unsigned)((nf * 4 + 2 * s) * 544));
        bf16x4 hi = ds_tr16(vs_base + (unsigned)((nf * 4 + 2 * s + 1) * 544));
        bf16x8 bb;
        bb[0]=lo[0]; bb[1]=lo[1]; bb[2]=lo[2]; bb[3]=lo[3];
        bb[4]=hi[0]; bb[5]=hi[1]; bb[6]=hi[2]; bb[7]=hi[3];
        vf[nf] = bb;
      }

      // P = exp2(sc), pack into PV A-frags
      bf16x8 pa[2];
#pragma unroll
      for (int nf = 0; nf < 2; ++nf) {
        float pv[2][4];
#pragma unroll
        for (int mf = 0; mf < 2; ++mf)
#pragma unroll
          for (int r = 0; r < 4; ++r)
            pv[mf][r] = EXP2(sc[mf][nf][r]);
        union { u32x4 u; bf16x8 b; } pk;
        pk.u[0] = cvt_pk_bf16(pv[0][0], pv[0][1]);
        pk.u[1] = cvt_pk_bf16(pv[0][2], pv[0][3]);
        pk.u[2] = cvt_pk_bf16(pv[1][0], pv[1][1]);
        pk.u[3] = cvt_pk_bf16(pv[1][2], pv[1][3]);
        pa[nf] = pk.b;
      }

      LGKM_FENCE();
      __builtin_amdgcn_s_setprio(1);
#pragma unroll
      for (int mq = 0; mq < 2; ++mq) {
#pragma unroll
        for (int nf = 0; nf < 4; ++nf)
          o[mq][nf] = __builtin_amdgcn_mfma_f32_16x16x32_bf16(pa[mq], vf[nf], o[mq][nf], 0, 0, 0);
        o1[mq] = __builtin_amdgcn_mfma_f32_16x16x32_bf16(pa[mq], ones, o1[mq], 0, 0, 0);
      }
      __builtin_amdgcn_s_setprio(0);
    }
    __syncthreads();                                   // barrier #2
  }

  // normalize + store: rowsum for q-row (4g+r) is lane-local in o1[mq][r]
#pragma unroll
  for (int mq = 0; mq < 2; ++mq)
#pragma unroll
    for (int r = 0; r < 4; ++r) {
      float inv = 1.0f / o1[mq][r];
      int qrow = qwin + mq * 16 + 4 * g + r;
#pragma unroll
      for (int nf = 0; nf < 4; ++nf)
        out[(bS + qrow) * HD + h * 64 + nf * 16 + ln] = o[mq][nf][r] * inv;
    }
}

extern "C" void kernel_launch(void* const* d_in, const int* in_sizes, int n_in,
                              void* d_out, int out_size, void* d_ws, size_t ws_size,
                              hipStream_t stream) {
  const float* q  = (const float*)d_in[0];
  const float* k  = (const float*)d_in[1];
  const float* v  = (const float*)d_in[2];
  const float* Wq = (const float*)d_in[3];
  const float* bq = (const float*)d_in[4];
  const float* Wk = (const float*)d_in[5];
  const float* bk = (const float*)d_in[6];
  const float* Wv = (const float*)d_in[7];
  const float* bv = (const float*)d_in[8];
  float* out = (float*)d_out;

  u16* qh = (u16*)d_ws;
  u16* kh = qh + (size_t)8192 * 1024;
  u16* vh = kh + (size_t)8192 * 1024;

  const size_t XB_OFF = (size_t)3 * 8192 * 1024;
  const size_t WT_OFF = XB_OFF + (size_t)3 * 8192 * 1024;
  const size_t NEED   = (WT_OFF + (size_t)3 * 1024 * 1024) * 2;

  if (ws_size >= NEED) {
    u16* Xb = (u16*)d_ws + XB_OFF;
    u16* Wt = (u16*)d_ws + WT_OFF;
    conv_kernel<<<dim3(1152, 3), 256, 0, stream>>>(q, k, v, Wq, Wk, Wv, Xb, Wt);
    gemm_kernel<<<dim3(8, 64, 3), 256, 0, stream>>>(Xb, Wt, bq, bk, bv, qh, kh, vh);
  } else {
    proj_kernel<<<dim3(8, 64, 3), 256, 0, stream>>>(q, k, v, Wq, Wk, Wv, bq, bk, bv, qh, kh, vh);
  }
  attn_kernel<<<dim3(8, 16, 4), 512, 0, stream>>>(qh, kh, vh, out);
}

// Round 11
// 178.621 us; speedup vs baseline: 1.2656x; 1.0459x over previous
//
#include <hip/hip_runtime.h>
#include <hip/hip_bf16.h>

// MultiHeadAttention: B=4 S=2048 D=1024 H=16 DK=DV=64 scale=8
// R11: remove attn's per-substep scheduling fence (rule #18 cost) by removing
// its only asm: V is produced TRANSPOSED by gemm z=2 (operand-swapped MFMA ->
// C lane axis = seq -> coalesced vT[b,h][dv][seq] stores). attn stages V^T
// rows (stride-72, like Ks) and reads V-frags with plain ds_read_b128 ->
// compiler emits counted lgkmcnt, substeps pipeline. conv frozen; gemm z01
// frozen; attn otherwise frozen (8w/QBLK256/KVBLK64/2-barrier/ones-MFMA).

typedef unsigned short u16;
typedef unsigned int   u32;
typedef short bf16x8 __attribute__((ext_vector_type(8)));
typedef short bf16x4 __attribute__((ext_vector_type(4)));
typedef float f32x4  __attribute__((ext_vector_type(4)));
typedef u32   u32x4  __attribute__((ext_vector_type(4)));

#define S_TOT 2048
#define HD    1024
#define QK_SCALE 0.18033688f   // log2(e)/8

#if __has_builtin(__builtin_amdgcn_exp2f)
#define EXP2(x) __builtin_amdgcn_exp2f(x)
#else
#define EXP2(x) exp2f(x)
#endif

__device__ __forceinline__ u16 f2bf(float f) {
  union { float f; unsigned u; } v; v.f = f;
  unsigned r = v.u + 0x7FFFu + ((v.u >> 16) & 1u);
  return (u16)(r >> 16);
}

__device__ __forceinline__ u32 cvt_pk_bf16(float lo, float hi) {
  u32 r;
  asm("v_cvt_pk_bf16_f32 %0, %1, %2" : "=v"(r) : "v"(lo), "v"(hi));
  return r;
}

__device__ __forceinline__ bf16x4 ds_tr16(unsigned a) {
  bf16x4 d;
  asm volatile("ds_read_b64_tr_b16 %0, %1" : "=v"(d) : "v"(a) : "memory");
  return d;
}

__device__ __forceinline__ void gld16(const u16* g, u16* l) {
  __builtin_amdgcn_global_load_lds(
      (const __attribute__((address_space(1))) u32*)g,
      (__attribute__((address_space(3))) u32*)l, 16, 0, 0);
}

// rule #18: inline-asm lgkmcnt needs sched_barrier(0) right after (gemm only)
#define LGKM_FENCE() do { asm volatile("s_waitcnt lgkmcnt(0)" ::: "memory"); \
                          __builtin_amdgcn_sched_barrier(0); } while (0)

// ---------------------------------------------------------------------------
// conv_kernel (frozen): fp32 -> bf16 re-layout (Xb row-perm; Wt k-major tiles).
// ---------------------------------------------------------------------------
__global__ __launch_bounds__(256)
void conv_kernel(const float* __restrict__ x0, const float* __restrict__ x1, const float* __restrict__ x2,
                 const float* __restrict__ w0, const float* __restrict__ w1, const float* __restrict__ w2,
                 u16* __restrict__ Xb, u16* __restrict__ Wt)
{
  const int z = blockIdx.y;
  const int t = threadIdx.x;
  if (blockIdx.x < 1024) {
    const float* X = z == 0 ? x0 : (z == 1 ? x1 : x2);
    u16* Xz = Xb + (size_t)z * 8388608;
    int tid = blockIdx.x * 256 + t;
#pragma unroll
    for (int i = 0; i < 8; ++i) {
      int c = tid + i * 262144;
      int row = c >> 8, k4 = (c & 255) * 4;
      const float4 xv = *(const float4*)&X[(size_t)row * 1024 + k4];
      int p = (k4 & ~31) + 8 * ((k4 & 15) >> 2) + 4 * ((k4 >> 4) & 1);
      bf16x4 sv = { (short)f2bf(xv.x), (short)f2bf(xv.y), (short)f2bf(xv.z), (short)f2bf(xv.w) };
      *(bf16x4*)&Xz[(size_t)row * 1024 + p] = sv;
    }
  } else {
    const float* W = z == 0 ? w0 : (z == 1 ? w1 : w2);
    u16* Wz = Wt + (size_t)z * 1048576;
    int tid = (blockIdx.x - 1024) * 256 + t;
#pragma unroll
    for (int i = 0; i < 8; ++i) {
      int c = tid + i * 32768;
      int k = c >> 8, n4 = (c & 255) * 4;
      const float4 wv = *(const float4*)&W[(size_t)k * 1024 + n4];
      int off = ((n4 >> 7) * 32 + (k >> 5)) * 4096 + ((n4 >> 4) & 7) * 512
              + ((k >> 4) & 1) * 256 + (k & 15) * 16 + (n4 & 15);
      bf16x4 sv = { (short)f2bf(wv.x), (short)f2bf(wv.y), (short)f2bf(wv.z), (short)f2bf(wv.w) };
      *(bf16x4*)&Wz[off] = sv;
    }
  }
}

// ---------------------------------------------------------------------------
// gemm_kernel: z in {0,1}: natural out (qh, kh). z==2: operand-swapped MFMA,
// writes vT[((b*16+h)*64+dv)*2048 + seq] (coalesced in seq).
// ---------------------------------------------------------------------------
__global__ __launch_bounds__(256)
void gemm_kernel(const u16* __restrict__ Xb, const u16* __restrict__ Wt,
                 const float* __restrict__ b0, const float* __restrict__ b1, const float* __restrict__ b2,
                 u16* __restrict__ o0, u16* __restrict__ o1, u16* __restrict__ vT)
{
  int p  = blockIdx.x + 8 * blockIdx.y + 512 * blockIdx.z;
  int wk = (p & 7) * 192 + (p >> 3);
  int nb = wk & 7, mb = (wk >> 3) & 63, z = wk >> 9;

  const u16* Xz = Xb + (size_t)z * 8388608;
  const u16* Wz = Wt + (size_t)z * 1048576;
  const float* BS = z == 0 ? b0 : (z == 1 ? b1 : b2);
  const float  osc = (z == 0) ? QK_SCALE : 1.0f;

  const int t = threadIdx.x;
  const int lane = t & 63, wid = t >> 6;
  const int g = lane >> 4, ln = lane & 15;
  const int mbase = mb * 128, nbase = nb * 128;

  __shared__ __align__(16) u16 Al[128 * 32];
  __shared__ __align__(16) u16 Bl[16 * 256];

  f32x4 acc[4][4];
#pragma unroll
  for (int i = 0; i < 4; ++i)
#pragma unroll
    for (int j = 0; j < 4; ++j) { acc[i][j][0]=0.f; acc[i][j][1]=0.f; acc[i][j][2]=0.f; acc[i][j][3]=0.f; }

  const u16* sa = Xz + (size_t)(mbase + (t >> 2)) * 1024 + (t & 3) * 8;
  const u16* sb = Wz + (size_t)(nb * 32) * 4096 + t * 8;
  u16* al_w = &Al[wid * 512];
  u16* bl_w = &Bl[wid * 512];

  if (z < 2) {
    const int wm = wid >> 1, wn = wid & 1;
    u16* O = z == 0 ? o0 : o1;
    const unsigned bs_base = (unsigned)(size_t)&Bl[0] + (unsigned)((wn * 4) * 1024) + lane * 8;

    for (int kb = 0; kb < 32; ++kb) {
      gld16(sa + kb * 32,                 al_w);
      gld16(sa + kb * 32 + 64 * 1024,     al_w + 2048);
      gld16(sb + kb * 4096,               bl_w);
      gld16(sb + kb * 4096 + 2048,        bl_w + 2048);
      __syncthreads();

      bf16x8 af[4];
#pragma unroll
      for (int mf = 0; mf < 4; ++mf)
        af[mf] = *(const bf16x8*)&Al[(wm * 64 + mf * 16 + ln) * 32 + g * 8];

      bf16x8 bfv[4];
#pragma unroll
      for (int nf = 0; nf < 4; ++nf) {
        bf16x4 lo = ds_tr16(bs_base + (unsigned)(nf * 1024));
        bf16x4 hi = ds_tr16(bs_base + (unsigned)(nf * 1024 + 512));
        bf16x8 bb;
        bb[0]=lo[0]; bb[1]=lo[1]; bb[2]=lo[2]; bb[3]=lo[3];
        bb[4]=hi[0]; bb[5]=hi[1]; bb[6]=hi[2]; bb[7]=hi[3];
        bfv[nf] = bb;
      }
      LGKM_FENCE();
#pragma unroll
      for (int mf = 0; mf < 4; ++mf)
#pragma unroll
        for (int nf = 0; nf < 4; ++nf)
          acc[mf][nf] = __builtin_amdgcn_mfma_f32_16x16x32_bf16(af[mf], bfv[nf], acc[mf][nf], 0, 0, 0);
      __syncthreads();
    }

#pragma unroll
    for (int nf = 0; nf < 4; ++nf) {
      int n = nbase + wn * 64 + nf * 16 + ln;
      float bv = BS[n];
#pragma unroll
      for (int mf = 0; mf < 4; ++mf)
#pragma unroll
        for (int r = 0; r < 4; ++r) {
          int m = mbase + wm * 64 + mf * 16 + 4 * g + r;
          O[(size_t)m * 1024 + n] = f2bf((acc[mf][nf][r] + bv) * osc);
        }
    }
  } else {
    // z==2 swapped: A = W-frag (tr from Bl), B = X-frag (b128 from Al).
    // C: row = dv (4g+r within frag), col = seq (ln) -> transposed store.
    const int wseq = wid >> 1, wdv = wid & 1;
    const unsigned bs_base2 = (unsigned)(size_t)&Bl[0] + (unsigned)((wdv * 4) * 1024) + lane * 8;

    for (int kb = 0; kb < 32; ++kb) {
      gld16(sa + kb * 32,                 al_w);
      gld16(sa + kb * 32 + 64 * 1024,     al_w + 2048);
      gld16(sb + kb * 4096,               bl_w);
      gld16(sb + kb * 4096 + 2048,        bl_w + 2048);
      __syncthreads();

      bf16x8 afw[4];                       // A: lane=dv, elems=k (tr-read)
#pragma unroll
      for (int mf = 0; mf < 4; ++mf) {
        bf16x4 lo = ds_tr16(bs_base2 + (unsigned)(mf * 1024));
        bf16x4 hi = ds_tr16(bs_base2 + (unsigned)(mf * 1024 + 512));
        bf16x8 bb;
        bb[0]=lo[0]; bb[1]=lo[1]; bb[2]=lo[2]; bb[3]=lo[3];
        bb[4]=hi[0]; bb[5]=hi[1]; bb[6]=hi[2]; bb[7]=hi[3];
        afw[mf] = bb;
      }
      bf16x8 bfx[4];                       // B: lane=seq, elems=k (b128)
#pragma unroll
      for (int nf = 0; nf < 4; ++nf)
        bfx[nf] = *(const bf16x8*)&Al[(wseq * 64 + nf * 16 + ln) * 32 + g * 8];
      LGKM_FENCE();
#pragma unroll
      for (int mf = 0; mf < 4; ++mf)
#pragma unroll
        for (int nf = 0; nf < 4; ++nf)
          acc[mf][nf] = __builtin_amdgcn_mfma_f32_16x16x32_bf16(afw[mf], bfx[nf], acc[mf][nf], 0, 0, 0);
      __syncthreads();
    }

#pragma unroll
    for (int mf = 0; mf < 4; ++mf)
#pragma unroll
      for (int r = 0; r < 4; ++r) {
        int dvg = nbase + wdv * 64 + mf * 16 + 4 * g + r;   // original n
        float bv = BS[dvg];
        int hh = dvg >> 6, dvl = dvg & 63;
#pragma unroll
        for (int nf = 0; nf < 4; ++nf) {
          int m = mbase + wseq * 64 + nf * 16 + ln;         // original m
          int bb = m >> 11, ss = m & 2047;
          vT[((size_t)(bb * 16 + hh) * 64 + dvl) * 2048 + ss] = f2bf(acc[mf][nf][r] + bv);
        }
      }
  }
}

// ---------------------------------------------------------------------------
// Fallback proj (R5 body + z==2 transposed scatter epilogue; unused when ws ok).
// ---------------------------------------------------------------------------
__global__ __launch_bounds__(256)
void proj_kernel(const float* __restrict__ x0, const float* __restrict__ x1, const float* __restrict__ x2,
                 const float* __restrict__ w0, const float* __restrict__ w1, const float* __restrict__ w2,
                 const float* __restrict__ b0, const float* __restrict__ b1, const float* __restrict__ b2,
                 u16* __restrict__ o0, u16* __restrict__ o1, u16* __restrict__ vT)
{
  int p  = blockIdx.x + 8 * blockIdx.y + 512 * blockIdx.z;
  int wk = (p & 7) * 192 + (p >> 3);
  int nb = wk & 7, mb = (wk >> 3) & 63, z = wk >> 9;

  const float* X  = z == 0 ? x0 : (z == 1 ? x1 : x2);
  const float* W  = z == 0 ? w0 : (z == 1 ? w1 : w2);
  const float* BS = z == 0 ? b0 : (z == 1 ? b1 : b2);
  const float  osc = (z == 0) ? QK_SCALE : 1.0f;

  const int t = threadIdx.x;
  const int lane = t & 63, wid = t >> 6;
  const int g = lane >> 4, ln = lane & 15;
  const int wm = wid >> 1, wn = wid & 1;
  const int mbase = mb * 128, nbase = nb * 128;

  __shared__ __align__(16) u16 As[128 * 40];
  __shared__ __align__(16) u16 Bs[16 * 272];

  f32x4 acc[4][4];
#pragma unroll
  for (int i = 0; i < 4; ++i)
#pragma unroll
    for (int j = 0; j < 4; ++j) { acc[i][j][0]=0.f; acc[i][j][1]=0.f; acc[i][j][2]=0.f; acc[i][j][3]=0.f; }

  const int arow = t >> 3;
  const int ak0  = (t & 7) * 4;
  const int ap   = 8 * ((ak0 & 15) >> 2) + 4 * (ak0 >> 4);
  const int bkr  = t >> 5;
  const int bnc  = (t & 31) * 4;
  const int bnblk = bnc >> 4, bncl = bnc & 15;

  const unsigned bs_base = (unsigned)(size_t)&Bs[0];

  for (int kb = 0; kb < 32; ++kb) {
    const int kbase = kb * 32;
#pragma unroll
    for (int ps = 0; ps < 4; ++ps) {
      int row = arow + 32 * ps;
      const float4 xv = *(const float4*)&X[(size_t)(mbase + row) * 1024 + kbase + ak0];
      bf16x4 sv = { (short)f2bf(xv.x), (short)f2bf(xv.y), (short)f2bf(xv.z), (short)f2bf(xv.w) };
      *(bf16x4*)&As[row * 40 + ap] = sv;
    }
#pragma unroll
    for (int ps = 0; ps < 4; ++ps) {
      int kr = bkr + 8 * ps;
      const float4 wv = *(const float4*)&W[(size_t)(kbase + kr) * 1024 + nbase + bnc];
      bf16x4 sv = { (short)f2bf(wv.x), (short)f2bf(wv.y), (short)f2bf(wv.z), (short)f2bf(wv.w) };
      *(bf16x4*)&Bs[(bnblk * 2 + (kr >> 4)) * 272 + (kr & 15) * 16 + bncl] = sv;
    }
    __syncthreads();

    bf16x8 af[4];
#pragma unroll
    for (int mf = 0; mf < 4; ++mf)
      af[mf] = *(const bf16x8*)&As[(wm * 64 + mf * 16 + ln) * 40 + g * 8];

    bf16x8 bfv[4];
#pragma unroll
    for (int nf = 0; nf < 4; ++nf) {
      unsigned base = bs_base + (unsigned)(((wn * 4 + nf) * 2) * 544) + lane * 8;
      bf16x4 lo = ds_tr16(base);
      bf16x4 hi = ds_tr16(base + 544);
      bf16x8 bb;
      bb[0]=lo[0]; bb[1]=lo[1]; bb[2]=lo[2]; bb[3]=lo[3];
      bb[4]=hi[0]; bb[5]=hi[1]; bb[6]=hi[2]; bb[7]=hi[3];
      bfv[nf] = bb;
    }
    LGKM_FENCE();
#pragma unroll
    for (int mf = 0; mf < 4; ++mf)
#pragma unroll
      for (int nf = 0; nf < 4; ++nf)
        acc[mf][nf] = __builtin_amdgcn_mfma_f32_16x16x32_bf16(af[mf], bfv[nf], acc[mf][nf], 0, 0, 0);
    __syncthreads();
  }

#pragma unroll
  for (int nf = 0; nf < 4; ++nf) {
    int n = nbase + wn * 64 + nf * 16 + ln;
    float bv = BS[n];
#pragma unroll
    for (int mf = 0; mf < 4; ++mf)
#pragma unroll
      for (int r = 0; r < 4; ++r) {
        int m = mbase + wm * 64 + mf * 16 + 4 * g + r;
        float val = (acc[mf][nf][r] + bv) * osc;
        if (z < 2) {
          u16* O = z == 0 ? o0 : o1;
          O[(size_t)m * 1024 + n] = f2bf(val);
        } else {
          vT[((size_t)((m >> 11) * 16 + (n >> 6)) * 64 + (n & 63)) * 2048 + (m & 2047)] = f2bf(val);
        }
      }
  }
}

// ---------------------------------------------------------------------------
// Attention R11: V^T LDS (stride-72 rows like Ks), V-frags via ds_read_b128,
// NO asm / NO fences in the loop. 8 waves, QBLK=256, KVBLK=64, 2-barrier
// protocol, load-early prefetch, ones-MFMA rowsum, setprio.
// ---------------------------------------------------------------------------
__global__ __launch_bounds__(512)
void attn_kernel(const u16* __restrict__ qh, const u16* __restrict__ kh, const u16* __restrict__ vT,
                 float* __restrict__ out)
{
  int p  = blockIdx.x + 8 * blockIdx.y + 128 * blockIdx.z;
  int wk = (p & 7) * 64 + (p >> 3);
  int qt = wk & 7, h = (wk >> 3) & 15, b = wk >> 7;

  const int t = threadIdx.x;
  const int lane = t & 63, wid = t >> 6;
  const int g = lane >> 4, ln = lane & 15;
  const size_t bS = (size_t)b * S_TOT;
  const int qwin = qt * 256 + wid * 32;

  __shared__ __align__(16) u16 Ks[64 * 72];   // row kv: 64 d-elems perm per 32-half
  __shared__ __align__(16) u16 Vt[64 * 72];   // row dv: 64 kv-elems perm per 32-half

  bf16x8 qf[2][2];
#pragma unroll
  for (int nf = 0; nf < 2; ++nf) {
    const u16* qrow = &qh[(bS + qwin + nf * 16 + ln) * HD + h * 64];
#pragma unroll
    for (int kk = 0; kk < 2; ++kk) {
      bf16x4 lo = *(const bf16x4*)&qrow[kk * 32 + 4 * g];
      bf16x4 hi = *(const bf16x4*)&qrow[kk * 32 + 4 * g + 16];
      bf16x8 qq;
      qq[0]=lo[0]; qq[1]=lo[1]; qq[2]=lo[2]; qq[3]=lo[3];
      qq[4]=hi[0]; qq[5]=hi[1]; qq[6]=hi[2]; qq[7]=hi[3];
      qf[nf][kk] = qq;
    }
  }

  bf16x8 ones;
#pragma unroll
  for (int j = 0; j < 8; ++j) ones[j] = (short)0x3F80;

  f32x4 o[2][4];
#pragma unroll
  for (int i = 0; i < 2; ++i)
#pragma unroll
    for (int j = 0; j < 4; ++j) { o[i][j][0]=0.f; o[i][j][1]=0.f; o[i][j][2]=0.f; o[i][j][3]=0.f; }
  f32x4 o1[2];
  o1[0][0]=0.f; o1[0][1]=0.f; o1[0][2]=0.f; o1[0][3]=0.f;
  o1[1][0]=0.f; o1[1][1]=0.f; o1[1][2]=0.f; o1[1][3]=0.f;

  // K staging: 512 threads cover 64 kv x 64 d (2 b64 each)
  const int skv = t >> 4;                 // 0..31, +32 second chunk
  const int sd0 = (t & 15) * 4;
  const int kpos = 32 * (sd0 >> 5) + 8 * ((sd0 & 15) >> 2) + 4 * ((sd0 >> 4) & 1);
  u16* ksw[2];
  ksw[0] = &Ks[skv * 72 + kpos];
  ksw[1] = &Ks[(skv + 32) * 72 + kpos];
  const u16* kp = &kh[(bS + skv) * HD + h * 64 + sd0];

  // V staging: 512 threads cover 64 dv x 64 kv (1 bf16x8 global read, 2 b64 writes)
  const int vdv  = t >> 3;                // 0..63
  const int vkv8 = (t & 7) * 8;           // 8 consecutive kv
  const int vp0  = 32 * (vkv8 >> 5) + 8 * ((vkv8 & 15) >> 2) + 4 * ((vkv8 >> 4) & 1);
  const int vkv4 = vkv8 + 4;
  const int vp1  = 32 * (vkv4 >> 5) + 8 * ((vkv4 & 15) >> 2) + 4 * ((vkv4 >> 4) & 1);
  u16* vsw0 = &Vt[vdv * 72 + vp0];
  u16* vsw1 = &Vt[vdv * 72 + vp1];
  const u16* vp = &vT[((size_t)(b * 16 + h) * 64 + vdv) * 2048 + vkv8];

  const size_t KSTEP = (size_t)64 * HD, C32 = (size_t)32 * HD;

  // prologue: interval 0
  bf16x4 kr[2];
  kr[0] = *(const bf16x4*)kp; kr[1] = *(const bf16x4*)(kp + C32);
  bf16x8 vr = *(const bf16x8*)vp;
  kp += KSTEP; vp += 64;

  for (int it = 0; it < 32; ++it) {
    *(bf16x4*)ksw[0] = kr[0];
    *(bf16x4*)ksw[1] = kr[1];
    bf16x4 vlo = { vr[0], vr[1], vr[2], vr[3] };
    bf16x4 vhi = { vr[4], vr[5], vr[6], vr[7] };
    *(bf16x4*)vsw0 = vlo;
    *(bf16x4*)vsw1 = vhi;
    __syncthreads();                                   // barrier #1

    if (it < 31) {
      kr[0] = *(const bf16x4*)kp; kr[1] = *(const bf16x4*)(kp + C32);
      vr = *(const bf16x8*)vp;
      kp += KSTEP; vp += 64;
    }

#pragma unroll
    for (int s = 0; s < 2; ++s) {
      bf16x8 kf[2][2];
#pragma unroll
      for (int mf = 0; mf < 2; ++mf)
#pragma unroll
        for (int kk = 0; kk < 2; ++kk)
          kf[mf][kk] = *(const bf16x8*)&Ks[(s * 32 + mf * 16 + ln) * 72 + kk * 32 + 8 * g];

      f32x4 sc[2][2];
      __builtin_amdgcn_s_setprio(1);
#pragma unroll
      for (int mf = 0; mf < 2; ++mf)
#pragma unroll
        for (int nf = 0; nf < 2; ++nf) {
          f32x4 a; a[0]=0.f; a[1]=0.f; a[2]=0.f; a[3]=0.f;
#pragma unroll
          for (int kk = 0; kk < 2; ++kk)
            a = __builtin_amdgcn_mfma_f32_16x16x32_bf16(kf[mf][kk], qf[nf][kk], a, 0, 0, 0);
          sc[mf][nf] = a;
        }
      __builtin_amdgcn_s_setprio(0);

      // V fragments: plain b128 from V^T rows (lane = dv, elems = kv-perm)
      bf16x8 vf[4];
#pragma unroll
      for (int nf = 0; nf < 4; ++nf)
        vf[nf] = *(const bf16x8*)&Vt[(nf * 16 + ln) * 72 + s * 32 + 8 * g];

      bf16x8 pa[2];
#pragma unroll
      for (int nf = 0; nf < 2; ++nf) {
        float pv[2][4];
#pragma unroll
        for (int mf = 0; mf < 2; ++mf)
#pragma unroll
          for (int r = 0; r < 4; ++r)
            pv[mf][r] = EXP2(sc[mf][nf][r]);
        union { u32x4 u; bf16x8 b; } pk;
        pk.u[0] = cvt_pk_bf16(pv[0][0], pv[0][1]);
        pk.u[1] = cvt_pk_bf16(pv[0][2], pv[0][3]);
        pk.u[2] = cvt_pk_bf16(pv[1][0], pv[1][1]);
        pk.u[3] = cvt_pk_bf16(pv[1][2], pv[1][3]);
        pa[nf] = pk.b;
      }

      __builtin_amdgcn_s_setprio(1);
#pragma unroll
      for (int mq = 0; mq < 2; ++mq) {
#pragma unroll
        for (int nf = 0; nf < 4; ++nf)
          o[mq][nf] = __builtin_amdgcn_mfma_f32_16x16x32_bf16(pa[mq], vf[nf], o[mq][nf], 0, 0, 0);
        o1[mq] = __builtin_amdgcn_mfma_f32_16x16x32_bf16(pa[mq], ones, o1[mq], 0, 0, 0);
      }
      __builtin_amdgcn_s_setprio(0);
    }
    __syncthreads();                                   // barrier #2
  }

#pragma unroll
  for (int mq = 0; mq < 2; ++mq)
#pragma unroll
    for (int r = 0; r < 4; ++r) {
      float inv = 1.0f / o1[mq][r];
      int qrow = qwin + mq * 16 + 4 * g + r;
#pragma unroll
      for (int nf = 0; nf < 4; ++nf)
        out[(bS + qrow) * HD + h * 64 + nf * 16 + ln] = o[mq][nf][r] * inv;
    }
}

extern "C" void kernel_launch(void* const* d_in, const int* in_sizes, int n_in,
                              void* d_out, int out_size, void* d_ws, size_t ws_size,
                              hipStream_t stream) {
  const float* q  = (const float*)d_in[0];
  const float* k  = (const float*)d_in[1];
  const float* v  = (const float*)d_in[2];
  const float* Wq = (const float*)d_in[3];
  const float* bq = (const float*)d_in[4];
  const float* Wk = (const float*)d_in[5];
  const float* bk = (const float*)d_in[6];
  const float* Wv = (const float*)d_in[7];
  const float* bv = (const float*)d_in[8];
  float* out = (float*)d_out;

  u16* qh = (u16*)d_ws;
  u16* kh = qh + (size_t)8192 * 1024;
  u16* vT = kh + (size_t)8192 * 1024;     // [b][h][dv][seq]

  const size_t XB_OFF = (size_t)3 * 8192 * 1024;
  const size_t WT_OFF = XB_OFF + (size_t)3 * 8192 * 1024;
  const size_t NEED   = (WT_OFF + (size_t)3 * 1024 * 1024) * 2;

  if (ws_size >= NEED) {
    u16* Xb = (u16*)d_ws + XB_OFF;
    u16* Wt = (u16*)d_ws + WT_OFF;
    conv_kernel<<<dim3(1152, 3), 256, 0, stream>>>(q, k, v, Wq, Wk, Wv, Xb, Wt);
    gemm_kernel<<<dim3(8, 64, 3), 256, 0, stream>>>(Xb, Wt, bq, bk, bv, qh, kh, vT);
  } else {
    proj_kernel<<<dim3(8, 64, 3), 256, 0, stream>>>(q, k, v, Wq, Wk, Wv, bq, bk, bv, qh, kh, vT);
  }
  attn_kernel<<<dim3(8, 16, 4), 512, 0, stream>>>(qh, kh, vT, out);
}

// Round 12
// 171.753 us; speedup vs baseline: 1.3162x; 1.0400x over previous
//
#include <hip/hip_runtime.h>
#include <hip/hip_bf16.h>

// MultiHeadAttention: B=4 S=2048 D=1024 H=16 DK=DV=64 scale=8
// R12: gemm converted to the catalog's T3 "minimum 2-phase" protocol —
// double-buffered LDS, tile t+1's global_load_lds issued BEFORE computing
// tile t, ONE __syncthreads per k-step (was: stage -> immediate barrier =
// full DMA latency exposed every step; MfmaUtil 23, VALUBusy 30, occ 20).
// Static buffer indices via unroll-by-2 (rule #20). attn/conv/proj frozen
// (R11: attn ~62us fence-free, conv ~24us BW-floor).

typedef unsigned short u16;
typedef unsigned int   u32;
typedef short bf16x8 __attribute__((ext_vector_type(8)));
typedef short bf16x4 __attribute__((ext_vector_type(4)));
typedef float f32x4  __attribute__((ext_vector_type(4)));
typedef u32   u32x4  __attribute__((ext_vector_type(4)));

#define S_TOT 2048
#define HD    1024
#define QK_SCALE 0.18033688f   // log2(e)/8

#if __has_builtin(__builtin_amdgcn_exp2f)
#define EXP2(x) __builtin_amdgcn_exp2f(x)
#else
#define EXP2(x) exp2f(x)
#endif

__device__ __forceinline__ u16 f2bf(float f) {
  union { float f; unsigned u; } v; v.f = f;
  unsigned r = v.u + 0x7FFFu + ((v.u >> 16) & 1u);
  return (u16)(r >> 16);
}

__device__ __forceinline__ u32 cvt_pk_bf16(float lo, float hi) {
  u32 r;
  asm("v_cvt_pk_bf16_f32 %0, %1, %2" : "=v"(r) : "v"(lo), "v"(hi));
  return r;
}

__device__ __forceinline__ bf16x4 ds_tr16(unsigned a) {
  bf16x4 d;
  asm volatile("ds_read_b64_tr_b16 %0, %1" : "=v"(d) : "v"(a) : "memory");
  return d;
}

__device__ __forceinline__ void gld16(const u16* g, u16* l) {
  __builtin_amdgcn_global_load_lds(
      (const __attribute__((address_space(1))) u32*)g,
      (__attribute__((address_space(3))) u32*)l, 16, 0, 0);
}

// rule #18: inline-asm lgkmcnt needs sched_barrier(0) right after (gemm only)
#define LGKM_FENCE() do { asm volatile("s_waitcnt lgkmcnt(0)" ::: "memory"); \
                          __builtin_amdgcn_sched_barrier(0); } while (0)

// ---------------------------------------------------------------------------
// conv_kernel (frozen): fp32 -> bf16 re-layout (Xb row-perm; Wt k-major tiles).
// ---------------------------------------------------------------------------
__global__ __launch_bounds__(256)
void conv_kernel(const float* __restrict__ x0, const float* __restrict__ x1, const float* __restrict__ x2,
                 const float* __restrict__ w0, const float* __restrict__ w1, const float* __restrict__ w2,
                 u16* __restrict__ Xb, u16* __restrict__ Wt)
{
  const int z = blockIdx.y;
  const int t = threadIdx.x;
  if (blockIdx.x < 1024) {
    const float* X = z == 0 ? x0 : (z == 1 ? x1 : x2);
    u16* Xz = Xb + (size_t)z * 8388608;
    int tid = blockIdx.x * 256 + t;
#pragma unroll
    for (int i = 0; i < 8; ++i) {
      int c = tid + i * 262144;
      int row = c >> 8, k4 = (c & 255) * 4;
      const float4 xv = *(const float4*)&X[(size_t)row * 1024 + k4];
      int p = (k4 & ~31) + 8 * ((k4 & 15) >> 2) + 4 * ((k4 >> 4) & 1);
      bf16x4 sv = { (short)f2bf(xv.x), (short)f2bf(xv.y), (short)f2bf(xv.z), (short)f2bf(xv.w) };
      *(bf16x4*)&Xz[(size_t)row * 1024 + p] = sv;
    }
  } else {
    const float* W = z == 0 ? w0 : (z == 1 ? w1 : w2);
    u16* Wz = Wt + (size_t)z * 1048576;
    int tid = (blockIdx.x - 1024) * 256 + t;
#pragma unroll
    for (int i = 0; i < 8; ++i) {
      int c = tid + i * 32768;
      int k = c >> 8, n4 = (c & 255) * 4;
      const float4 wv = *(const float4*)&W[(size_t)k * 1024 + n4];
      int off = ((n4 >> 7) * 32 + (k >> 5)) * 4096 + ((n4 >> 4) & 7) * 512
              + ((k >> 4) & 1) * 256 + (k & 15) * 16 + (n4 & 15);
      bf16x4 sv = { (short)f2bf(wv.x), (short)f2bf(wv.y), (short)f2bf(wv.z), (short)f2bf(wv.w) };
      *(bf16x4*)&Wz[off] = sv;
    }
  }
}

// ---------------------------------------------------------------------------
// gemm_kernel R12: 2-phase double-buffered. z in {0,1}: natural out (qh, kh).
// z==2: operand-swapped MFMA, writes vT[((b*16+h)*64+dv)*2048 + seq].
// ---------------------------------------------------------------------------
__global__ __launch_bounds__(256)
void gemm_kernel(const u16* __restrict__ Xb, const u16* __restrict__ Wt,
                 const float* __restrict__ b0, const float* __restrict__ b1, const float* __restrict__ b2,
                 u16* __restrict__ o0, u16* __restrict__ o1, u16* __restrict__ vT)
{
  int p  = blockIdx.x + 8 * blockIdx.y + 512 * blockIdx.z;
  int wk = (p & 7) * 192 + (p >> 3);
  int nb = wk & 7, mb = (wk >> 3) & 63, z = wk >> 9;

  const u16* Xz = Xb + (size_t)z * 8388608;
  const u16* Wz = Wt + (size_t)z * 1048576;
  const float* BS = z == 0 ? b0 : (z == 1 ? b1 : b2);
  const float  osc = (z == 0) ? QK_SCALE : 1.0f;

  const int t = threadIdx.x;
  const int lane = t & 63, wid = t >> 6;
  const int g = lane >> 4, ln = lane & 15;
  const int mbase = mb * 128, nbase = nb * 128;

  __shared__ __align__(16) u16 Al[2][128 * 32];
  __shared__ __align__(16) u16 Bl[2][16 * 256];

  f32x4 acc[4][4];
#pragma unroll
  for (int i = 0; i < 4; ++i)
#pragma unroll
    for (int j = 0; j < 4; ++j) { acc[i][j][0]=0.f; acc[i][j][1]=0.f; acc[i][j][2]=0.f; acc[i][j][3]=0.f; }

  const u16* sa = Xz + (size_t)(mbase + (t >> 2)) * 1024 + (t & 3) * 8;
  const u16* sb = Wz + (size_t)(nb * 32) * 4096 + t * 8;
  u16* alw[2] = { &Al[0][wid * 512], &Al[1][wid * 512] };
  u16* blw[2] = { &Bl[0][wid * 512], &Bl[1][wid * 512] };

  auto stage = [&](int kb, int buf) __attribute__((always_inline)) {
    gld16(sa + kb * 32,               alw[buf]);
    gld16(sa + kb * 32 + 64 * 1024,   alw[buf] + 2048);
    gld16(sb + kb * 4096,             blw[buf]);
    gld16(sb + kb * 4096 + 2048,      blw[buf] + 2048);
  };

  // prologue: tile 0 -> buf0
  stage(0, 0);
  __syncthreads();

  if (z < 2) {
    const int wm = wid >> 1, wn = wid & 1;
    u16* O = z == 0 ? o0 : o1;
    const unsigned bsb[2] = {
      (unsigned)(size_t)&Bl[0][0] + (unsigned)((wn * 4) * 1024) + lane * 8,
      (unsigned)(size_t)&Bl[1][0] + (unsigned)((wn * 4) * 1024) + lane * 8 };

    auto compute = [&](int cur) __attribute__((always_inline)) {
      bf16x8 af[4];
#pragma unroll
      for (int mf = 0; mf < 4; ++mf)
        af[mf] = *(const bf16x8*)&Al[cur][(wm * 64 + mf * 16 + ln) * 32 + g * 8];
      bf16x8 bfv[4];
#pragma unroll
      for (int nf = 0; nf < 4; ++nf) {
        bf16x4 lo = ds_tr16(bsb[cur] + (unsigned)(nf * 1024));
        bf16x4 hi = ds_tr16(bsb[cur] + (unsigned)(nf * 1024 + 512));
        bf16x8 bb;
        bb[0]=lo[0]; bb[1]=lo[1]; bb[2]=lo[2]; bb[3]=lo[3];
        bb[4]=hi[0]; bb[5]=hi[1]; bb[6]=hi[2]; bb[7]=hi[3];
        bfv[nf] = bb;
      }
      LGKM_FENCE();
      __builtin_amdgcn_s_setprio(1);
#pragma unroll
      for (int mf = 0; mf < 4; ++mf)
#pragma unroll
        for (int nf = 0; nf < 4; ++nf)
          acc[mf][nf] = __builtin_amdgcn_mfma_f32_16x16x32_bf16(af[mf], bfv[nf], acc[mf][nf], 0, 0, 0);
      __builtin_amdgcn_s_setprio(0);
    };

    for (int kb = 0; kb < 32; kb += 2) {
      if (kb + 1 < 32) stage(kb + 1, 1);
      compute(0);
      __syncthreads();
      if (kb + 2 < 32) stage(kb + 2, 0);
      compute(1);
      __syncthreads();
    }

#pragma unroll
    for (int nf = 0; nf < 4; ++nf) {
      int n = nbase + wn * 64 + nf * 16 + ln;
      float bv = BS[n];
#pragma unroll
      for (int mf = 0; mf < 4; ++mf)
#pragma unroll
        for (int r = 0; r < 4; ++r) {
          int m = mbase + wm * 64 + mf * 16 + 4 * g + r;
          O[(size_t)m * 1024 + n] = f2bf((acc[mf][nf][r] + bv) * osc);
        }
    }
  } else {
    // z==2 swapped: A = W-frag (tr), B = X-frag (b128); transposed store.
    const int wseq = wid >> 1, wdv = wid & 1;
    const unsigned bsb2[2] = {
      (unsigned)(size_t)&Bl[0][0] + (unsigned)((wdv * 4) * 1024) + lane * 8,
      (unsigned)(size_t)&Bl[1][0] + (unsigned)((wdv * 4) * 1024) + lane * 8 };

    auto compute2 = [&](int cur) __attribute__((always_inline)) {
      bf16x8 afw[4];
#pragma unroll
      for (int mf = 0; mf < 4; ++mf) {
        bf16x4 lo = ds_tr16(bsb2[cur] + (unsigned)(mf * 1024));
        bf16x4 hi = ds_tr16(bsb2[cur] + (unsigned)(mf * 1024 + 512));
        bf16x8 bb;
        bb[0]=lo[0]; bb[1]=lo[1]; bb[2]=lo[2]; bb[3]=lo[3];
        bb[4]=hi[0]; bb[5]=hi[1]; bb[6]=hi[2]; bb[7]=hi[3];
        afw[mf] = bb;
      }
      bf16x8 bfx[4];
#pragma unroll
      for (int nf = 0; nf < 4; ++nf)
        bfx[nf] = *(const bf16x8*)&Al[cur][(wseq * 64 + nf * 16 + ln) * 32 + g * 8];
      LGKM_FENCE();
      __builtin_amdgcn_s_setprio(1);
#pragma unroll
      for (int mf = 0; mf < 4; ++mf)
#pragma unroll
        for (int nf = 0; nf < 4; ++nf)
          acc[mf][nf] = __builtin_amdgcn_mfma_f32_16x16x32_bf16(afw[mf], bfx[nf], acc[mf][nf], 0, 0, 0);
      __builtin_amdgcn_s_setprio(0);
    };

    for (int kb = 0; kb < 32; kb += 2) {
      if (kb + 1 < 32) stage(kb + 1, 1);
      compute2(0);
      __syncthreads();
      if (kb + 2 < 32) stage(kb + 2, 0);
      compute2(1);
      __syncthreads();
    }

#pragma unroll
    for (int mf = 0; mf < 4; ++mf)
#pragma unroll
      for (int r = 0; r < 4; ++r) {
        int dvg = nbase + wdv * 64 + mf * 16 + 4 * g + r;
        float bv = BS[dvg];
        int hh = dvg >> 6, dvl = dvg & 63;
#pragma unroll
        for (int nf = 0; nf < 4; ++nf) {
          int m = mbase + wseq * 64 + nf * 16 + ln;
          int bb = m >> 11, ss = m & 2047;
          vT[((size_t)(bb * 16 + hh) * 64 + dvl) * 2048 + ss] = f2bf(acc[mf][nf][r] + bv);
        }
      }
  }
}

// ---------------------------------------------------------------------------
// Fallback proj (frozen; z==2 transposed scatter epilogue).
// ---------------------------------------------------------------------------
__global__ __launch_bounds__(256)
void proj_kernel(const float* __restrict__ x0, const float* __restrict__ x1, const float* __restrict__ x2,
                 const float* __restrict__ w0, const float* __restrict__ w1, const float* __restrict__ w2,
                 const float* __restrict__ b0, const float* __restrict__ b1, const float* __restrict__ b2,
                 u16* __restrict__ o0, u16* __restrict__ o1, u16* __restrict__ vT)
{
  int p  = blockIdx.x + 8 * blockIdx.y + 512 * blockIdx.z;
  int wk = (p & 7) * 192 + (p >> 3);
  int nb = wk & 7, mb = (wk >> 3) & 63, z = wk >> 9;

  const float* X  = z == 0 ? x0 : (z == 1 ? x1 : x2);
  const float* W  = z == 0 ? w0 : (z == 1 ? w1 : w2);
  const float* BS = z == 0 ? b0 : (z == 1 ? b1 : b2);
  const float  osc = (z == 0) ? QK_SCALE : 1.0f;

  const int t = threadIdx.x;
  const int lane = t & 63, wid = t >> 6;
  const int g = lane >> 4, ln = lane & 15;
  const int wm = wid >> 1, wn = wid & 1;
  const int mbase = mb * 128, nbase = nb * 128;

  __shared__ __align__(16) u16 As[128 * 40];
  __shared__ __align__(16) u16 Bs[16 * 272];

  f32x4 acc[4][4];
#pragma unroll
  for (int i = 0; i < 4; ++i)
#pragma unroll
    for (int j = 0; j < 4; ++j) { acc[i][j][0]=0.f; acc[i][j][1]=0.f; acc[i][j][2]=0.f; acc[i][j][3]=0.f; }

  const int arow = t >> 3;
  const int ak0  = (t & 7) * 4;
  const int ap   = 8 * ((ak0 & 15) >> 2) + 4 * (ak0 >> 4);
  const int bkr  = t >> 5;
  const int bnc  = (t & 31) * 4;
  const int bnblk = bnc >> 4, bncl = bnc & 15;

  const unsigned bs_base = (unsigned)(size_t)&Bs[0];

  for (int kb = 0; kb < 32; ++kb) {
    const int kbase = kb * 32;
#pragma unroll
    for (int ps = 0; ps < 4; ++ps) {
      int row = arow + 32 * ps;
      const float4 xv = *(const float4*)&X[(size_t)(mbase + row) * 1024 + kbase + ak0];
      bf16x4 sv = { (short)f2bf(xv.x), (short)f2bf(xv.y), (short)f2bf(xv.z), (short)f2bf(xv.w) };
      *(bf16x4*)&As[row * 40 + ap] = sv;
    }
#pragma unroll
    for (int ps = 0; ps < 4; ++ps) {
      int kr = bkr + 8 * ps;
      const float4 wv = *(const float4*)&W[(size_t)(kbase + kr) * 1024 + nbase + bnc];
      bf16x4 sv = { (short)f2bf(wv.x), (short)f2bf(wv.y), (short)f2bf(wv.z), (short)f2bf(wv.w) };
      *(bf16x4*)&Bs[(bnblk * 2 + (kr >> 4)) * 272 + (kr & 15) * 16 + bncl] = sv;
    }
    __syncthreads();

    bf16x8 af[4];
#pragma unroll
    for (int mf = 0; mf < 4; ++mf)
      af[mf] = *(const bf16x8*)&As[(wm * 64 + mf * 16 + ln) * 40 + g * 8];

    bf16x8 bfv[4];
#pragma unroll
    for (int nf = 0; nf < 4; ++nf) {
      unsigned base = bs_base + (unsigned)(((wn * 4 + nf) * 2) * 544) + lane * 8;
      bf16x4 lo = ds_tr16(base);
      bf16x4 hi = ds_tr16(base + 544);
      bf16x8 bb;
      bb[0]=lo[0]; bb[1]=lo[1]; bb[2]=lo[2]; bb[3]=lo[3];
      bb[4]=hi[0]; bb[5]=hi[1]; bb[6]=hi[2]; bb[7]=hi[3];
      bfv[nf] = bb;
    }
    LGKM_FENCE();
#pragma unroll
    for (int mf = 0; mf < 4; ++mf)
#pragma unroll
      for (int nf = 0; nf < 4; ++nf)
        acc[mf][nf] = __builtin_amdgcn_mfma_f32_16x16x32_bf16(af[mf], bfv[nf], acc[mf][nf], 0, 0, 0);
    __syncthreads();
  }

#pragma unroll
  for (int nf = 0; nf < 4; ++nf) {
    int n = nbase + wn * 64 + nf * 16 + ln;
    float bv = BS[n];
#pragma unroll
    for (int mf = 0; mf < 4; ++mf)
#pragma unroll
      for (int r = 0; r < 4; ++r) {
        int m = mbase + wm * 64 + mf * 16 + 4 * g + r;
        float val = (acc[mf][nf][r] + bv) * osc;
        if (z < 2) {
          u16* O = z == 0 ? o0 : o1;
          O[(size_t)m * 1024 + n] = f2bf(val);
        } else {
          vT[((size_t)((m >> 11) * 16 + (n >> 6)) * 64 + (n & 63)) * 2048 + (m & 2047)] = f2bf(val);
        }
      }
  }
}

// ---------------------------------------------------------------------------
// Attention (R11, frozen): V^T LDS, plain b128 V-frags, no asm/fences in loop.
// 8 waves, QBLK=256, KVBLK=64, 2-barrier protocol, ones-MFMA rowsum, setprio.
// ---------------------------------------------------------------------------
__global__ __launch_bounds__(512)
void attn_kernel(const u16* __restrict__ qh, const u16* __restrict__ kh, const u16* __restrict__ vT,
                 float* __restrict__ out)
{
  int p  = blockIdx.x + 8 * blockIdx.y + 128 * blockIdx.z;
  int wk = (p & 7) * 64 + (p >> 3);
  int qt = wk & 7, h = (wk >> 3) & 15, b = wk >> 7;

  const int t = threadIdx.x;
  const int lane = t & 63, wid = t >> 6;
  const int g = lane >> 4, ln = lane & 15;
  const size_t bS = (size_t)b * S_TOT;
  const int qwin = qt * 256 + wid * 32;

  __shared__ __align__(16) u16 Ks[64 * 72];
  __shared__ __align__(16) u16 Vt[64 * 72];

  bf16x8 qf[2][2];
#pragma unroll
  for (int nf = 0; nf < 2; ++nf) {
    const u16* qrow = &qh[(bS + qwin + nf * 16 + ln) * HD + h * 64];
#pragma unroll
    for (int kk = 0; kk < 2; ++kk) {
      bf16x4 lo = *(const bf16x4*)&qrow[kk * 32 + 4 * g];
      bf16x4 hi = *(const bf16x4*)&qrow[kk * 32 + 4 * g + 16];
      bf16x8 qq;
      qq[0]=lo[0]; qq[1]=lo[1]; qq[2]=lo[2]; qq[3]=lo[3];
      qq[4]=hi[0]; qq[5]=hi[1]; qq[6]=hi[2]; qq[7]=hi[3];
      qf[nf][kk] = qq;
    }
  }

  bf16x8 ones;
#pragma unroll
  for (int j = 0; j < 8; ++j) ones[j] = (short)0x3F80;

  f32x4 o[2][4];
#pragma unroll
  for (int i = 0; i < 2; ++i)
#pragma unroll
    for (int j = 0; j < 4; ++j) { o[i][j][0]=0.f; o[i][j][1]=0.f; o[i][j][2]=0.f; o[i][j][3]=0.f; }
  f32x4 o1[2];
  o1[0][0]=0.f; o1[0][1]=0.f; o1[0][2]=0.f; o1[0][3]=0.f;
  o1[1][0]=0.f; o1[1][1]=0.f; o1[1][2]=0.f; o1[1][3]=0.f;

  const int skv = t >> 4;
  const int sd0 = (t & 15) * 4;
  const int kpos = 32 * (sd0 >> 5) + 8 * ((sd0 & 15) >> 2) + 4 * ((sd0 >> 4) & 1);
  u16* ksw[2];
  ksw[0] = &Ks[skv * 72 + kpos];
  ksw[1] = &Ks[(skv + 32) * 72 + kpos];
  const u16* kp = &kh[(bS + skv) * HD + h * 64 + sd0];

  const int vdv  = t >> 3;
  const int vkv8 = (t & 7) * 8;
  const int vp0  = 32 * (vkv8 >> 5) + 8 * ((vkv8 & 15) >> 2) + 4 * ((vkv8 >> 4) & 1);
  const int vkv4 = vkv8 + 4;
  const int vp1  = 32 * (vkv4 >> 5) + 8 * ((vkv4 & 15) >> 2) + 4 * ((vkv4 >> 4) & 1);
  u16* vsw0 = &Vt[vdv * 72 + vp0];
  u16* vsw1 = &Vt[vdv * 72 + vp1];
  const u16* vp = &vT[((size_t)(b * 16 + h) * 64 + vdv) * 2048 + vkv8];

  const size_t KSTEP = (size_t)64 * HD, C32 = (size_t)32 * HD;

  bf16x4 kr[2];
  kr[0] = *(const bf16x4*)kp; kr[1] = *(const bf16x4*)(kp + C32);
  bf16x8 vr = *(const bf16x8*)vp;
  kp += KSTEP; vp += 64;

  for (int it = 0; it < 32; ++it) {
    *(bf16x4*)ksw[0] = kr[0];
    *(bf16x4*)ksw[1] = kr[1];
    bf16x4 vlo = { vr[0], vr[1], vr[2], vr[3] };
    bf16x4 vhi = { vr[4], vr[5], vr[6], vr[7] };
    *(bf16x4*)vsw0 = vlo;
    *(bf16x4*)vsw1 = vhi;
    __syncthreads();

    if (it < 31) {
      kr[0] = *(const bf16x4*)kp; kr[1] = *(const bf16x4*)(kp + C32);
      vr = *(const bf16x8*)vp;
      kp += KSTEP; vp += 64;
    }

#pragma unroll
    for (int s = 0; s < 2; ++s) {
      bf16x8 kf[2][2];
#pragma unroll
      for (int mf = 0; mf < 2; ++mf)
#pragma unroll
        for (int kk = 0; kk < 2; ++kk)
          kf[mf][kk] = *(const bf16x8*)&Ks[(s * 32 + mf * 16 + ln) * 72 + kk * 32 + 8 * g];

      f32x4 sc[2][2];
      __builtin_amdgcn_s_setprio(1);
#pragma unroll
      for (int mf = 0; mf < 2; ++mf)
#pragma unroll
        for (int nf = 0; nf < 2; ++nf) {
          f32x4 a; a[0]=0.f; a[1]=0.f; a[2]=0.f; a[3]=0.f;
#pragma unroll
          for (int kk = 0; kk < 2; ++kk)
            a = __builtin_amdgcn_mfma_f32_16x16x32_bf16(kf[mf][kk], qf[nf][kk], a, 0, 0, 0);
          sc[mf][nf] = a;
        }
      __builtin_amdgcn_s_setprio(0);

      bf16x8 vf[4];
#pragma unroll
      for (int nf = 0; nf < 4; ++nf)
        vf[nf] = *(const bf16x8*)&Vt[(nf * 16 + ln) * 72 + s * 32 + 8 * g];

      bf16x8 pa[2];
#pragma unroll
      for (int nf = 0; nf < 2; ++nf) {
        float pv[2][4];
#pragma unroll
        for (int mf = 0; mf < 2; ++mf)
#pragma unroll
          for (int r = 0; r < 4; ++r)
            pv[mf][r] = EXP2(sc[mf][nf][r]);
        union { u32x4 u; bf16x8 b; } pk;
        pk.u[0] = cvt_pk_bf16(pv[0][0], pv[0][1]);
        pk.u[1] = cvt_pk_bf16(pv[0][2], pv[0][3]);
        pk.u[2] = cvt_pk_bf16(pv[1][0], pv[1][1]);
        pk.u[3] = cvt_pk_bf16(pv[1][2], pv[1][3]);
        pa[nf] = pk.b;
      }

      __builtin_amdgcn_s_setprio(1);
#pragma unroll
      for (int mq = 0; mq < 2; ++mq) {
#pragma unroll
        for (int nf = 0; nf < 4; ++nf)
          o[mq][nf] = __builtin_amdgcn_mfma_f32_16x16x32_bf16(pa[mq], vf[nf], o[mq][nf], 0, 0, 0);
        o1[mq] = __builtin_amdgcn_mfma_f32_16x16x32_bf16(pa[mq], ones, o1[mq], 0, 0, 0);
      }
      __builtin_amdgcn_s_setprio(0);
    }
    __syncthreads();
  }

#pragma unroll
  for (int mq = 0; mq < 2; ++mq)
#pragma unroll
    for (int r = 0; r < 4; ++r) {
      float inv = 1.0f / o1[mq][r];
      int qrow = qwin + mq * 16 + 4 * g + r;
#pragma unroll
      for (int nf = 0; nf < 4; ++nf)
        out[(bS + qrow) * HD + h * 64 + nf * 16 + ln] = o[mq][nf][r] * inv;
    }
}

extern "C" void kernel_launch(void* const* d_in, const int* in_sizes, int n_in,
                              void* d_out, int out_size, void* d_ws, size_t ws_size,
                              hipStream_t stream) {
  const float* q  = (const float*)d_in[0];
  const float* k  = (const float*)d_in[1];
  const float* v  = (const float*)d_in[2];
  const float* Wq = (const float*)d_in[3];
  const float* bq = (const float*)d_in[4];
  const float* Wk = (const float*)d_in[5];
  const float* bk = (const float*)d_in[6];
  const float* Wv = (const float*)d_in[7];
  const float* bv = (const float*)d_in[8];
  float* out = (float*)d_out;

  u16* qh = (u16*)d_ws;
  u16* kh = qh + (size_t)8192 * 1024;
  u16* vT = kh + (size_t)8192 * 1024;     // [b][h][dv][seq]

  const size_t XB_OFF = (size_t)3 * 8192 * 1024;
  const size_t WT_OFF = XB_OFF + (size_t)3 * 8192 * 1024;
  const size_t NEED   = (WT_OFF + (size_t)3 * 1024 * 1024) * 2;

  if (ws_size >= NEED) {
    u16* Xb = (u16*)d_ws + XB_OFF;
    u16* Wt = (u16*)d_ws + WT_OFF;
    conv_kernel<<<dim3(1152, 3), 256, 0, stream>>>(q, k, v, Wq, Wk, Wv, Xb, Wt);
    gemm_kernel<<<dim3(8, 64, 3), 256, 0, stream>>>(Xb, Wt, bq, bk, bv, qh, kh, vT);
  } else {
    proj_kernel<<<dim3(8, 64, 3), 256, 0, stream>>>(q, k, v, Wq, Wk, Wv, bq, bk, bv, qh, kh, vT);
  }
  attn_kernel<<<dim3(8, 16, 4), 512, 0, stream>>>(qh, kh, vT, out);
}

// Round 13
// 171.172 us; speedup vs baseline: 1.3206x; 1.0034x over previous
//
#include <hip/hip_runtime.h>
#include <hip/hip_bf16.h>

// MultiHeadAttention: B=4 S=2048 D=1024 H=16 DK=DV=64 scale=8
// R13: gemm made fence-free + all-plain-b128 (the R11 mechanism, applied to
// the last fence-carrying kernel): conv writes Wt as W^T tiles [128n][32kperm]
// so B-frags are ds_read_b128 like A (no tr-reads, no LGKM_FENCE in gemm).
// 8-way b128 bank conflict at 64B row stride fixed per rule #21: XOR swizzle
// ((row&6)<<2) baked into Xb/Wt by conv (inverse side) and applied on gemm
// reads (read side); DMA staging stays byte-linear. attn/conv-X/proj frozen.

typedef unsigned short u16;
typedef unsigned int   u32;
typedef short bf16x8 __attribute__((ext_vector_type(8)));
typedef short bf16x4 __attribute__((ext_vector_type(4)));
typedef float f32x4  __attribute__((ext_vector_type(4)));
typedef u32   u32x4  __attribute__((ext_vector_type(4)));

#define S_TOT 2048
#define HD    1024
#define QK_SCALE 0.18033688f   // log2(e)/8

#if __has_builtin(__builtin_amdgcn_exp2f)
#define EXP2(x) __builtin_amdgcn_exp2f(x)
#else
#define EXP2(x) exp2f(x)
#endif

__device__ __forceinline__ u16 f2bf(float f) {
  union { float f; unsigned u; } v; v.f = f;
  unsigned r = v.u + 0x7FFFu + ((v.u >> 16) & 1u);
  return (u16)(r >> 16);
}

__device__ __forceinline__ u32 cvt_pk_bf16(float lo, float hi) {
  u32 r;
  asm("v_cvt_pk_bf16_f32 %0, %1, %2" : "=v"(r) : "v"(lo), "v"(hi));
  return r;
}

__device__ __forceinline__ bf16x4 ds_tr16(unsigned a) {
  bf16x4 d;
  asm volatile("ds_read_b64_tr_b16 %0, %1" : "=v"(d) : "v"(a) : "memory");
  return d;
}

__device__ __forceinline__ void gld16(const u16* g, u16* l) {
  __builtin_amdgcn_global_load_lds(
      (const __attribute__((address_space(1))) u32*)g,
      (__attribute__((address_space(3))) u32*)l, 16, 0, 0);
}

// rule #18 fence — now used ONLY by the fallback proj (gemm is asm-free)
#define LGKM_FENCE() do { asm volatile("s_waitcnt lgkmcnt(0)" ::: "memory"); \
                          __builtin_amdgcn_sched_barrier(0); } while (0)

// ---------------------------------------------------------------------------
// conv_kernel: fp32 -> bf16 re-layout.
//  Xb: row-major, intra-32 split-K perm, + XOR swizzle ((row&6)<<2).
//  Wt: W^T tiles [(nb*32+kb)][128 n][32 kperm], same XOR swizzle per n-row.
// ---------------------------------------------------------------------------
__global__ __launch_bounds__(256)
void conv_kernel(const float* __restrict__ x0, const float* __restrict__ x1, const float* __restrict__ x2,
                 const float* __restrict__ w0, const float* __restrict__ w1, const float* __restrict__ w2,
                 u16* __restrict__ Xb, u16* __restrict__ Wt)
{
  const int z = blockIdx.y;
  const int t = threadIdx.x;
  if (blockIdx.x < 1024) {
    const float* X = z == 0 ? x0 : (z == 1 ? x1 : x2);
    u16* Xz = Xb + (size_t)z * 8388608;
    int tid = blockIdx.x * 256 + t;
#pragma unroll
    for (int i = 0; i < 8; ++i) {
      int c = tid + i * 262144;
      int row = c >> 8, k4 = (c & 255) * 4;
      const float4 xv = *(const float4*)&X[(size_t)row * 1024 + k4];
      int p = (k4 & ~31) + 8 * ((k4 & 15) >> 2) + 4 * ((k4 >> 4) & 1);
      p ^= (row & 6) << 2;                       // read-side-matched swizzle
      bf16x4 sv = { (short)f2bf(xv.x), (short)f2bf(xv.y), (short)f2bf(xv.z), (short)f2bf(xv.w) };
      *(bf16x4*)&Xz[(size_t)row * 1024 + p] = sv;
    }
  } else {
    const float* W = z == 0 ? w0 : (z == 1 ? w1 : w2);
    u16* Wz = Wt + (size_t)z * 1048576;
    int tid = (blockIdx.x - 1024) * 256 + t;     // 0..32767
#pragma unroll
    for (int i = 0; i < 8; ++i) {
      int c = tid + i * 32768;                   // 262144 total: (n, k4)
      int n = c & 1023, k4 = (c >> 10) * 4;
      float wv0 = W[(size_t)(k4 + 0) * 1024 + n];
      float wv1 = W[(size_t)(k4 + 1) * 1024 + n];
      float wv2 = W[(size_t)(k4 + 2) * 1024 + n];
      float wv3 = W[(size_t)(k4 + 3) * 1024 + n];
      int kl = k4 & 31;
      int kp = 8 * ((kl & 15) >> 2) + 4 * ((kl >> 4) & 1);
      int off = ((n >> 7) * 32 + (k4 >> 5)) * 4096 + (n & 127) * 32
              + (kp ^ ((n & 6) << 2));
      bf16x4 sv = { (short)f2bf(wv0), (short)f2bf(wv1), (short)f2bf(wv2), (short)f2bf(wv3) };
      *(bf16x4*)&Wz[off] = sv;
    }
  }
}

// ---------------------------------------------------------------------------
// gemm_kernel R13: 2-phase double-buffered, all plain b128 fragment reads
// (XOR-swizzled), no inline asm. z<2: natural out. z==2: swapped -> vT.
// ---------------------------------------------------------------------------
__global__ __launch_bounds__(256)
void gemm_kernel(const u16* __restrict__ Xb, const u16* __restrict__ Wt,
                 const float* __restrict__ b0, const float* __restrict__ b1, const float* __restrict__ b2,
                 u16* __restrict__ o0, u16* __restrict__ o1, u16* __restrict__ vT)
{
  int p  = blockIdx.x + 8 * blockIdx.y + 512 * blockIdx.z;
  int wk = (p & 7) * 192 + (p >> 3);
  int nb = wk & 7, mb = (wk >> 3) & 63, z = wk >> 9;

  const u16* Xz = Xb + (size_t)z * 8388608;
  const u16* Wz = Wt + (size_t)z * 1048576;
  const float* BS = z == 0 ? b0 : (z == 1 ? b1 : b2);
  const float  osc = (z == 0) ? QK_SCALE : 1.0f;

  const int t = threadIdx.x;
  const int lane = t & 63, wid = t >> 6;
  const int g = lane >> 4, ln = lane & 15;
  const int mbase = mb * 128, nbase = nb * 128;
  const int xr = (ln & 6) << 2;                  // read-side swizzle (u16)

  __shared__ __align__(16) u16 Al[2][128 * 32];
  __shared__ __align__(16) u16 Bl[2][128 * 32];

  f32x4 acc[4][4];
#pragma unroll
  for (int i = 0; i < 4; ++i)
#pragma unroll
    for (int j = 0; j < 4; ++j) { acc[i][j][0]=0.f; acc[i][j][1]=0.f; acc[i][j][2]=0.f; acc[i][j][3]=0.f; }

  const u16* sa = Xz + (size_t)(mbase + (t >> 2)) * 1024 + (t & 3) * 8;
  const u16* sb = Wz + (size_t)(nb * 32) * 4096 + t * 8;
  u16* alw[2] = { &Al[0][wid * 512], &Al[1][wid * 512] };
  u16* blw[2] = { &Bl[0][wid * 512], &Bl[1][wid * 512] };

  auto stage = [&](int kb, int buf) __attribute__((always_inline)) {
    gld16(sa + kb * 32,               alw[buf]);
    gld16(sa + kb * 32 + 64 * 1024,   alw[buf] + 2048);
    gld16(sb + kb * 4096,             blw[buf]);
    gld16(sb + kb * 4096 + 2048,      blw[buf] + 2048);
  };

  stage(0, 0);
  __syncthreads();

  if (z < 2) {
    const int wm = wid >> 1, wn = wid & 1;
    u16* O = z == 0 ? o0 : o1;

    auto compute = [&](int cur) __attribute__((always_inline)) {
      bf16x8 af[4], bfv[4];
#pragma unroll
      for (int mf = 0; mf < 4; ++mf)
        af[mf] = *(const bf16x8*)&Al[cur][(wm * 64 + mf * 16 + ln) * 32 + (g * 8 ^ xr)];
#pragma unroll
      for (int nf = 0; nf < 4; ++nf)
        bfv[nf] = *(const bf16x8*)&Bl[cur][(wn * 64 + nf * 16 + ln) * 32 + (g * 8 ^ xr)];
      __builtin_amdgcn_s_setprio(1);
#pragma unroll
      for (int mf = 0; mf < 4; ++mf)
#pragma unroll
        for (int nf = 0; nf < 4; ++nf)
          acc[mf][nf] = __builtin_amdgcn_mfma_f32_16x16x32_bf16(af[mf], bfv[nf], acc[mf][nf], 0, 0, 0);
      __builtin_amdgcn_s_setprio(0);
    };

    for (int kb = 0; kb < 32; kb += 2) {
      if (kb + 1 < 32) stage(kb + 1, 1);
      compute(0);
      __syncthreads();
      if (kb + 2 < 32) stage(kb + 2, 0);
      compute(1);
      __syncthreads();
    }

#pragma unroll
    for (int nf = 0; nf < 4; ++nf) {
      int n = nbase + wn * 64 + nf * 16 + ln;
      float bv = BS[n];
#pragma unroll
      for (int mf = 0; mf < 4; ++mf)
#pragma unroll
        for (int r = 0; r < 4; ++r) {
          int m = mbase + wm * 64 + mf * 16 + 4 * g + r;
          O[(size_t)m * 1024 + n] = f2bf((acc[mf][nf][r] + bv) * osc);
        }
    }
  } else {
    // z==2 swapped: A = W-frag (b128 from Bl), B = X-frag (b128 from Al).
    const int wseq = wid >> 1, wdv = wid & 1;

    auto compute2 = [&](int cur) __attribute__((always_inline)) {
      bf16x8 afw[4], bfx[4];
#pragma unroll
      for (int mf = 0; mf < 4; ++mf)
        afw[mf] = *(const bf16x8*)&Bl[cur][(wdv * 64 + mf * 16 + ln) * 32 + (g * 8 ^ xr)];
#pragma unroll
      for (int nf = 0; nf < 4; ++nf)
        bfx[nf] = *(const bf16x8*)&Al[cur][(wseq * 64 + nf * 16 + ln) * 32 + (g * 8 ^ xr)];
      __builtin_amdgcn_s_setprio(1);
#pragma unroll
      for (int mf = 0; mf < 4; ++mf)
#pragma unroll
        for (int nf = 0; nf < 4; ++nf)
          acc[mf][nf] = __builtin_amdgcn_mfma_f32_16x16x32_bf16(afw[mf], bfx[nf], acc[mf][nf], 0, 0, 0);
      __builtin_amdgcn_s_setprio(0);
    };

    for (int kb = 0; kb < 32; kb += 2) {
      if (kb + 1 < 32) stage(kb + 1, 1);
      compute2(0);
      __syncthreads();
      if (kb + 2 < 32) stage(kb + 2, 0);
      compute2(1);
      __syncthreads();
    }

#pragma unroll
    for (int mf = 0; mf < 4; ++mf)
#pragma unroll
      for (int r = 0; r < 4; ++r) {
        int dvg = nbase + wdv * 64 + mf * 16 + 4 * g + r;
        float bv = BS[dvg];
        int hh = dvg >> 6, dvl = dvg & 63;
#pragma unroll
        for (int nf = 0; nf < 4; ++nf) {
          int m = mbase + wseq * 64 + nf * 16 + ln;
          int bb = m >> 11, ss = m & 2047;
          vT[((size_t)(bb * 16 + hh) * 64 + dvl) * 2048 + ss] = f2bf(acc[mf][nf][r] + bv);
        }
      }
  }
}

// ---------------------------------------------------------------------------
// Fallback proj (frozen; reads original X/W; z==2 transposed scatter).
// ---------------------------------------------------------------------------
__global__ __launch_bounds__(256)
void proj_kernel(const float* __restrict__ x0, const float* __restrict__ x1, const float* __restrict__ x2,
                 const float* __restrict__ w0, const float* __restrict__ w1, const float* __restrict__ w2,
                 const float* __restrict__ b0, const float* __restrict__ b1, const float* __restrict__ b2,
                 u16* __restrict__ o0, u16* __restrict__ o1, u16* __restrict__ vT)
{
  int p  = blockIdx.x + 8 * blockIdx.y + 512 * blockIdx.z;
  int wk = (p & 7) * 192 + (p >> 3);
  int nb = wk & 7, mb = (wk >> 3) & 63, z = wk >> 9;

  const float* X  = z == 0 ? x0 : (z == 1 ? x1 : x2);
  const float* W  = z == 0 ? w0 : (z == 1 ? w1 : w2);
  const float* BS = z == 0 ? b0 : (z == 1 ? b1 : b2);
  const float  osc = (z == 0) ? QK_SCALE : 1.0f;

  const int t = threadIdx.x;
  const int lane = t & 63, wid = t >> 6;
  const int g = lane >> 4, ln = lane & 15;
  const int wm = wid >> 1, wn = wid & 1;
  const int mbase = mb * 128, nbase = nb * 128;

  __shared__ __align__(16) u16 As[128 * 40];
  __shared__ __align__(16) u16 Bs[16 * 272];

  f32x4 acc[4][4];
#pragma unroll
  for (int i = 0; i < 4; ++i)
#pragma unroll
    for (int j = 0; j < 4; ++j) { acc[i][j][0]=0.f; acc[i][j][1]=0.f; acc[i][j][2]=0.f; acc[i][j][3]=0.f; }

  const int arow = t >> 3;
  const int ak0  = (t & 7) * 4;
  const int ap   = 8 * ((ak0 & 15) >> 2) + 4 * (ak0 >> 4);
  const int bkr  = t >> 5;
  const int bnc  = (t & 31) * 4;
  const int bnblk = bnc >> 4, bncl = bnc & 15;

  const unsigned bs_base = (unsigned)(size_t)&Bs[0];

  for (int kb = 0; kb < 32; ++kb) {
    const int kbase = kb * 32;
#pragma unroll
    for (int ps = 0; ps < 4; ++ps) {
      int row = arow + 32 * ps;
      const float4 xv = *(const float4*)&X[(size_t)(mbase + row) * 1024 + kbase + ak0];
      bf16x4 sv = { (short)f2bf(xv.x), (short)f2bf(xv.y), (short)f2bf(xv.z), (short)f2bf(xv.w) };
      *(bf16x4*)&As[row * 40 + ap] = sv;
    }
#pragma unroll
    for (int ps = 0; ps < 4; ++ps) {
      int kr = bkr + 8 * ps;
      const float4 wv = *(const float4*)&W[(size_t)(kbase + kr) * 1024 + nbase + bnc];
      bf16x4 sv = { (short)f2bf(wv.x), (short)f2bf(wv.y), (short)f2bf(wv.z), (short)f2bf(wv.w) };
      *(bf16x4*)&Bs[(bnblk * 2 + (kr >> 4)) * 272 + (kr & 15) * 16 + bncl] = sv;
    }
    __syncthreads();

    bf16x8 af[4];
#pragma unroll
    for (int mf = 0; mf < 4; ++mf)
      af[mf] = *(const bf16x8*)&As[(wm * 64 + mf * 16 + ln) * 40 + g * 8];

    bf16x8 bfv[4];
#pragma unroll
    for (int nf = 0; nf < 4; ++nf) {
      unsigned base = bs_base + (unsigned)(((wn * 4 + nf) * 2) * 544) + lane * 8;
      bf16x4 lo = ds_tr16(base);
      bf16x4 hi = ds_tr16(base + 544);
      bf16x8 bb;
      bb[0]=lo[0]; bb[1]=lo[1]; bb[2]=lo[2]; bb[3]=lo[3];
      bb[4]=hi[0]; bb[5]=hi[1]; bb[6]=hi[2]; bb[7]=hi[3];
      bfv[nf] = bb;
    }
    LGKM_FENCE();
#pragma unroll
    for (int mf = 0; mf < 4; ++mf)
#pragma unroll
      for (int nf = 0; nf < 4; ++nf)
        acc[mf][nf] = __builtin_amdgcn_mfma_f32_16x16x32_bf16(af[mf], bfv[nf], acc[mf][nf], 0, 0, 0);
    __syncthreads();
  }

#pragma unroll
  for (int nf = 0; nf < 4; ++nf) {
    int n = nbase + wn * 64 + nf * 16 + ln;
    float bv = BS[n];
#pragma unroll
    for (int mf = 0; mf < 4; ++mf)
#pragma unroll
      for (int r = 0; r < 4; ++r) {
        int m = mbase + wm * 64 + mf * 16 + 4 * g + r;
        float val = (acc[mf][nf][r] + bv) * osc;
        if (z < 2) {
          u16* O = z == 0 ? o0 : o1;
          O[(size_t)m * 1024 + n] = f2bf(val);
        } else {
          vT[((size_t)((m >> 11) * 16 + (n >> 6)) * 64 + (n & 63)) * 2048 + (m & 2047)] = f2bf(val);
        }
      }
  }
}

// ---------------------------------------------------------------------------
// Attention (R11, frozen): V^T LDS, plain b128 V-frags, no asm/fences in loop.
// 8 waves, QBLK=256, KVBLK=64, 2-barrier protocol, ones-MFMA rowsum, setprio.
// ---------------------------------------------------------------------------
__global__ __launch_bounds__(512)
void attn_kernel(const u16* __restrict__ qh, const u16* __restrict__ kh, const u16* __restrict__ vT,
                 float* __restrict__ out)
{
  int p  = blockIdx.x + 8 * blockIdx.y + 128 * blockIdx.z;
  int wk = (p & 7) * 64 + (p >> 3);
  int qt = wk & 7, h = (wk >> 3) & 15, b = wk >> 7;

  const int t = threadIdx.x;
  const int lane = t & 63, wid = t >> 6;
  const int g = lane >> 4, ln = lane & 15;
  const size_t bS = (size_t)b * S_TOT;
  const int qwin = qt * 256 + wid * 32;

  __shared__ __align__(16) u16 Ks[64 * 72];
  __shared__ __align__(16) u16 Vt[64 * 72];

  bf16x8 qf[2][2];
#pragma unroll
  for (int nf = 0; nf < 2; ++nf) {
    const u16* qrow = &qh[(bS + qwin + nf * 16 + ln) * HD + h * 64];
#pragma unroll
    for (int kk = 0; kk < 2; ++kk) {
      bf16x4 lo = *(const bf16x4*)&qrow[kk * 32 + 4 * g];
      bf16x4 hi = *(const bf16x4*)&qrow[kk * 32 + 4 * g + 16];
      bf16x8 qq;
      qq[0]=lo[0]; qq[1]=lo[1]; qq[2]=lo[2]; qq[3]=lo[3];
      qq[4]=hi[0]; qq[5]=hi[1]; qq[6]=hi[2]; qq[7]=hi[3];
      qf[nf][kk] = qq;
    }
  }

  bf16x8 ones;
#pragma unroll
  for (int j = 0; j < 8; ++j) ones[j] = (short)0x3F80;

  f32x4 o[2][4];
#pragma unroll
  for (int i = 0; i < 2; ++i)
#pragma unroll
    for (int j = 0; j < 4; ++j) { o[i][j][0]=0.f; o[i][j][1]=0.f; o[i][j][2]=0.f; o[i][j][3]=0.f; }
  f32x4 o1[2];
  o1[0][0]=0.f; o1[0][1]=0.f; o1[0][2]=0.f; o1[0][3]=0.f;
  o1[1][0]=0.f; o1[1][1]=0.f; o1[1][2]=0.f; o1[1][3]=0.f;

  const int skv = t >> 4;
  const int sd0 = (t & 15) * 4;
  const int kpos = 32 * (sd0 >> 5) + 8 * ((sd0 & 15) >> 2) + 4 * ((sd0 >> 4) & 1);
  u16* ksw[2];
  ksw[0] = &Ks[skv * 72 + kpos];
  ksw[1] = &Ks[(skv + 32) * 72 + kpos];
  const u16* kp = &kh[(bS + skv) * HD + h * 64 + sd0];

  const int vdv  = t >> 3;
  const int vkv8 = (t & 7) * 8;
  const int vp0  = 32 * (vkv8 >> 5) + 8 * ((vkv8 & 15) >> 2) + 4 * ((vkv8 >> 4) & 1);
  const int vkv4 = vkv8 + 4;
  const int vp1  = 32 * (vkv4 >> 5) + 8 * ((vkv4 & 15) >> 2) + 4 * ((vkv4 >> 4) & 1);
  u16* vsw0 = &Vt[vdv * 72 + vp0];
  u16* vsw1 = &Vt[vdv * 72 + vp1];
  const u16* vp = &vT[((size_t)(b * 16 + h) * 64 + vdv) * 2048 + vkv8];

  const size_t KSTEP = (size_t)64 * HD, C32 = (size_t)32 * HD;

  bf16x4 kr[2];
  kr[0] = *(const bf16x4*)kp; kr[1] = *(const bf16x4*)(kp + C32);
  bf16x8 vr = *(const bf16x8*)vp;
  kp += KSTEP; vp += 64;

  for (int it = 0; it < 32; ++it) {
    *(bf16x4*)ksw[0] = kr[0];
    *(bf16x4*)ksw[1] = kr[1];
    bf16x4 vlo = { vr[0], vr[1], vr[2], vr[3] };
    bf16x4 vhi = { vr[4], vr[5], vr[6], vr[7] };
    *(bf16x4*)vsw0 = vlo;
    *(bf16x4*)vsw1 = vhi;
    __syncthreads();

    if (it < 31) {
      kr[0] = *(const bf16x4*)kp; kr[1] = *(const bf16x4*)(kp + C32);
      vr = *(const bf16x8*)vp;
      kp += KSTEP; vp += 64;
    }

#pragma unroll
    for (int s = 0; s < 2; ++s) {
      bf16x8 kf[2][2];
#pragma unroll
      for (int mf = 0; mf < 2; ++mf)
#pragma unroll
        for (int kk = 0; kk < 2; ++kk)
          kf[mf][kk] = *(const bf16x8*)&Ks[(s * 32 + mf * 16 + ln) * 72 + kk * 32 + 8 * g];

      f32x4 sc[2][2];
      __builtin_amdgcn_s_setprio(1);
#pragma unroll
      for (int mf = 0; mf < 2; ++mf)
#pragma unroll
        for (int nf = 0; nf < 2; ++nf) {
          f32x4 a; a[0]=0.f; a[1]=0.f; a[2]=0.f; a[3]=0.f;
#pragma unroll
          for (int kk = 0; kk < 2; ++kk)
            a = __builtin_amdgcn_mfma_f32_16x16x32_bf16(kf[mf][kk], qf[nf][kk], a, 0, 0, 0);
          sc[mf][nf] = a;
        }
      __builtin_amdgcn_s_setprio(0);

      bf16x8 vf[4];
#pragma unroll
      for (int nf = 0; nf < 4; ++nf)
        vf[nf] = *(const bf16x8*)&Vt[(nf * 16 + ln) * 72 + s * 32 + 8 * g];

      bf16x8 pa[2];
#pragma unroll
      for (int nf = 0; nf < 2; ++nf) {
        float pv[2][4];
#pragma unroll
        for (int mf = 0; mf < 2; ++mf)
#pragma unroll
          for (int r = 0; r < 4; ++r)
            pv[mf][r] = EXP2(sc[mf][nf][r]);
        union { u32x4 u; bf16x8 b; } pk;
        pk.u[0] = cvt_pk_bf16(pv[0][0], pv[0][1]);
        pk.u[1] = cvt_pk_bf16(pv[0][2], pv[0][3]);
        pk.u[2] = cvt_pk_bf16(pv[1][0], pv[1][1]);
        pk.u[3] = cvt_pk_bf16(pv[1][2], pv[1][3]);
        pa[nf] = pk.b;
      }

      __builtin_amdgcn_s_setprio(1);
#pragma unroll
      for (int mq = 0; mq < 2; ++mq) {
#pragma unroll
        for (int nf = 0; nf < 4; ++nf)
          o[mq][nf] = __builtin_amdgcn_mfma_f32_16x16x32_bf16(pa[mq], vf[nf], o[mq][nf], 0, 0, 0);
        o1[mq] = __builtin_amdgcn_mfma_f32_16x16x32_bf16(pa[mq], ones, o1[mq], 0, 0, 0);
      }
      __builtin_amdgcn_s_setprio(0);
    }
    __syncthreads();
  }

#pragma unroll
  for (int mq = 0; mq < 2; ++mq)
#pragma unroll
    for (int r = 0; r < 4; ++r) {
      float inv = 1.0f / o1[mq][r];
      int qrow = qwin + mq * 16 + 4 * g + r;
#pragma unroll
      for (int nf = 0; nf < 4; ++nf)
        out[(bS + qrow) * HD + h * 64 + nf * 16 + ln] = o[mq][nf][r] * inv;
    }
}

extern "C" void kernel_launch(void* const* d_in, const int* in_sizes, int n_in,
                              void* d_out, int out_size, void* d_ws, size_t ws_size,
                              hipStream_t stream) {
  const float* q  = (const float*)d_in[0];
  const float* k  = (const float*)d_in[1];
  const float* v  = (const float*)d_in[2];
  const float* Wq = (const float*)d_in[3];
  const float* bq = (const float*)d_in[4];
  const float* Wk = (const float*)d_in[5];
  const float* bk = (const float*)d_in[6];
  const float* Wv = (const float*)d_in[7];
  const float* bv = (const float*)d_in[8];
  float* out = (float*)d_out;

  u16* qh = (u16*)d_ws;
  u16* kh = qh + (size_t)8192 * 1024;
  u16* vT = kh + (size_t)8192 * 1024;     // [b][h][dv][seq]

  const size_t XB_OFF = (size_t)3 * 8192 * 1024;
  const size_t WT_OFF = XB_OFF + (size_t)3 * 8192 * 1024;
  const size_t NEED   = (WT_OFF + (size_t)3 * 1024 * 1024) * 2;

  if (ws_size >= NEED) {
    u16* Xb = (u16*)d_ws + XB_OFF;
    u16* Wt = (u16*)d_ws + WT_OFF;
    conv_kernel<<<dim3(1152, 3), 256, 0, stream>>>(q, k, v, Wq, Wk, Wv, Xb, Wt);
    gemm_kernel<<<dim3(8, 64, 3), 256, 0, stream>>>(Xb, Wt, bq, bk, bv, qh, kh, vT);
  } else {
    proj_kernel<<<dim3(8, 64, 3), 256, 0, stream>>>(q, k, v, Wq, Wk, Wv, bq, bk, bv, qh, kh, vT);
  }
  attn_kernel<<<dim3(8, 16, 4), 512, 0, stream>>>(qh, kh, vT, out);
}

// Round 14
// 171.006 us; speedup vs baseline: 1.3219x; 1.0010x over previous
//
#include <hip/hip_runtime.h>
#include <hip/hip_bf16.h>

// MultiHeadAttention: B=4 S=2048 D=1024 H=16 DK=DV=64 scale=8
// R14: gemm = T4 counted-vmcnt pipeline (m218: counted-vs-drain0 +38-73%).
// 3 LDS buffers; stage(t+2) issued in phase t; end-of-phase sync is
// s_waitcnt vmcnt(4) + raw s_barrier (NOT __syncthreads' vmcnt(0) drain) —
// the 4 newest DMAs (tile t+2) stay in flight across the barrier; in-order
// vmcnt retire guarantees tile t+1 landed. R13 evidence: conflicts 0, fence
// gone, still 608 TF == m233's 2-phase number -> barrier drain is the wall.
// attn/conv/proj frozen.

typedef unsigned short u16;
typedef unsigned int   u32;
typedef short bf16x8 __attribute__((ext_vector_type(8)));
typedef short bf16x4 __attribute__((ext_vector_type(4)));
typedef float f32x4  __attribute__((ext_vector_type(4)));
typedef u32   u32x4  __attribute__((ext_vector_type(4)));

#define S_TOT 2048
#define HD    1024
#define QK_SCALE 0.18033688f   // log2(e)/8

#if __has_builtin(__builtin_amdgcn_exp2f)
#define EXP2(x) __builtin_amdgcn_exp2f(x)
#else
#define EXP2(x) exp2f(x)
#endif

__device__ __forceinline__ u16 f2bf(float f) {
  union { float f; unsigned u; } v; v.f = f;
  unsigned r = v.u + 0x7FFFu + ((v.u >> 16) & 1u);
  return (u16)(r >> 16);
}

__device__ __forceinline__ u32 cvt_pk_bf16(float lo, float hi) {
  u32 r;
  asm("v_cvt_pk_bf16_f32 %0, %1, %2" : "=v"(r) : "v"(lo), "v"(hi));
  return r;
}

__device__ __forceinline__ bf16x4 ds_tr16(unsigned a) {
  bf16x4 d;
  asm volatile("ds_read_b64_tr_b16 %0, %1" : "=v"(d) : "v"(a) : "memory");
  return d;
}

__device__ __forceinline__ void gld16(const u16* g, u16* l) {
  __builtin_amdgcn_global_load_lds(
      (const __attribute__((address_space(1))) u32*)g,
      (__attribute__((address_space(3))) u32*)l, 16, 0, 0);
}

// rule #18 fence — used ONLY by the fallback proj
#define LGKM_FENCE() do { asm volatile("s_waitcnt lgkmcnt(0)" ::: "memory"); \
                          __builtin_amdgcn_sched_barrier(0); } while (0)

// counted-vmcnt phase boundary: keep N newest DMAs in flight across barrier
#define PIPE_BAR(N) do { asm volatile("s_waitcnt vmcnt(" #N ")" ::: "memory"); \
                         __builtin_amdgcn_s_barrier(); \
                         __builtin_amdgcn_sched_barrier(0); } while (0)

// ---------------------------------------------------------------------------
// conv_kernel (frozen): fp32 -> bf16 re-layout.
//  Xb: row-major, intra-32 split-K perm, + XOR swizzle ((row&6)<<2).
//  Wt: W^T tiles [(nb*32+kb)][128 n][32 kperm], same XOR swizzle per n-row.
// ---------------------------------------------------------------------------
__global__ __launch_bounds__(256)
void conv_kernel(const float* __restrict__ x0, const float* __restrict__ x1, const float* __restrict__ x2,
                 const float* __restrict__ w0, const float* __restrict__ w1, const float* __restrict__ w2,
                 u16* __restrict__ Xb, u16* __restrict__ Wt)
{
  const int z = blockIdx.y;
  const int t = threadIdx.x;
  if (blockIdx.x < 1024) {
    const float* X = z == 0 ? x0 : (z == 1 ? x1 : x2);
    u16* Xz = Xb + (size_t)z * 8388608;
    int tid = blockIdx.x * 256 + t;
#pragma unroll
    for (int i = 0; i < 8; ++i) {
      int c = tid + i * 262144;
      int row = c >> 8, k4 = (c & 255) * 4;
      const float4 xv = *(const float4*)&X[(size_t)row * 1024 + k4];
      int p = (k4 & ~31) + 8 * ((k4 & 15) >> 2) + 4 * ((k4 >> 4) & 1);
      p ^= (row & 6) << 2;
      bf16x4 sv = { (short)f2bf(xv.x), (short)f2bf(xv.y), (short)f2bf(xv.z), (short)f2bf(xv.w) };
      *(bf16x4*)&Xz[(size_t)row * 1024 + p] = sv;
    }
  } else {
    const float* W = z == 0 ? w0 : (z == 1 ? w1 : w2);
    u16* Wz = Wt + (size_t)z * 1048576;
    int tid = (blockIdx.x - 1024) * 256 + t;
#pragma unroll
    for (int i = 0; i < 8; ++i) {
      int c = tid + i * 32768;
      int n = c & 1023, k4 = (c >> 10) * 4;
      float wv0 = W[(size_t)(k4 + 0) * 1024 + n];
      float wv1 = W[(size_t)(k4 + 1) * 1024 + n];
      float wv2 = W[(size_t)(k4 + 2) * 1024 + n];
      float wv3 = W[(size_t)(k4 + 3) * 1024 + n];
      int kl = k4 & 31;
      int kp = 8 * ((kl & 15) >> 2) + 4 * ((kl >> 4) & 1);
      int off = ((n >> 7) * 32 + (k4 >> 5)) * 4096 + (n & 127) * 32
              + (kp ^ ((n & 6) << 2));
      bf16x4 sv = { (short)f2bf(wv0), (short)f2bf(wv1), (short)f2bf(wv2), (short)f2bf(wv3) };
      *(bf16x4*)&Wz[off] = sv;
    }
  }
}

// ---------------------------------------------------------------------------
// gemm_kernel R14: 3-buffer counted-vmcnt pipeline, all-plain-b128 swizzled
// fragment reads, no drain-0 in the main loop. z<2: natural out. z==2 -> vT.
// ---------------------------------------------------------------------------
__global__ __launch_bounds__(256)
void gemm_kernel(const u16* __restrict__ Xb, const u16* __restrict__ Wt,
                 const float* __restrict__ b0, const float* __restrict__ b1, const float* __restrict__ b2,
                 u16* __restrict__ o0, u16* __restrict__ o1, u16* __restrict__ vT)
{
  int p  = blockIdx.x + 8 * blockIdx.y + 512 * blockIdx.z;
  int wk = (p & 7) * 192 + (p >> 3);
  int nb = wk & 7, mb = (wk >> 3) & 63, z = wk >> 9;

  const u16* Xz = Xb + (size_t)z * 8388608;
  const u16* Wz = Wt + (size_t)z * 1048576;
  const float* BS = z == 0 ? b0 : (z == 1 ? b1 : b2);
  const float  osc = (z == 0) ? QK_SCALE : 1.0f;

  const int t = threadIdx.x;
  const int lane = t & 63, wid = t >> 6;
  const int g = lane >> 4, ln = lane & 15;
  const int mbase = mb * 128, nbase = nb * 128;
  const int xr = (ln & 6) << 2;                  // read-side swizzle (u16)

  __shared__ __align__(16) u16 Al[3][128 * 32];  // 3 x 8KB
  __shared__ __align__(16) u16 Bl[3][128 * 32];  // 3 x 8KB

  f32x4 acc[4][4];
#pragma unroll
  for (int i = 0; i < 4; ++i)
#pragma unroll
    for (int j = 0; j < 4; ++j) { acc[i][j][0]=0.f; acc[i][j][1]=0.f; acc[i][j][2]=0.f; acc[i][j][3]=0.f; }

  const u16* sa = Xz + (size_t)(mbase + (t >> 2)) * 1024 + (t & 3) * 8;
  const u16* sb = Wz + (size_t)(nb * 32) * 4096 + t * 8;
  u16* alw[3] = { &Al[0][wid * 512], &Al[1][wid * 512], &Al[2][wid * 512] };
  u16* blw[3] = { &Bl[0][wid * 512], &Bl[1][wid * 512], &Bl[2][wid * 512] };

  auto stage = [&](int kb, int buf) __attribute__((always_inline)) {
    gld16(sa + kb * 32,               alw[buf]);
    gld16(sa + kb * 32 + 64 * 1024,   alw[buf] + 2048);
    gld16(sb + kb * 4096,             blw[buf]);
    gld16(sb + kb * 4096 + 2048,      blw[buf] + 2048);
  };

  // prologue: tiles 0,1 staged; wait tile 0 (keep tile 1's 4 DMAs in flight)
  stage(0, 0);
  stage(1, 1);
  PIPE_BAR(4);

  if (z < 2) {
    const int wm = wid >> 1, wn = wid & 1;
    u16* O = z == 0 ? o0 : o1;

    auto compute = [&](int cur) __attribute__((always_inline)) {
      bf16x8 af[4], bfv[4];
#pragma unroll
      for (int mf = 0; mf < 4; ++mf)
        af[mf] = *(const bf16x8*)&Al[cur][(wm * 64 + mf * 16 + ln) * 32 + (g * 8 ^ xr)];
#pragma unroll
      for (int nf = 0; nf < 4; ++nf)
        bfv[nf] = *(const bf16x8*)&Bl[cur][(wn * 64 + nf * 16 + ln) * 32 + (g * 8 ^ xr)];
      __builtin_amdgcn_s_setprio(1);
#pragma unroll
      for (int mf = 0; mf < 4; ++mf)
#pragma unroll
        for (int nf = 0; nf < 4; ++nf)
          acc[mf][nf] = __builtin_amdgcn_mfma_f32_16x16x32_bf16(af[mf], bfv[nf], acc[mf][nf], 0, 0, 0);
      __builtin_amdgcn_s_setprio(0);
    };

    // phases 0..29: stage(t+2), compute(t), vmcnt(4)+barrier
    for (int kb = 0; kb < 30; kb += 3) {
      stage(kb + 2, 2); compute(0); PIPE_BAR(4);
      stage(kb + 3, 0); compute(1); PIPE_BAR(4);
      stage(kb + 4, 1); compute(2); PIPE_BAR(4);
    }
    // epilogue: phase 30 (wait tile 31 fully), phase 31
    compute(0); PIPE_BAR(0);
    compute(1);

#pragma unroll
    for (int nf = 0; nf < 4; ++nf) {
      int n = nbase + wn * 64 + nf * 16 + ln;
      float bv = BS[n];
#pragma unroll
      for (int mf = 0; mf < 4; ++mf)
#pragma unroll
        for (int r = 0; r < 4; ++r) {
          int m = mbase + wm * 64 + mf * 16 + 4 * g + r;
          O[(size_t)m * 1024 + n] = f2bf((acc[mf][nf][r] + bv) * osc);
        }
    }
  } else {
    // z==2 swapped: A = W-frag (b128 from Bl), B = X-frag (b128 from Al).
    const int wseq = wid >> 1, wdv = wid & 1;

    auto compute2 = [&](int cur) __attribute__((always_inline)) {
      bf16x8 afw[4], bfx[4];
#pragma unroll
      for (int mf = 0; mf < 4; ++mf)
        afw[mf] = *(const bf16x8*)&Bl[cur][(wdv * 64 + mf * 16 + ln) * 32 + (g * 8 ^ xr)];
#pragma unroll
      for (int nf = 0; nf < 4; ++nf)
        bfx[nf] = *(const bf16x8*)&Al[cur][(wseq * 64 + nf * 16 + ln) * 32 + (g * 8 ^ xr)];
      __builtin_amdgcn_s_setprio(1);
#pragma unroll
      for (int mf = 0; mf < 4; ++mf)
#pragma unroll
        for (int nf = 0; nf < 4; ++nf)
          acc[mf][nf] = __builtin_amdgcn_mfma_f32_16x16x32_bf16(afw[mf], bfx[nf], acc[mf][nf], 0, 0, 0);
      __builtin_amdgcn_s_setprio(0);
    };

    for (int kb = 0; kb < 30; kb += 3) {
      stage(kb + 2, 2); compute2(0); PIPE_BAR(4);
      stage(kb + 3, 0); compute2(1); PIPE_BAR(4);
      stage(kb + 4, 1); compute2(2); PIPE_BAR(4);
    }
    compute2(0); PIPE_BAR(0);
    compute2(1);

#pragma unroll
    for (int mf = 0; mf < 4; ++mf)
#pragma unroll
      for (int r = 0; r < 4; ++r) {
        int dvg = nbase + wdv * 64 + mf * 16 + 4 * g + r;
        float bv = BS[dvg];
        int hh = dvg >> 6, dvl = dvg & 63;
#pragma unroll
        for (int nf = 0; nf < 4; ++nf) {
          int m = mbase + wseq * 64 + nf * 16 + ln;
          int bb = m >> 11, ss = m & 2047;
          vT[((size_t)(bb * 16 + hh) * 64 + dvl) * 2048 + ss] = f2bf(acc[mf][nf][r] + bv);
        }
      }
  }
}

// ---------------------------------------------------------------------------
// Fallback proj (frozen; reads original X/W; z==2 transposed scatter).
// ---------------------------------------------------------------------------
__global__ __launch_bounds__(256)
void proj_kernel(const float* __restrict__ x0, const float* __restrict__ x1, const float* __restrict__ x2,
                 const float* __restrict__ w0, const float* __restrict__ w1, const float* __restrict__ w2,
                 const float* __restrict__ b0, const float* __restrict__ b1, const float* __restrict__ b2,
                 u16* __restrict__ o0, u16* __restrict__ o1, u16* __restrict__ vT)
{
  int p  = blockIdx.x + 8 * blockIdx.y + 512 * blockIdx.z;
  int wk = (p & 7) * 192 + (p >> 3);
  int nb = wk & 7, mb = (wk >> 3) & 63, z = wk >> 9;

  const float* X  = z == 0 ? x0 : (z == 1 ? x1 : x2);
  const float* W  = z == 0 ? w0 : (z == 1 ? w1 : w2);
  const float* BS = z == 0 ? b0 : (z == 1 ? b1 : b2);
  const float  osc = (z == 0) ? QK_SCALE : 1.0f;

  const int t = threadIdx.x;
  const int lane = t & 63, wid = t >> 6;
  const int g = lane >> 4, ln = lane & 15;
  const int wm = wid >> 1, wn = wid & 1;
  const int mbase = mb * 128, nbase = nb * 128;

  __shared__ __align__(16) u16 As[128 * 40];
  __shared__ __align__(16) u16 Bs[16 * 272];

  f32x4 acc[4][4];
#pragma unroll
  for (int i = 0; i < 4; ++i)
#pragma unroll
    for (int j = 0; j < 4; ++j) { acc[i][j][0]=0.f; acc[i][j][1]=0.f; acc[i][j][2]=0.f; acc[i][j][3]=0.f; }

  const int arow = t >> 3;
  const int ak0  = (t & 7) * 4;
  const int ap   = 8 * ((ak0 & 15) >> 2) + 4 * (ak0 >> 4);
  const int bkr  = t >> 5;
  const int bnc  = (t & 31) * 4;
  const int bnblk = bnc >> 4, bncl = bnc & 15;

  const unsigned bs_base = (unsigned)(size_t)&Bs[0];

  for (int kb = 0; kb < 32; ++kb) {
    const int kbase = kb * 32;
#pragma unroll
    for (int ps = 0; ps < 4; ++ps) {
      int row = arow + 32 * ps;
      const float4 xv = *(const float4*)&X[(size_t)(mbase + row) * 1024 + kbase + ak0];
      bf16x4 sv = { (short)f2bf(xv.x), (short)f2bf(xv.y), (short)f2bf(xv.z), (short)f2bf(xv.w) };
      *(bf16x4*)&As[row * 40 + ap] = sv;
    }
#pragma unroll
    for (int ps = 0; ps < 4; ++ps) {
      int kr = bkr + 8 * ps;
      const float4 wv = *(const float4*)&W[(size_t)(kbase + kr) * 1024 + nbase + bnc];
      bf16x4 sv = { (short)f2bf(wv.x), (short)f2bf(wv.y), (short)f2bf(wv.z), (short)f2bf(wv.w) };
      *(bf16x4*)&Bs[(bnblk * 2 + (kr >> 4)) * 272 + (kr & 15) * 16 + bncl] = sv;
    }
    __syncthreads();

    bf16x8 af[4];
#pragma unroll
    for (int mf = 0; mf < 4; ++mf)
      af[mf] = *(const bf16x8*)&As[(wm * 64 + mf * 16 + ln) * 40 + g * 8];

    bf16x8 bfv[4];
#pragma unroll
    for (int nf = 0; nf < 4; ++nf) {
      unsigned base = bs_base + (unsigned)(((wn * 4 + nf) * 2) * 544) + lane * 8;
      bf16x4 lo = ds_tr16(base);
      bf16x4 hi = ds_tr16(base + 544);
      bf16x8 bb;
      bb[0]=lo[0]; bb[1]=lo[1]; bb[2]=lo[2]; bb[3]=lo[3];
      bb[4]=hi[0]; bb[5]=hi[1]; bb[6]=hi[2]; bb[7]=hi[3];
      bfv[nf] = bb;
    }
    LGKM_FENCE();
#pragma unroll
    for (int mf = 0; mf < 4; ++mf)
#pragma unroll
      for (int nf = 0; nf < 4; ++nf)
        acc[mf][nf] = __builtin_amdgcn_mfma_f32_16x16x32_bf16(af[mf], bfv[nf], acc[mf][nf], 0, 0, 0);
    __syncthreads();
  }

#pragma unroll
  for (int nf = 0; nf < 4; ++nf) {
    int n = nbase + wn * 64 + nf * 16 + ln;
    float bv = BS[n];
#pragma unroll
    for (int mf = 0; mf < 4; ++mf)
#pragma unroll
      for (int r = 0; r < 4; ++r) {
        int m = mbase + wm * 64 + mf * 16 + 4 * g + r;
        float val = (acc[mf][nf][r] + bv) * osc;
        if (z < 2) {
          u16* O = z == 0 ? o0 : o1;
          O[(size_t)m * 1024 + n] = f2bf(val);
        } else {
          vT[((size_t)((m >> 11) * 16 + (n >> 6)) * 64 + (n & 63)) * 2048 + (m & 2047)] = f2bf(val);
        }
      }
  }
}

// ---------------------------------------------------------------------------
// Attention (R11, frozen): V^T LDS, plain b128 V-frags, no asm/fences in loop.
// 8 waves, QBLK=256, KVBLK=64, 2-barrier protocol, ones-MFMA rowsum, setprio.
// ---------------------------------------------------------------------------
__global__ __launch_bounds__(512)
void attn_kernel(const u16* __restrict__ qh, const u16* __restrict__ kh, const u16* __restrict__ vT,
                 float* __restrict__ out)
{
  int p  = blockIdx.x + 8 * blockIdx.y + 128 * blockIdx.z;
  int wk = (p & 7) * 64 + (p >> 3);
  int qt = wk & 7, h = (wk >> 3) & 15, b = wk >> 7;

  const int t = threadIdx.x;
  const int lane = t & 63, wid = t >> 6;
  const int g = lane >> 4, ln = lane & 15;
  const size_t bS = (size_t)b * S_TOT;
  const int qwin = qt * 256 + wid * 32;

  __shared__ __align__(16) u16 Ks[64 * 72];
  __shared__ __align__(16) u16 Vt[64 * 72];

  bf16x8 qf[2][2];
#pragma unroll
  for (int nf = 0; nf < 2; ++nf) {
    const u16* qrow = &qh[(bS + qwin + nf * 16 + ln) * HD + h * 64];
#pragma unroll
    for (int kk = 0; kk < 2; ++kk) {
      bf16x4 lo = *(const bf16x4*)&qrow[kk * 32 + 4 * g];
      bf16x4 hi = *(const bf16x4*)&qrow[kk * 32 + 4 * g + 16];
      bf16x8 qq;
      qq[0]=lo[0]; qq[1]=lo[1]; qq[2]=lo[2]; qq[3]=lo[3];
      qq[4]=hi[0]; qq[5]=hi[1]; qq[6]=hi[2]; qq[7]=hi[3];
      qf[nf][kk] = qq;
    }
  }

  bf16x8 ones;
#pragma unroll
  for (int j = 0; j < 8; ++j) ones[j] = (short)0x3F80;

  f32x4 o[2][4];
#pragma unroll
  for (int i = 0; i < 2; ++i)
#pragma unroll
    for (int j = 0; j < 4; ++j) { o[i][j][0]=0.f; o[i][j][1]=0.f; o[i][j][2]=0.f; o[i][j][3]=0.f; }
  f32x4 o1[2];
  o1[0][0]=0.f; o1[0][1]=0.f; o1[0][2]=0.f; o1[0][3]=0.f;
  o1[1][0]=0.f; o1[1][1]=0.f; o1[1][2]=0.f; o1[1][3]=0.f;

  const int skv = t >> 4;
  const int sd0 = (t & 15) * 4;
  const int kpos = 32 * (sd0 >> 5) + 8 * ((sd0 & 15) >> 2) + 4 * ((sd0 >> 4) & 1);
  u16* ksw[2];
  ksw[0] = &Ks[skv * 72 + kpos];
  ksw[1] = &Ks[(skv + 32) * 72 + kpos];
  const u16* kp = &kh[(bS + skv) * HD + h * 64 + sd0];

  const int vdv  = t >> 3;
  const int vkv8 = (t & 7) * 8;
  const int vp0  = 32 * (vkv8 >> 5) + 8 * ((vkv8 & 15) >> 2) + 4 * ((vkv8 >> 4) & 1);
  const int vkv4 = vkv8 + 4;
  const int vp1  = 32 * (vkv4 >> 5) + 8 * ((vkv4 & 15) >> 2) + 4 * ((vkv4 >> 4) & 1);
  u16* vsw0 = &Vt[vdv * 72 + vp0];
  u16* vsw1 = &Vt[vdv * 72 + vp1];
  const u16* vp = &vT[((size_t)(b * 16 + h) * 64 + vdv) * 2048 + vkv8];

  const size_t KSTEP = (size_t)64 * HD, C32 = (size_t)32 * HD;

  bf16x4 kr[2];
  kr[0] = *(const bf16x4*)kp; kr[1] = *(const bf16x4*)(kp + C32);
  bf16x8 vr = *(const bf16x8*)vp;
  kp += KSTEP; vp += 64;

  for (int it = 0; it < 32; ++it) {
    *(bf16x4*)ksw[0] = kr[0];
    *(bf16x4*)ksw[1] = kr[1];
    bf16x4 vlo = { vr[0], vr[1], vr[2], vr[3] };
    bf16x4 vhi = { vr[4], vr[5], vr[6], vr[7] };
    *(bf16x4*)vsw0 = vlo;
    *(bf16x4*)vsw1 = vhi;
    __syncthreads();

    if (it < 31) {
      kr[0] = *(const bf16x4*)kp; kr[1] = *(const bf16x4*)(kp + C32);
      vr = *(const bf16x8*)vp;
      kp += KSTEP; vp += 64;
    }

#pragma unroll
    for (int s = 0; s < 2; ++s) {
      bf16x8 kf[2][2];
#pragma unroll
      for (int mf = 0; mf < 2; ++mf)
#pragma unroll
        for (int kk = 0; kk < 2; ++kk)
          kf[mf][kk] = *(const bf16x8*)&Ks[(s * 32 + mf * 16 + ln) * 72 + kk * 32 + 8 * g];

      f32x4 sc[2][2];
      __builtin_amdgcn_s_setprio(1);
#pragma unroll
      for (int mf = 0; mf < 2; ++mf)
#pragma unroll
        for (int nf = 0; nf < 2; ++nf) {
          f32x4 a; a[0]=0.f; a[1]=0.f; a[2]=0.f; a[3]=0.f;
#pragma unroll
          for (int kk = 0; kk < 2; ++kk)
            a = __builtin_amdgcn_mfma_f32_16x16x32_bf16(kf[mf][kk], qf[nf][kk], a, 0, 0, 0);
          sc[mf][nf] = a;
        }
      __builtin_amdgcn_s_setprio(0);

      bf16x8 vf[4];
#pragma unroll
      for (int nf = 0; nf < 4; ++nf)
        vf[nf] = *(const bf16x8*)&Vt[(nf * 16 + ln) * 72 + s * 32 + 8 * g];

      bf16x8 pa[2];
#pragma unroll
      for (int nf = 0; nf < 2; ++nf) {
        float pv[2][4];
#pragma unroll
        for (int mf = 0; mf < 2; ++mf)
#pragma unroll
          for (int r = 0; r < 4; ++r)
            pv[mf][r] = EXP2(sc[mf][nf][r]);
        union { u32x4 u; bf16x8 b; } pk;
        pk.u[0] = cvt_pk_bf16(pv[0][0], pv[0][1]);
        pk.u[1] = cvt_pk_bf16(pv[0][2], pv[0][3]);
        pk.u[2] = cvt_pk_bf16(pv[1][0], pv[1][1]);
        pk.u[3] = cvt_pk_bf16(pv[1][2], pv[1][3]);
        pa[nf] = pk.b;
      }

      __builtin_amdgcn_s_setprio(1);
#pragma unroll
      for (int mq = 0; mq < 2; ++mq) {
#pragma unroll
        for (int nf = 0; nf < 4; ++nf)
          o[mq][nf] = __builtin_amdgcn_mfma_f32_16x16x32_bf16(pa[mq], vf[nf], o[mq][nf], 0, 0, 0);
        o1[mq] = __builtin_amdgcn_mfma_f32_16x16x32_bf16(pa[mq], ones, o1[mq], 0, 0, 0);
      }
      __builtin_amdgcn_s_setprio(0);
    }
    __syncthreads();
  }

#pragma unroll
  for (int mq = 0; mq < 2; ++mq)
#pragma unroll
    for (int r = 0; r < 4; ++r) {
      float inv = 1.0f / o1[mq][r];
      int qrow = qwin + mq * 16 + 4 * g + r;
#pragma unroll
      for (int nf = 0; nf < 4; ++nf)
        out[(bS + qrow) * HD + h * 64 + nf * 16 + ln] = o[mq][nf][r] * inv;
    }
}

extern "C" void kernel_launch(void* const* d_in, const int* in_sizes, int n_in,
                              void* d_out, int out_size, void* d_ws, size_t ws_size,
                              hipStream_t stream) {
  const float* q  = (const float*)d_in[0];
  const float* k  = (const float*)d_in[1];
  const float* v  = (const float*)d_in[2];
  const float* Wq = (const float*)d_in[3];
  const float* bq = (const float*)d_in[4];
  const float* Wk = (const float*)d_in[5];
  const float* bk = (const float*)d_in[6];
  const float* Wv = (const float*)d_in[7];
  const float* bv = (const float*)d_in[8];
  float* out = (float*)d_out;

  u16* qh = (u16*)d_ws;
  u16* kh = qh + (size_t)8192 * 1024;
  u16* vT = kh + (size_t)8192 * 1024;     // [b][h][dv][seq]

  const size_t XB_OFF = (size_t)3 * 8192 * 1024;
  const size_t WT_OFF = XB_OFF + (size_t)3 * 8192 * 1024;
  const size_t NEED   = (WT_OFF + (size_t)3 * 1024 * 1024) * 2;

  if (ws_size >= NEED) {
    u16* Xb = (u16*)d_ws + XB_OFF;
    u16* Wt = (u16*)d_ws + WT_OFF;
    conv_kernel<<<dim3(1152, 3), 256, 0, stream>>>(q, k, v, Wq, Wk, Wv, Xb, Wt);
    gemm_kernel<<<dim3(8, 64, 3), 256, 0, stream>>>(Xb, Wt, bq, bk, bv, qh, kh, vT);
  } else {
    proj_kernel<<<dim3(8, 64, 3), 256, 0, stream>>>(q, k, v, Wq, Wk, Wv, bq, bk, bv, qh, kh, vT);
  }
  attn_kernel<<<dim3(8, 16, 4), 512, 0, stream>>>(qh, kh, vT, out);
}

// Round 15
// 168.647 us; speedup vs baseline: 1.3404x; 1.0140x over previous
//
#include <hip/hip_runtime.h>
#include <hip/hip_bf16.h>

// MultiHeadAttention: B=4 S=2048 D=1024 H=16 DK=DV=64 scale=8
// R15: gemm LDS-traffic halved — B-fragments load DIRECTLY global->VGPR from
// the fragment-ordered, L2-resident Wt (one b128/frag, prefetched 1 phase
// ahead, compiler-counted vmcnt for the reg dep); only A stays in LDS (3-buf
// counted-vmcnt protocol, vmcnt(6) = 2 A-DMA + 4 B-loads in flight).
// Evidence: R12/R13/R14 pinned at 84us across 3 sync structures; per-phase
// LDS pipe ~512cyc vs 77cyc MFMA -> LDS BW was the wall (32 b128 + 16KB DMA).
// Removing B: 256cyc, under the MFMA floor. Wt XOR swizzle dropped (B skips
// LDS); Xb swizzle kept. attn/conv-X/proj frozen.

typedef unsigned short u16;
typedef unsigned int   u32;
typedef short bf16x8 __attribute__((ext_vector_type(8)));
typedef short bf16x4 __attribute__((ext_vector_type(4)));
typedef float f32x4  __attribute__((ext_vector_type(4)));
typedef u32   u32x4  __attribute__((ext_vector_type(4)));

#define S_TOT 2048
#define HD    1024
#define QK_SCALE 0.18033688f   // log2(e)/8

#if __has_builtin(__builtin_amdgcn_exp2f)
#define EXP2(x) __builtin_amdgcn_exp2f(x)
#else
#define EXP2(x) exp2f(x)
#endif

__device__ __forceinline__ u16 f2bf(float f) {
  union { float f; unsigned u; } v; v.f = f;
  unsigned r = v.u + 0x7FFFu + ((v.u >> 16) & 1u);
  return (u16)(r >> 16);
}

__device__ __forceinline__ u32 cvt_pk_bf16(float lo, float hi) {
  u32 r;
  asm("v_cvt_pk_bf16_f32 %0, %1, %2" : "=v"(r) : "v"(lo), "v"(hi));
  return r;
}

__device__ __forceinline__ bf16x4 ds_tr16(unsigned a) {
  bf16x4 d;
  asm volatile("ds_read_b64_tr_b16 %0, %1" : "=v"(d) : "v"(a) : "memory");
  return d;
}

__device__ __forceinline__ void gld16(const u16* g, u16* l) {
  __builtin_amdgcn_global_load_lds(
      (const __attribute__((address_space(1))) u32*)g,
      (__attribute__((address_space(3))) u32*)l, 16, 0, 0);
}

// rule #18 fence — used ONLY by the fallback proj
#define LGKM_FENCE() do { asm volatile("s_waitcnt lgkmcnt(0)" ::: "memory"); \
                          __builtin_amdgcn_sched_barrier(0); } while (0)

// counted-vmcnt phase boundary: keep N newest VMEM ops in flight across barrier
#define PIPE_BAR(N) do { asm volatile("s_waitcnt vmcnt(" #N ")" ::: "memory"); \
                         __builtin_amdgcn_s_barrier(); \
                         __builtin_amdgcn_sched_barrier(0); } while (0)

// ---------------------------------------------------------------------------
// conv_kernel: fp32 -> bf16 re-layout.
//  Xb: row-major, intra-32 split-K perm, + XOR swizzle ((row&6)<<2)  [A: LDS]
//  Wt: W^T tiles [(nb*32+kb)][128 n][32 kperm], NO swizzle            [B: reg]
// ---------------------------------------------------------------------------
__global__ __launch_bounds__(256)
void conv_kernel(const float* __restrict__ x0, const float* __restrict__ x1, const float* __restrict__ x2,
                 const float* __restrict__ w0, const float* __restrict__ w1, const float* __restrict__ w2,
                 u16* __restrict__ Xb, u16* __restrict__ Wt)
{
  const int z = blockIdx.y;
  const int t = threadIdx.x;
  if (blockIdx.x < 1024) {
    const float* X = z == 0 ? x0 : (z == 1 ? x1 : x2);
    u16* Xz = Xb + (size_t)z * 8388608;
    int tid = blockIdx.x * 256 + t;
#pragma unroll
    for (int i = 0; i < 8; ++i) {
      int c = tid + i * 262144;
      int row = c >> 8, k4 = (c & 255) * 4;
      const float4 xv = *(const float4*)&X[(size_t)row * 1024 + k4];
      int p = (k4 & ~31) + 8 * ((k4 & 15) >> 2) + 4 * ((k4 >> 4) & 1);
      p ^= (row & 6) << 2;
      bf16x4 sv = { (short)f2bf(xv.x), (short)f2bf(xv.y), (short)f2bf(xv.z), (short)f2bf(xv.w) };
      *(bf16x4*)&Xz[(size_t)row * 1024 + p] = sv;
    }
  } else {
    const float* W = z == 0 ? w0 : (z == 1 ? w1 : w2);
    u16* Wz = Wt + (size_t)z * 1048576;
    int tid = (blockIdx.x - 1024) * 256 + t;
#pragma unroll
    for (int i = 0; i < 8; ++i) {
      int c = tid + i * 32768;
      int n = c & 1023, k4 = (c >> 10) * 4;
      float wv0 = W[(size_t)(k4 + 0) * 1024 + n];
      float wv1 = W[(size_t)(k4 + 1) * 1024 + n];
      float wv2 = W[(size_t)(k4 + 2) * 1024 + n];
      float wv3 = W[(size_t)(k4 + 3) * 1024 + n];
      int kl = k4 & 31;
      int kp = 8 * ((kl & 15) >> 2) + 4 * ((kl >> 4) & 1);
      int off = ((n >> 7) * 32 + (k4 >> 5)) * 4096 + (n & 127) * 32 + kp;
      bf16x4 sv = { (short)f2bf(wv0), (short)f2bf(wv1), (short)f2bf(wv2), (short)f2bf(wv3) };
      *(bf16x4*)&Wz[off] = sv;
    }
  }
}

// ---------------------------------------------------------------------------
// gemm_kernel R15: A in LDS (3-buf, counted vmcnt), B direct global->reg
// (ping-pong prefetch). z<2: natural out. z==2: swapped operands -> vT.
// ---------------------------------------------------------------------------
__global__ __launch_bounds__(256)
void gemm_kernel(const u16* __restrict__ Xb, const u16* __restrict__ Wt,
                 const float* __restrict__ b0, const float* __restrict__ b1, const float* __restrict__ b2,
                 u16* __restrict__ o0, u16* __restrict__ o1, u16* __restrict__ vT)
{
  int p  = blockIdx.x + 8 * blockIdx.y + 512 * blockIdx.z;
  int wk = (p & 7) * 192 + (p >> 3);
  int nb = wk & 7, mb = (wk >> 3) & 63, z = wk >> 9;

  const u16* Xz = Xb + (size_t)z * 8388608;
  const u16* Wz = Wt + (size_t)z * 1048576;
  const float* BS = z == 0 ? b0 : (z == 1 ? b1 : b2);
  const float  osc = (z == 0) ? QK_SCALE : 1.0f;

  const int t = threadIdx.x;
  const int lane = t & 63, wid = t >> 6;
  const int g = lane >> 4, ln = lane & 15;
  const int mbase = mb * 128, nbase = nb * 128;
  const int xr = (ln & 6) << 2;                  // A read-side swizzle (u16)

  __shared__ __align__(16) u16 Al[3][128 * 32];  // 3 x 8KB (A only)

  f32x4 acc[4][4];
#pragma unroll
  for (int i = 0; i < 4; ++i)
#pragma unroll
    for (int j = 0; j < 4; ++j) { acc[i][j][0]=0.f; acc[i][j][1]=0.f; acc[i][j][2]=0.f; acc[i][j][3]=0.f; }

  const u16* sa = Xz + (size_t)(mbase + (t >> 2)) * 1024 + (t & 3) * 8;
  u16* alw[3] = { &Al[0][wid * 512], &Al[1][wid * 512], &Al[2][wid * 512] };

  auto stage = [&](int kb, int buf) __attribute__((always_inline)) {
    gld16(sa + kb * 32,               alw[buf]);
    gld16(sa + kb * 32 + 64 * 1024,   alw[buf] + 2048);
  };

  // B fragment source: wave's 128-row W^T panel half (wn/wdv selects 64 rows)
  const int whalf = (z < 2) ? (wid & 1) : (wid & 1);   // second wave-axis
  const u16* wfp = Wz + (size_t)(nb * 32) * 4096
                 + (whalf * 64 + ln) * 32 + g * 8;

  auto loadB = [&](int kb, bf16x8* dst) __attribute__((always_inline)) {
#pragma unroll
    for (int nf = 0; nf < 4; ++nf)
      dst[nf] = *(const bf16x8*)(wfp + (size_t)kb * 4096 + nf * 512);
  };

  bf16x8 bA[4], bB[4];

  // prologue: A tile0, B tile0, A tile1; wait tile0's A (keep newest 6)
  stage(0, 0);
  loadB(0, bA);
  stage(1, 1);
  PIPE_BAR(6);

  if (z < 2) {
    const int wm = wid >> 1;
    u16* O = z == 0 ? o0 : o1;

    auto compute = [&](int cur, const bf16x8* bq) __attribute__((always_inline)) {
      bf16x8 af[4];
#pragma unroll
      for (int mf = 0; mf < 4; ++mf)
        af[mf] = *(const bf16x8*)&Al[cur][(wm * 64 + mf * 16 + ln) * 32 + (g * 8 ^ xr)];
      __builtin_amdgcn_s_setprio(1);
#pragma unroll
      for (int mf = 0; mf < 4; ++mf)
#pragma unroll
        for (int nf = 0; nf < 4; ++nf)
          acc[mf][nf] = __builtin_amdgcn_mfma_f32_16x16x32_bf16(af[mf], bq[nf], acc[mf][nf], 0, 0, 0);
      __builtin_amdgcn_s_setprio(0);
    };

    // phases 0..29 (6-unrolled: A-buf = t%3, B ping-pong = t%2, all static)
    for (int kb = 0; kb < 30; kb += 6) {
      stage(kb + 2, 2); loadB(kb + 1, bB); compute(0, bA); PIPE_BAR(6);
      stage(kb + 3, 0); loadB(kb + 2, bA); compute(1, bB); PIPE_BAR(6);
      stage(kb + 4, 1); loadB(kb + 3, bB); compute(2, bA); PIPE_BAR(6);
      stage(kb + 5, 2); loadB(kb + 4, bA); compute(0, bB); PIPE_BAR(6);
      stage(kb + 6, 0); loadB(kb + 5, bB); compute(1, bA); PIPE_BAR(6);
      stage(kb + 7, 1); loadB(kb + 6, bA); compute(2, bB); PIPE_BAR(6);
    }
    // epilogue: phases 30, 31 (A tiles 30,31 staged at t=28,29; drain then finish)
    loadB(31, bB); compute(0, bA); PIPE_BAR(0);
    compute(1, bB);

#pragma unroll
    for (int nf = 0; nf < 4; ++nf) {
      int n = nbase + whalf * 64 + nf * 16 + ln;
      float bv = BS[n];
#pragma unroll
      for (int mf = 0; mf < 4; ++mf)
#pragma unroll
        for (int r = 0; r < 4; ++r) {
          int m = mbase + wm * 64 + mf * 16 + 4 * g + r;
          O[(size_t)m * 1024 + n] = f2bf((acc[mf][nf][r] + bv) * osc);
        }
    }
  } else {
    // z==2 swapped: A-operand = W-frags (regs), B-operand = X-frags (LDS).
    const int wseq = wid >> 1;

    auto compute2 = [&](int cur, const bf16x8* wq) __attribute__((always_inline)) {
      bf16x8 bfx[4];
#pragma unroll
      for (int nf = 0; nf < 4; ++nf)
        bfx[nf] = *(const bf16x8*)&Al[cur][(wseq * 64 + nf * 16 + ln) * 32 + (g * 8 ^ xr)];
      __builtin_amdgcn_s_setprio(1);
#pragma unroll
      for (int mf = 0; mf < 4; ++mf)
#pragma unroll
        for (int nf = 0; nf < 4; ++nf)
          acc[mf][nf] = __builtin_amdgcn_mfma_f32_16x16x32_bf16(wq[mf], bfx[nf], acc[mf][nf], 0, 0, 0);
      __builtin_amdgcn_s_setprio(0);
    };

    for (int kb = 0; kb < 30; kb += 6) {
      stage(kb + 2, 2); loadB(kb + 1, bB); compute2(0, bA); PIPE_BAR(6);
      stage(kb + 3, 0); loadB(kb + 2, bA); compute2(1, bB); PIPE_BAR(6);
      stage(kb + 4, 1); loadB(kb + 3, bB); compute2(2, bA); PIPE_BAR(6);
      stage(kb + 5, 2); loadB(kb + 4, bA); compute2(0, bB); PIPE_BAR(6);
      stage(kb + 6, 0); loadB(kb + 5, bB); compute2(1, bA); PIPE_BAR(6);
      stage(kb + 7, 1); loadB(kb + 6, bA); compute2(2, bB); PIPE_BAR(6);
    }
    loadB(31, bB); compute2(0, bA); PIPE_BAR(0);
    compute2(1, bB);

#pragma unroll
    for (int mf = 0; mf < 4; ++mf)
#pragma unroll
      for (int r = 0; r < 4; ++r) {
        int dvg = nbase + whalf * 64 + mf * 16 + 4 * g + r;
        float bv = BS[dvg];
        int hh = dvg >> 6, dvl = dvg & 63;
#pragma unroll
        for (int nf = 0; nf < 4; ++nf) {
          int m = mbase + wseq * 64 + nf * 16 + ln;
          int bb = m >> 11, ss = m & 2047;
          vT[((size_t)(bb * 16 + hh) * 64 + dvl) * 2048 + ss] = f2bf(acc[mf][nf][r] + bv);
        }
      }
  }
}

// ---------------------------------------------------------------------------
// Fallback proj (frozen; reads original X/W; z==2 transposed scatter).
// ---------------------------------------------------------------------------
__global__ __launch_bounds__(256)
void proj_kernel(const float* __restrict__ x0, const float* __restrict__ x1, const float* __restrict__ x2,
                 const float* __restrict__ w0, const float* __restrict__ w1, const float* __restrict__ w2,
                 const float* __restrict__ b0, const float* __restrict__ b1, const float* __restrict__ b2,
                 u16* __restrict__ o0, u16* __restrict__ o1, u16* __restrict__ vT)
{
  int p  = blockIdx.x + 8 * blockIdx.y + 512 * blockIdx.z;
  int wk = (p & 7) * 192 + (p >> 3);
  int nb = wk & 7, mb = (wk >> 3) & 63, z = wk >> 9;

  const float* X  = z == 0 ? x0 : (z == 1 ? x1 : x2);
  const float* W  = z == 0 ? w0 : (z == 1 ? w1 : w2);
  const float* BS = z == 0 ? b0 : (z == 1 ? b1 : b2);
  const float  osc = (z == 0) ? QK_SCALE : 1.0f;

  const int t = threadIdx.x;
  const int lane = t & 63, wid = t >> 6;
  const int g = lane >> 4, ln = lane & 15;
  const int wm = wid >> 1, wn = wid & 1;
  const int mbase = mb * 128, nbase = nb * 128;

  __shared__ __align__(16) u16 As[128 * 40];
  __shared__ __align__(16) u16 Bs[16 * 272];

  f32x4 acc[4][4];
#pragma unroll
  for (int i = 0; i < 4; ++i)
#pragma unroll
    for (int j = 0; j < 4; ++j) { acc[i][j][0]=0.f; acc[i][j][1]=0.f; acc[i][j][2]=0.f; acc[i][j][3]=0.f; }

  const int arow = t >> 3;
  const int ak0  = (t & 7) * 4;
  const int ap   = 8 * ((ak0 & 15) >> 2) + 4 * (ak0 >> 4);
  const int bkr  = t >> 5;
  const int bnc  = (t & 31) * 4;
  const int bnblk = bnc >> 4, bncl = bnc & 15;

  const unsigned bs_base = (unsigned)(size_t)&Bs[0];

  for (int kb = 0; kb < 32; ++kb) {
    const int kbase = kb * 32;
#pragma unroll
    for (int ps = 0; ps < 4; ++ps) {
      int row = arow + 32 * ps;
      const float4 xv = *(const float4*)&X[(size_t)(mbase + row) * 1024 + kbase + ak0];
      bf16x4 sv = { (short)f2bf(xv.x), (short)f2bf(xv.y), (short)f2bf(xv.z), (short)f2bf(xv.w) };
      *(bf16x4*)&As[row * 40 + ap] = sv;
    }
#pragma unroll
    for (int ps = 0; ps < 4; ++ps) {
      int kr = bkr + 8 * ps;
      const float4 wv = *(const float4*)&W[(size_t)(kbase + kr) * 1024 + nbase + bnc];
      bf16x4 sv = { (short)f2bf(wv.x), (short)f2bf(wv.y), (short)f2bf(wv.z), (short)f2bf(wv.w) };
      *(bf16x4*)&Bs[(bnblk * 2 + (kr >> 4)) * 272 + (kr & 15) * 16 + bncl] = sv;
    }
    __syncthreads();

    bf16x8 af[4];
#pragma unroll
    for (int mf = 0; mf < 4; ++mf)
      af[mf] = *(const bf16x8*)&As[(wm * 64 + mf * 16 + ln) * 40 + g * 8];

    bf16x8 bfv[4];
#pragma unroll
    for (int nf = 0; nf < 4; ++nf) {
      unsigned base = bs_base + (unsigned)(((wn * 4 + nf) * 2) * 544) + lane * 8;
      bf16x4 lo = ds_tr16(base);
      bf16x4 hi = ds_tr16(base + 544);
      bf16x8 bb;
      bb[0]=lo[0]; bb[1]=lo[1]; bb[2]=lo[2]; bb[3]=lo[3];
      bb[4]=hi[0]; bb[5]=hi[1]; bb[6]=hi[2]; bb[7]=hi[3];
      bfv[nf] = bb;
    }
    LGKM_FENCE();
#pragma unroll
    for (int mf = 0; mf < 4; ++mf)
#pragma unroll
      for (int nf = 0; nf < 4; ++nf)
        acc[mf][nf] = __builtin_amdgcn_mfma_f32_16x16x32_bf16(af[mf], bfv[nf], acc[mf][nf], 0, 0, 0);
    __syncthreads();
  }

#pragma unroll
  for (int nf = 0; nf < 4; ++nf) {
    int n = nbase + wn * 64 + nf * 16 + ln;
    float bv = BS[n];
#pragma unroll
    for (int mf = 0; mf < 4; ++mf)
#pragma unroll
      for (int r = 0; r < 4; ++r) {
        int m = mbase + wm * 64 + mf * 16 + 4 * g + r;
        float val = (acc[mf][nf][r] + bv) * osc;
        if (z < 2) {
          u16* O = z == 0 ? o0 : o1;
          O[(size_t)m * 1024 + n] = f2bf(val);
        } else {
          vT[((size_t)((m >> 11) * 16 + (n >> 6)) * 64 + (n & 63)) * 2048 + (m & 2047)] = f2bf(val);
        }
      }
  }
}

// ---------------------------------------------------------------------------
// Attention (R11, frozen): V^T LDS, plain b128 V-frags, no asm/fences in loop.
// 8 waves, QBLK=256, KVBLK=64, 2-barrier protocol, ones-MFMA rowsum, setprio.
// ---------------------------------------------------------------------------
__global__ __launch_bounds__(512)
void attn_kernel(const u16* __restrict__ qh, const u16* __restrict__ kh, const u16* __restrict__ vT,
                 float* __restrict__ out)
{
  int p  = blockIdx.x + 8 * blockIdx.y + 128 * blockIdx.z;
  int wk = (p & 7) * 64 + (p >> 3);
  int qt = wk & 7, h = (wk >> 3) & 15, b = wk >> 7;

  const int t = threadIdx.x;
  const int lane = t & 63, wid = t >> 6;
  const int g = lane >> 4, ln = lane & 15;
  const size_t bS = (size_t)b * S_TOT;
  const int qwin = qt * 256 + wid * 32;

  __shared__ __align__(16) u16 Ks[64 * 72];
  __shared__ __align__(16) u16 Vt[64 * 72];

  bf16x8 qf[2][2];
#pragma unroll
  for (int nf = 0; nf < 2; ++nf) {
    const u16* qrow = &qh[(bS + qwin + nf * 16 + ln) * HD + h * 64];
#pragma unroll
    for (int kk = 0; kk < 2; ++kk) {
      bf16x4 lo = *(const bf16x4*)&qrow[kk * 32 + 4 * g];
      bf16x4 hi = *(const bf16x4*)&qrow[kk * 32 + 4 * g + 16];
      bf16x8 qq;
      qq[0]=lo[0]; qq[1]=lo[1]; qq[2]=lo[2]; qq[3]=lo[3];
      qq[4]=hi[0]; qq[5]=hi[1]; qq[6]=hi[2]; qq[7]=hi[3];
      qf[nf][kk] = qq;
    }
  }

  bf16x8 ones;
#pragma unroll
  for (int j = 0; j < 8; ++j) ones[j] = (short)0x3F80;

  f32x4 o[2][4];
#pragma unroll
  for (int i = 0; i < 2; ++i)
#pragma unroll
    for (int j = 0; j < 4; ++j) { o[i][j][0]=0.f; o[i][j][1]=0.f; o[i][j][2]=0.f; o[i][j][3]=0.f; }
  f32x4 o1[2];
  o1[0][0]=0.f; o1[0][1]=0.f; o1[0][2]=0.f; o1[0][3]=0.f;
  o1[1][0]=0.f; o1[1][1]=0.f; o1[1][2]=0.f; o1[1][3]=0.f;

  const int skv = t >> 4;
  const int sd0 = (t & 15) * 4;
  const int kpos = 32 * (sd0 >> 5) + 8 * ((sd0 & 15) >> 2) + 4 * ((sd0 >> 4) & 1);
  u16* ksw[2];
  ksw[0] = &Ks[skv * 72 + kpos];
  ksw[1] = &Ks[(skv + 32) * 72 + kpos];
  const u16* kp = &kh[(bS + skv) * HD + h * 64 + sd0];

  const int vdv  = t >> 3;
  const int vkv8 = (t & 7) * 8;
  const int vp0  = 32 * (vkv8 >> 5) + 8 * ((vkv8 & 15) >> 2) + 4 * ((vkv8 >> 4) & 1);
  const int vkv4 = vkv8 + 4;
  const int vp1  = 32 * (vkv4 >> 5) + 8 * ((vkv4 & 15) >> 2) + 4 * ((vkv4 >> 4) & 1);
  u16* vsw0 = &Vt[vdv * 72 + vp0];
  u16* vsw1 = &Vt[vdv * 72 + vp1];
  const u16* vp = &vT[((size_t)(b * 16 + h) * 64 + vdv) * 2048 + vkv8];

  const size_t KSTEP = (size_t)64 * HD, C32 = (size_t)32 * HD;

  bf16x4 kr[2];
  kr[0] = *(const bf16x4*)kp; kr[1] = *(const bf16x4*)(kp + C32);
  bf16x8 vr = *(const bf16x8*)vp;
  kp += KSTEP; vp += 64;

  for (int it = 0; it < 32; ++it) {
    *(bf16x4*)ksw[0] = kr[0];
    *(bf16x4*)ksw[1] = kr[1];
    bf16x4 vlo = { vr[0], vr[1], vr[2], vr[3] };
    bf16x4 vhi = { vr[4], vr[5], vr[6], vr[7] };
    *(bf16x4*)vsw0 = vlo;
    *(bf16x4*)vsw1 = vhi;
    __syncthreads();

    if (it < 31) {
      kr[0] = *(const bf16x4*)kp; kr[1] = *(const bf16x4*)(kp + C32);
      vr = *(const bf16x8*)vp;
      kp += KSTEP; vp += 64;
    }

#pragma unroll
    for (int s = 0; s < 2; ++s) {
      bf16x8 kf[2][2];
#pragma unroll
      for (int mf = 0; mf < 2; ++mf)
#pragma unroll
        for (int kk = 0; kk < 2; ++kk)
          kf[mf][kk] = *(const bf16x8*)&Ks[(s * 32 + mf * 16 + ln) * 72 + kk * 32 + 8 * g];

      f32x4 sc[2][2];
      __builtin_amdgcn_s_setprio(1);
#pragma unroll
      for (int mf = 0; mf < 2; ++mf)
#pragma unroll
        for (int nf = 0; nf < 2; ++nf) {
          f32x4 a; a[0]=0.f; a[1]=0.f; a[2]=0.f; a[3]=0.f;
#pragma unroll
          for (int kk = 0; kk < 2; ++kk)
            a = __builtin_amdgcn_mfma_f32_16x16x32_bf16(kf[mf][kk], qf[nf][kk], a, 0, 0, 0);
          sc[mf][nf] = a;
        }
      __builtin_amdgcn_s_setprio(0);

      bf16x8 vf[4];
#pragma unroll
      for (int nf = 0; nf < 4; ++nf)
        vf[nf] = *(const bf16x8*)&Vt[(nf * 16 + ln) * 72 + s * 32 + 8 * g];

      bf16x8 pa[2];
#pragma unroll
      for (int nf = 0; nf < 2; ++nf) {
        float pv[2][4];
#pragma unroll
        for (int mf = 0; mf < 2; ++mf)
#pragma unroll
          for (int r = 0; r < 4; ++r)
            pv[mf][r] = EXP2(sc[mf][nf][r]);
        union { u32x4 u; bf16x8 b; } pk;
        pk.u[0] = cvt_pk_bf16(pv[0][0], pv[0][1]);
        pk.u[1] = cvt_pk_bf16(pv[0][2], pv[0][3]);
        pk.u[2] = cvt_pk_bf16(pv[1][0], pv[1][1]);
        pk.u[3] = cvt_pk_bf16(pv[1][2], pv[1][3]);
        pa[nf] = pk.b;
      }

      __builtin_amdgcn_s_setprio(1);
#pragma unroll
      for (int mq = 0; mq < 2; ++mq) {
#pragma unroll
        for (int nf = 0; nf < 4; ++nf)
          o[mq][nf] = __builtin_amdgcn_mfma_f32_16x16x32_bf16(pa[mq], vf[nf], o[mq][nf], 0, 0, 0);
        o1[mq] = __builtin_amdgcn_mfma_f32_16x16x32_bf16(pa[mq], ones, o1[mq], 0, 0, 0);
      }
      __builtin_amdgcn_s_setprio(0);
    }
    __syncthreads();
  }

#pragma unroll
  for (int mq = 0; mq < 2; ++mq)
#pragma unroll
    for (int r = 0; r < 4; ++r) {
      float inv = 1.0f / o1[mq][r];
      int qrow = qwin + mq * 16 + 4 * g + r;
#pragma unroll
      for (int nf = 0; nf < 4; ++nf)
        out[(bS + qrow) * HD + h * 64 + nf * 16 + ln] = o[mq][nf][r] * inv;
    }
}

extern "C" void kernel_launch(void* const* d_in, const int* in_sizes, int n_in,
                              void* d_out, int out_size, void* d_ws, size_t ws_size,
                              hipStream_t stream) {
  const float* q  = (const float*)d_in[0];
  const float* k  = (const float*)d_in[1];
  const float* v  = (const float*)d_in[2];
  const float* Wq = (const float*)d_in[3];
  const float* bq = (const float*)d_in[4];
  const float* Wk = (const float*)d_in[5];
  const float* bk = (const float*)d_in[6];
  const float* Wv = (const float*)d_in[7];
  const float* bv = (const float*)d_in[8];
  float* out = (float*)d_out;

  u16* qh = (u16*)d_ws;
  u16* kh = qh + (size_t)8192 * 1024;
  u16* vT = kh + (size_t)8192 * 1024;     // [b][h][dv][seq]

  const size_t XB_OFF = (size_t)3 * 8192 * 1024;
  const size_t WT_OFF = XB_OFF + (size_t)3 * 8192 * 1024;
  const size_t NEED   = (WT_OFF + (size_t)3 * 1024 * 1024) * 2;

  if (ws_size >= NEED) {
    u16* Xb = (u16*)d_ws + XB_OFF;
    u16* Wt = (u16*)d_ws + WT_OFF;
    conv_kernel<<<dim3(1152, 3), 256, 0, stream>>>(q, k, v, Wq, Wk, Wv, Xb, Wt);
    gemm_kernel<<<dim3(8, 64, 3), 256, 0, stream>>>(Xb, Wt, bq, bk, bv, qh, kh, vT);
  } else {
    proj_kernel<<<dim3(8, 64, 3), 256, 0, stream>>>(q, k, v, Wq, Wk, Wv, bq, bk, bv, qh, kh, vT);
  }
  attn_kernel<<<dim3(8, 16, 4), 512, 0, stream>>>(qh, kh, vT, out);
}